// Round 1
// baseline (282.293 us; speedup 1.0000x reference)
//
#include <hip/hip_runtime.h>
#include <math.h>

#define HEADS 8
#define DH 32
#define NB 64        // batch B
#define NN 256       // sequence N
#define ND 256       // model dim D
#define INNER 256    // HEADS*DH
#define NEG_MAX (-3.402823466e+38f)

// -------- ws layout (floats) --------
// proj   : [16384][1024]  cols 0-255 q*scale | 256-511 k | 512-767 v | 768-1023 gates(sigmoid)
// qt     : [256][256]     tied (mean over batch) q, layout [i][head*32+d]
// att    : [16384][256]   attention output * gates
// maskc  : [64][256] int  canonical mask
#define OFF_PROJ 0
#define OFF_QT   (16384*1024)
#define OFF_ATT  (OFF_QT + 256*256)
#define OFF_MASK (OFF_ATT + 16384*256)

// ---------------------------------------------------------------------------
// Kernel 0: canonicalize mask (handles bool-bytes or int32 input layout)
__global__ void mask_canon_kernel(const unsigned char* __restrict__ mraw,
                                  int* __restrict__ mout) {
    __shared__ int cnt[256];
    int tid = threadIdx.x;
    int c = 0;
    for (int i = tid; i < 4096; i += 256)
        if ((i & 3) != 0 && mraw[i] != 0) c++;
    cnt[tid] = c;
    __syncthreads();
    for (int s = 128; s > 0; s >>= 1) {
        if (tid < s) cnt[tid] += cnt[tid + s];
        __syncthreads();
    }
    int isBool = cnt[0] > 16;   // int32 layout has zero high bytes
    if (isBool) {
        for (int i = tid; i < NB * NN; i += 256)
            mout[i] = mraw[i] ? 1 : 0;
    } else {
        const int* mi = (const int*)mraw;
        for (int i = tid; i < NB * NN; i += 256)
            mout[i] = mi[i] ? 1 : 0;
    }
}

// ---------------------------------------------------------------------------
// Kernel 1: proj = x @ [Wq | Wkv | Wg]  (16384 x 1024), fused epilogues.
// Tiled fp32 GEMM: BM=64 BN=64 BK=16, 256 threads, 4x4 micro-tile.
__global__ __launch_bounds__(256) void proj_gemm(
    const float* __restrict__ x, const float* __restrict__ Wq,
    const float* __restrict__ Wkv, const float* __restrict__ Wg,
    const float* __restrict__ bg, float* __restrict__ proj) {
    __shared__ float As[16][64];  // [k][m]
    __shared__ float Bs[16][64];  // [k][n]
    const int tid = threadIdx.x;
    const int m0 = blockIdx.y * 64;
    const int n0 = blockIdx.x * 64;   // 0..960

    const float* Bsrc; int ldb, bn0, mode;
    if (n0 < 256)      { Bsrc = Wq;  ldb = 256; bn0 = n0;       mode = 0; }
    else if (n0 < 768) { Bsrc = Wkv; ldb = 512; bn0 = n0 - 256; mode = 1; }
    else               { Bsrc = Wg;  ldb = 256; bn0 = n0 - 768; mode = 2; }

    const int tx = tid & 15, ty = tid >> 4;
    const int arow = tid >> 2, acol = (tid & 3) << 2;   // A loads
    const int brow = tid >> 4, bcol = (tid & 15) << 2;  // B loads

    float acc[4][4] = {};

    for (int k0 = 0; k0 < 256; k0 += 16) {
        float4 av = *(const float4*)(x + (size_t)(m0 + arow) * 256 + k0 + acol);
        float4 bv = *(const float4*)(Bsrc + (size_t)(k0 + brow) * ldb + bn0 + bcol);
        __syncthreads();
        As[acol + 0][arow] = av.x;
        As[acol + 1][arow] = av.y;
        As[acol + 2][arow] = av.z;
        As[acol + 3][arow] = av.w;
        *(float4*)(&Bs[brow][bcol]) = bv;
        __syncthreads();
#pragma unroll
        for (int kk = 0; kk < 16; kk++) {
            float a[4], b[4];
#pragma unroll
            for (int i = 0; i < 4; i++) a[i] = As[kk][ty * 4 + i];
#pragma unroll
            for (int j = 0; j < 4; j++) b[j] = Bs[kk][tx * 4 + j];
#pragma unroll
            for (int i = 0; i < 4; i++)
#pragma unroll
                for (int j = 0; j < 4; j++)
                    acc[i][j] = fmaf(a[i], b[j], acc[i][j]);
        }
    }

    const float qscale = 0.17677669529663687f;  // 1/sqrt(32)
#pragma unroll
    for (int i = 0; i < 4; i++) {
        int gm = m0 + ty * 4 + i;
#pragma unroll
        for (int j = 0; j < 4; j++) {
            int gn = n0 + tx * 4 + j;
            float v = acc[i][j];
            if (mode == 0) v *= qscale;
            else if (mode == 2) v = 1.0f / (1.0f + expf(-(v + bg[gn - 768])));
            proj[(size_t)gm * 1024 + gn] = v;
        }
    }
}

// ---------------------------------------------------------------------------
// Kernel 2: q_tied[i][c] = mean_b q_scaled[b][i][c]
__global__ void qtied_kernel(const float* __restrict__ proj,
                             float* __restrict__ qt) {
    int idx = blockIdx.x * blockDim.x + threadIdx.x;  // 0..65535
    int i = idx >> 8;
    int c = idx & 255;
    float s = 0.f;
    for (int b = 0; b < NB; b++)
        s += proj[(size_t)(b * NN + i) * 1024 + c];
    qt[idx] = s * (1.0f / 64.0f);
}

// ---------------------------------------------------------------------------
// Kernel 3: attention. One block per (batch, head); one thread per query row.
// Online softmax; K/V tiles (64 rows) staged in LDS. Output *= gates.
__global__ __launch_bounds__(256) void attn_kernel(
    const float* __restrict__ proj, const float* __restrict__ qt,
    const float* __restrict__ bias, const int* __restrict__ mask,
    float* __restrict__ att) {
    const int b = blockIdx.x >> 3;
    const int h = blockIdx.x & 7;
    const int i = threadIdx.x;   // query row

    __shared__ float Ks[64][DH];
    __shared__ float Vs[64][DH];
    __shared__ int Ms[NN];

    Ms[i] = mask[b * NN + i];
    const int mask_i = mask[b * NN + i];

    float q[DH];
#pragma unroll
    for (int d = 0; d < DH; d += 4) {
        float4 qv = *(const float4*)(qt + (size_t)i * 256 + h * 32 + d);
        q[d] = qv.x; q[d + 1] = qv.y; q[d + 2] = qv.z; q[d + 3] = qv.w;
    }

    float m = -INFINITY, l = 0.f;
    float acc[DH] = {};
    const float* brow = bias + ((size_t)h * NN + i) * NN;

    for (int j0 = 0; j0 < NN; j0 += 64) {
        __syncthreads();
        {   // stage K/V tile: 64 rows x 32 cols; 4 threads per row, 8 floats each
            int row = threadIdx.x >> 2;
            int col = (threadIdx.x & 3) << 3;
            const float* src = proj + (size_t)(b * NN + j0 + row) * 1024 + h * 32 + col;
            float4 k0v = *(const float4*)(src + 256);
            float4 k1v = *(const float4*)(src + 256 + 4);
            float4 v0v = *(const float4*)(src + 512);
            float4 v1v = *(const float4*)(src + 512 + 4);
            *(float4*)&Ks[row][col] = k0v;
            *(float4*)&Ks[row][col + 4] = k1v;
            *(float4*)&Vs[row][col] = v0v;
            *(float4*)&Vs[row][col + 4] = v1v;
        }
        __syncthreads();

        for (int jj = 0; jj < 64; jj++) {
            int j = j0 + jj;
            float s;
            if (mask_i && Ms[j]) {
                float dot = 0.f;
#pragma unroll
                for (int d = 0; d < DH; d++) dot = fmaf(q[d], Ks[jj][d], dot);
                s = dot + brow[j];
            } else {
                s = NEG_MAX;
            }
            float mnew = fmaxf(m, s);
            float corr = __expf(m - mnew);
            float w = __expf(s - mnew);
            l = l * corr + w;
#pragma unroll
            for (int d = 0; d < DH; d++)
                acc[d] = acc[d] * corr + w * Vs[jj][d];
            m = mnew;
        }
    }

    float invl = 1.0f / l;
    const float* grow = proj + (size_t)(b * NN + i) * 1024 + 768 + h * 32;
    float* orow = att + (size_t)(b * NN + i) * 256 + h * 32;
#pragma unroll
    for (int d = 0; d < DH; d++) orow[d] = acc[d] * invl * grow[d];
}

// ---------------------------------------------------------------------------
// Kernel 4: out = att_gated @ Wo + bo   (16384 x 256) @ (256 x 256)
__global__ __launch_bounds__(256) void out_gemm(
    const float* __restrict__ A, const float* __restrict__ Wo,
    const float* __restrict__ bo, float* __restrict__ out) {
    __shared__ float As[16][64];
    __shared__ float Bs[16][64];
    const int tid = threadIdx.x;
    const int m0 = blockIdx.y * 64;
    const int n0 = blockIdx.x * 64;

    const int tx = tid & 15, ty = tid >> 4;
    const int arow = tid >> 2, acol = (tid & 3) << 2;
    const int brow = tid >> 4, bcol = (tid & 15) << 2;

    float acc[4][4] = {};

    for (int k0 = 0; k0 < 256; k0 += 16) {
        float4 av = *(const float4*)(A + (size_t)(m0 + arow) * 256 + k0 + acol);
        float4 bv = *(const float4*)(Wo + (size_t)(k0 + brow) * 256 + n0 + bcol);
        __syncthreads();
        As[acol + 0][arow] = av.x;
        As[acol + 1][arow] = av.y;
        As[acol + 2][arow] = av.z;
        As[acol + 3][arow] = av.w;
        *(float4*)(&Bs[brow][bcol]) = bv;
        __syncthreads();
#pragma unroll
        for (int kk = 0; kk < 16; kk++) {
            float a[4], bb[4];
#pragma unroll
            for (int i = 0; i < 4; i++) a[i] = As[kk][ty * 4 + i];
#pragma unroll
            for (int j = 0; j < 4; j++) bb[j] = Bs[kk][tx * 4 + j];
#pragma unroll
            for (int i = 0; i < 4; i++)
#pragma unroll
                for (int j = 0; j < 4; j++)
                    acc[i][j] = fmaf(a[i], bb[j], acc[i][j]);
        }
    }

#pragma unroll
    for (int i = 0; i < 4; i++) {
        int gm = m0 + ty * 4 + i;
#pragma unroll
        for (int j = 0; j < 4; j++) {
            int gn = n0 + tx * 4 + j;
            out[(size_t)gm * 256 + gn] = acc[i][j] + bo[gn];
        }
    }
}

// ---------------------------------------------------------------------------
extern "C" void kernel_launch(void* const* d_in, const int* in_sizes, int n_in,
                              void* d_out, int out_size, void* d_ws, size_t ws_size,
                              hipStream_t stream) {
    const float* x    = (const float*)d_in[0];
    const unsigned char* mraw = (const unsigned char*)d_in[1];
    const float* bias = (const float*)d_in[2];
    const float* Wq   = (const float*)d_in[3];
    const float* Wkv  = (const float*)d_in[4];
    const float* Wg   = (const float*)d_in[5];
    const float* bg   = (const float*)d_in[6];
    const float* Wo   = (const float*)d_in[7];
    const float* bo   = (const float*)d_in[8];

    float* ws    = (float*)d_ws;
    float* proj  = ws + OFF_PROJ;
    float* qt    = ws + OFF_QT;
    float* att   = ws + OFF_ATT;
    int*   maskc = (int*)(ws + OFF_MASK);

    hipLaunchKernelGGL(mask_canon_kernel, dim3(1), dim3(256), 0, stream, mraw, maskc);
    hipLaunchKernelGGL(proj_gemm, dim3(16, 256), dim3(256), 0, stream,
                       x, Wq, Wkv, Wg, bg, proj);
    hipLaunchKernelGGL(qtied_kernel, dim3(256), dim3(256), 0, stream, proj, qt);
    hipLaunchKernelGGL(attn_kernel, dim3(512), dim3(256), 0, stream,
                       proj, qt, bias, maskc, att);
    hipLaunchKernelGGL(out_gemm, dim3(4, 256), dim3(256), 0, stream,
                       att, Wo, bo, (float*)d_out);
}

// Round 3
// 264.204 us; speedup vs baseline: 1.0685x; 1.0685x over previous
//
#include <hip/hip_runtime.h>
#include <math.h>

typedef unsigned short ushort_t;
typedef unsigned int uint_t;
typedef __attribute__((ext_vector_type(8))) short short8v;   // 8 bf16 (4 VGPR)
typedef __attribute__((ext_vector_type(4))) float f32x4;

#define HEADS 8
#define DH 32
#define NB 64        // batch B
#define NN 256       // sequence N
#define ND 256       // model dim D (= K of all GEMMs)
#define NEG_MAX (-3.402823466e+38f)

// -------- ws layout (float offsets) --------
// proj  : [16384][768] fp32   cols 0-255 k | 256-511 v | 512-767 gates
// x_hi/x_lo : [16384][256] bf16 (ushort)  -- ALIASED by att_hi/att_lo after proj
// BT_hi/BT_lo : [1024][256] bf16  rows 0-511 WkvT | 512-767 WgT | 768-1023 WoT
// xbar  : [256][256] fp32 ; qt : [256][256] fp32 ; mask : [64][256] int
#define OFF_PROJ  0
#define OFF_XHI   12582912            // 16384*768
#define OFF_XLO   14680064            // +16384*256/2
#define OFF_ATTHI OFF_XHI
#define OFF_ATTLO OFF_XLO
#define OFF_BTHI  16777216
#define OFF_BTLO  16908288            // +1024*256/2
#define OFF_XBAR  17039360
#define OFF_QT    17104896
#define OFF_MASK  17170432

// ---------------------------------------------------------------------------
__device__ __forceinline__ ushort_t f2bf(float x) {
    uint_t u = __float_as_uint(x);
    u = (u + 0x7fffu + ((u >> 16) & 1u)) >> 16;   // RNE
    return (ushort_t)u;
}
__device__ __forceinline__ float bf2f(ushort_t u) {
    return __uint_as_float(((uint_t)u) << 16);
}
__device__ __forceinline__ void gl2lds16(const void* g, void* l) {
    typedef const __attribute__((address_space(1))) uint32_t* gptr_t;
    typedef __attribute__((address_space(3))) uint32_t* lptr_t;
    __builtin_amdgcn_global_load_lds((gptr_t)(uintptr_t)g,
                                     (lptr_t)(uintptr_t)l, 16, 0, 0);
}

// ---------------------------------------------------------------------------
// Kernel 0: canonicalize mask (bool-bytes or int32)
__global__ void mask_canon_kernel(const unsigned char* __restrict__ mraw,
                                  int* __restrict__ mout) {
    __shared__ int cnt[256];
    int tid = threadIdx.x;
    int c = 0;
    for (int i = tid; i < 4096; i += 256)
        if ((i & 3) != 0 && mraw[i] != 0) c++;
    cnt[tid] = c;
    __syncthreads();
    for (int s = 128; s > 0; s >>= 1) {
        if (tid < s) cnt[tid] += cnt[tid + s];
        __syncthreads();
    }
    int isBool = cnt[0] > 16;
    if (isBool) {
        for (int i = tid; i < NB * NN; i += 256) mout[i] = mraw[i] ? 1 : 0;
    } else {
        const int* mi = (const int*)mraw;
        for (int i = tid; i < NB * NN; i += 256) mout[i] = mi[i] ? 1 : 0;
    }
}

// ---------------------------------------------------------------------------
// Kernel 1: split x -> bf16 hi/lo
__global__ __launch_bounds__(256) void split_x_kernel(
    const float* __restrict__ x, ushort_t* __restrict__ xhi,
    ushort_t* __restrict__ xlo) {
    int idx = blockIdx.x * 256 + threadIdx.x;     // one float4 each
    float4 v = ((const float4*)x)[idx];
    ushort4 h, l;
    h.x = f2bf(v.x); l.x = f2bf(v.x - bf2f(h.x));
    h.y = f2bf(v.y); l.y = f2bf(v.y - bf2f(h.y));
    h.z = f2bf(v.z); l.z = f2bf(v.z - bf2f(h.z));
    h.w = f2bf(v.w); l.w = f2bf(v.w - bf2f(h.w));
    ((ushort4*)xhi)[idx] = h;
    ((ushort4*)xlo)[idx] = l;
}

// Kernel 2: xbar = mean over batch of x  (256x256)
__global__ __launch_bounds__(256) void xbar_kernel(const float* __restrict__ x,
                                                   float* __restrict__ xbar) {
    int idx = blockIdx.x * 256 + threadIdx.x;     // i*256+c
    float s = 0.f;
    for (int b = 0; b < NB; b++) s += x[(size_t)b * 65536 + idx];
    xbar[idx] = s * (1.0f / 64.0f);
}

// Kernel 3: build transposed+split weights BT[n][k] (n: 0-511 Wkv, 512-767 Wg,
// 768-1023 Wo)
__global__ __launch_bounds__(256) void wsplit_kernel(
    const float* __restrict__ Wkv, const float* __restrict__ Wg,
    const float* __restrict__ Wo, ushort_t* __restrict__ bthi,
    ushort_t* __restrict__ btlo) {
    int idx = blockIdx.x * 256 + threadIdx.x;     // 0..262143
    int n = idx >> 8, k = idx & 255;
    float v;
    if (n < 512)      v = Wkv[(size_t)k * 512 + n];
    else if (n < 768) v = Wg[(size_t)k * 256 + (n - 512)];
    else              v = Wo[(size_t)k * 256 + (n - 768)];
    ushort_t h = f2bf(v);
    bthi[idx] = h;
    btlo[idx] = f2bf(v - bf2f(h));
}

// Kernel 4: qt = xbar @ Wq * scale  (256x256x256, fp32, tiny)
__global__ __launch_bounds__(256) void qt_gemm(const float* __restrict__ xbar,
                                               const float* __restrict__ Wq,
                                               float* __restrict__ qt) {
    __shared__ float xrow[256];
    int i = blockIdx.x, t = threadIdx.x;
    xrow[t] = xbar[i * 256 + t];
    __syncthreads();
    float s = 0.f;
    for (int k = 0; k < 256; k++) s = fmaf(xrow[k], Wq[(size_t)k * 256 + t], s);
    qt[i * 256 + t] = s * 0.17677669529663687f;   // 1/sqrt(32)
}

// ---------------------------------------------------------------------------
// MFMA split-bf16 GEMM: C[M,768 or 256] = A[M,256] @ B  (B given as BT[n][k]).
// 128x128 tile, BK=32, 256 threads (4 waves, 2x2), 4x4 16x16x32 frags/wave.
// EPI 0: proj epilogue (sigmoid for gc>=512 w/ bias=bg), ldc=768
// EPI 1: out epilogue (+bias=bo), ldc=256
template <int EPI>
__global__ __launch_bounds__(256) void mfma_gemm(
    const ushort_t* __restrict__ Ahi, const ushort_t* __restrict__ Alo,
    const ushort_t* __restrict__ Bthi, const ushort_t* __restrict__ Btlo,
    const float* __restrict__ bias, float* __restrict__ C) {
    __shared__ ushort_t Ah[4096], Al[4096], Bh[4096], Bl[4096];  // [128][32]
    const int t = threadIdx.x;
    const int m0 = blockIdx.y * 128;
    const int n0 = blockIdx.x * 128;
    const int wid = t >> 6, lane = t & 63;
    const int wr = wid >> 1, wc = wid & 1;
    const int lr = lane & 15, lg = lane >> 4;

    f32x4 acc[4][4] = {};

    for (int ks = 0; ks < 8; ++ks) {
        const int k0 = ks * 32;
#pragma unroll
        for (int it = 0; it < 2; ++it) {
            int c = t + it * 256;                 // 0..511
            int row = c >> 2, sub = c & 3;
            size_t ga = (size_t)(m0 + row) * 256 + k0 + sub * 8;
            size_t gb = (size_t)(n0 + row) * 256 + k0 + sub * 8;
            gl2lds16(Ahi + ga, (char*)Ah + c * 16);
            gl2lds16(Alo + ga, (char*)Al + c * 16);
            gl2lds16(Bthi + gb, (char*)Bh + c * 16);
            gl2lds16(Btlo + gb, (char*)Bl + c * 16);
        }
        __syncthreads();

        short8v ah[4], al[4], bh[4], bl[4];
#pragma unroll
        for (int m = 0; m < 4; m++) {
            int off = (wr * 64 + m * 16 + lr) * 32 + lg * 8;
            ah[m] = *(const short8v*)&Ah[off];
            al[m] = *(const short8v*)&Al[off];
        }
#pragma unroll
        for (int n = 0; n < 4; n++) {
            int off = (wc * 64 + n * 16 + lr) * 32 + lg * 8;
            bh[n] = *(const short8v*)&Bh[off];
            bl[n] = *(const short8v*)&Bl[off];
        }
#pragma unroll
        for (int m = 0; m < 4; m++)
#pragma unroll
            for (int n = 0; n < 4; n++) {
                acc[m][n] = __builtin_amdgcn_mfma_f32_16x16x32_bf16(
                    ah[m], bh[n], acc[m][n], 0, 0, 0);
                acc[m][n] = __builtin_amdgcn_mfma_f32_16x16x32_bf16(
                    ah[m], bl[n], acc[m][n], 0, 0, 0);
                acc[m][n] = __builtin_amdgcn_mfma_f32_16x16x32_bf16(
                    al[m], bh[n], acc[m][n], 0, 0, 0);
            }
        __syncthreads();
    }

#pragma unroll
    for (int m = 0; m < 4; m++)
#pragma unroll
        for (int n = 0; n < 4; n++) {
            int gr0 = m0 + wr * 64 + m * 16 + lg * 4;
            int gc = n0 + wc * 64 + n * 16 + lr;
#pragma unroll
            for (int r = 0; r < 4; r++) {
                float v = acc[m][n][r];
                int gr = gr0 + r;
                if (EPI == 0) {
                    if (gc >= 512) v = 1.f / (1.f + __expf(-(v + bias[gc - 512])));
                    C[(size_t)gr * 768 + gc] = v;
                } else {
                    C[(size_t)gr * 256 + gc] = v + bias[gc];
                }
            }
        }
}

// ---------------------------------------------------------------------------
// Kernel: attention (fp32). Block per (b,h); thread per query row.
// Two-pass per 32-key tile: scores -> tile max -> single rescale + PV.
__global__ __launch_bounds__(256) void attn_kernel(
    const float* __restrict__ proj, const float* __restrict__ qt,
    const float* __restrict__ bias, const int* __restrict__ mask,
    ushort_t* __restrict__ atthi, ushort_t* __restrict__ attlo) {
    const int b = blockIdx.x >> 3;
    const int h = blockIdx.x & 7;
    const int i = threadIdx.x;

    __shared__ float Ks[32][36];
    __shared__ float Vs[32][36];
    __shared__ int Ms[NN];

    Ms[i] = mask[b * NN + i];
    __syncthreads();
    const int my_mask = mask[b * NN + i];

    float q[DH];
#pragma unroll
    for (int c = 0; c < 8; c++) {
        float4 qv = *(const float4*)(qt + (size_t)i * 256 + h * 32 + c * 4);
        q[4 * c] = qv.x; q[4 * c + 1] = qv.y; q[4 * c + 2] = qv.z; q[4 * c + 3] = qv.w;
    }

    float m = -INFINITY, l = 0.f;
    float acc[DH] = {};
    const float* brow = bias + ((size_t)h * NN + i) * NN;

    for (int j0 = 0; j0 < NN; j0 += 32) {
        __syncthreads();
        {   // stage 32x32 K and V tiles
            int row = threadIdx.x >> 3;
            int col = (threadIdx.x & 7) << 2;
            const float* src = proj + (size_t)(b * NN + j0 + row) * 768 + h * 32 + col;
            float4 kv = *(const float4*)(src);
            float4 vv = *(const float4*)(src + 256);
            *(float4*)&Ks[row][col] = kv;
            *(float4*)&Vs[row][col] = vv;
        }
        __syncthreads();

        float s[32];
#pragma unroll 4
        for (int jj = 0; jj < 32; ++jj) {
            if (my_mask && Ms[j0 + jj]) {
                const float4* kr = (const float4*)&Ks[jj][0];
                float d0 = 0.f, d1 = 0.f, d2 = 0.f, d3 = 0.f;
#pragma unroll
                for (int c = 0; c < 8; c += 4) {
                    float4 k0v = kr[c], k1v = kr[c + 1], k2v = kr[c + 2], k3v = kr[c + 3];
                    d0 = fmaf(q[4 * c + 0], k0v.x, d0); d0 = fmaf(q[4 * c + 1], k0v.y, d0);
                    d0 = fmaf(q[4 * c + 2], k0v.z, d0); d0 = fmaf(q[4 * c + 3], k0v.w, d0);
                    d1 = fmaf(q[4 * c + 4], k1v.x, d1); d1 = fmaf(q[4 * c + 5], k1v.y, d1);
                    d1 = fmaf(q[4 * c + 6], k1v.z, d1); d1 = fmaf(q[4 * c + 7], k1v.w, d1);
                    d2 = fmaf(q[4 * c + 8], k2v.x, d2); d2 = fmaf(q[4 * c + 9], k2v.y, d2);
                    d2 = fmaf(q[4 * c + 10], k2v.z, d2); d2 = fmaf(q[4 * c + 11], k2v.w, d2);
                    d3 = fmaf(q[4 * c + 12], k3v.x, d3); d3 = fmaf(q[4 * c + 13], k3v.y, d3);
                    d3 = fmaf(q[4 * c + 14], k3v.z, d3); d3 = fmaf(q[4 * c + 15], k3v.w, d3);
                }
                s[jj] = (d0 + d1) + (d2 + d3) + brow[j0 + jj];
            } else {
                s[jj] = NEG_MAX;
            }
        }

        float tmax = s[0];
#pragma unroll
        for (int jj = 1; jj < 32; ++jj) tmax = fmaxf(tmax, s[jj]);
        float mnew = fmaxf(m, tmax);
        float corr = __expf(m - mnew);    // m=-inf first tile -> 0
        l *= corr;
#pragma unroll
        for (int d = 0; d < DH; d++) acc[d] *= corr;
#pragma unroll 4
        for (int jj = 0; jj < 32; ++jj) {
            float w = __expf(s[jj] - mnew);
            l += w;
            const float4* vr = (const float4*)&Vs[jj][0];
#pragma unroll
            for (int c = 0; c < 8; ++c) {
                float4 vv = vr[c];
                acc[4 * c + 0] = fmaf(w, vv.x, acc[4 * c + 0]);
                acc[4 * c + 1] = fmaf(w, vv.y, acc[4 * c + 1]);
                acc[4 * c + 2] = fmaf(w, vv.z, acc[4 * c + 2]);
                acc[4 * c + 3] = fmaf(w, vv.w, acc[4 * c + 3]);
            }
        }
        m = mnew;
    }

    float invl = 1.0f / l;
    const float* grow = proj + (size_t)(b * NN + i) * 768 + 512 + h * 32;
    ushort_t* oh = atthi + ((size_t)(b * NN + i) * 256 + h * 32);
    ushort_t* ol = attlo + ((size_t)(b * NN + i) * 256 + h * 32);
#pragma unroll
    for (int c = 0; c < 8; c++) {
        float4 gv = *(const float4*)(grow + 4 * c);
        float v0 = acc[4 * c + 0] * invl * gv.x;
        float v1 = acc[4 * c + 1] * invl * gv.y;
        float v2 = acc[4 * c + 2] * invl * gv.z;
        float v3 = acc[4 * c + 3] * invl * gv.w;
        ushort4 hh, ll;
        hh.x = f2bf(v0); ll.x = f2bf(v0 - bf2f(hh.x));
        hh.y = f2bf(v1); ll.y = f2bf(v1 - bf2f(hh.y));
        hh.z = f2bf(v2); ll.z = f2bf(v2 - bf2f(hh.z));
        hh.w = f2bf(v3); ll.w = f2bf(v3 - bf2f(hh.w));
        ((ushort4*)oh)[c] = hh;
        ((ushort4*)ol)[c] = ll;
    }
}

// ---------------------------------------------------------------------------
extern "C" void kernel_launch(void* const* d_in, const int* in_sizes, int n_in,
                              void* d_out, int out_size, void* d_ws, size_t ws_size,
                              hipStream_t stream) {
    const float* x    = (const float*)d_in[0];
    const unsigned char* mraw = (const unsigned char*)d_in[1];
    const float* bias = (const float*)d_in[2];
    const float* Wq   = (const float*)d_in[3];
    const float* Wkv  = (const float*)d_in[4];
    const float* Wg   = (const float*)d_in[5];
    const float* bg   = (const float*)d_in[6];
    const float* Wo   = (const float*)d_in[7];
    const float* bo   = (const float*)d_in[8];

    float* ws = (float*)d_ws;
    float*    proj  = ws + OFF_PROJ;
    ushort_t* xhi   = (ushort_t*)(ws + OFF_XHI);
    ushort_t* xlo   = (ushort_t*)(ws + OFF_XLO);
    ushort_t* atthi = (ushort_t*)(ws + OFF_ATTHI);   // aliases xhi (dead by then)
    ushort_t* attlo = (ushort_t*)(ws + OFF_ATTLO);
    ushort_t* bthi  = (ushort_t*)(ws + OFF_BTHI);
    ushort_t* btlo  = (ushort_t*)(ws + OFF_BTLO);
    float*    xbar  = ws + OFF_XBAR;
    float*    qt    = ws + OFF_QT;
    int*      maskc = (int*)(ws + OFF_MASK);

    hipLaunchKernelGGL(mask_canon_kernel, dim3(1), dim3(256), 0, stream, mraw, maskc);
    hipLaunchKernelGGL(split_x_kernel, dim3(4096), dim3(256), 0, stream, x, xhi, xlo);
    hipLaunchKernelGGL(xbar_kernel, dim3(256), dim3(256), 0, stream, x, xbar);
    hipLaunchKernelGGL(wsplit_kernel, dim3(1024), dim3(256), 0, stream,
                       Wkv, Wg, Wo, bthi, btlo);
    hipLaunchKernelGGL(qt_gemm, dim3(256), dim3(256), 0, stream, xbar, Wq, qt);
    // proj = x @ [Wkv|Wg] : M=16384, N=768
    hipLaunchKernelGGL((mfma_gemm<0>), dim3(6, 128), dim3(256), 0, stream,
                       xhi, xlo, bthi, btlo, bg, proj);
    hipLaunchKernelGGL(attn_kernel, dim3(512), dim3(256), 0, stream,
                       proj, qt, bias, maskc, atthi, attlo);
    // out = att @ Wo + bo : M=16384, N=256 (BT rows 768..1023)
    hipLaunchKernelGGL((mfma_gemm<1>), dim3(2, 128), dim3(256), 0, stream,
                       atthi, attlo, bthi + 768 * 256, btlo + 768 * 256, bo,
                       (float*)d_out);
}

// Round 4
// 217.151 us; speedup vs baseline: 1.3000x; 1.2167x over previous
//
#include <hip/hip_runtime.h>
#include <math.h>

typedef unsigned short ushort_t;
typedef unsigned int uint_t;
typedef __attribute__((ext_vector_type(8))) short short8v;   // 8 bf16 (4 VGPR)
typedef __attribute__((ext_vector_type(4))) float f32x4;

#define HEADS 8
#define DH 32
#define NB 64        // batch B
#define NN 256       // sequence N
#define ND 256       // model dim D (= K of all GEMMs)
#define NEG_MAX (-3.402823466e+38f)

// -------- ws layout (float offsets) --------
// kh/kl   : [16384][256] ushort  (K, bf16 hi/lo, row=(b,j), col=h*32+d)
// vth/vtl : [64][8][32][256] ushort (V transposed: [b][h][d][j])
// gates   : [16384][256] fp32
// xhi/xlo : [16384][256] ushort  -- ALIASED by att_hi/att_lo after proj
// bthi/btlo: [1024][256] ushort  rows 0-511 WkvT | 512-767 WgT | 768-1023 WoT
// qth/qtl : [256][256] ushort ; xbar [256][256] f32 ; mask [64][256] int
#define OFF_KH    0
#define OFF_KL    2097152
#define OFF_VTH   4194304
#define OFF_VTL   6291456
#define OFF_GATES 8388608
#define OFF_XHI   12582912
#define OFF_XLO   14680064
#define OFF_ATTHI OFF_XHI
#define OFF_ATTLO OFF_XLO
#define OFF_BTHI  16777216
#define OFF_BTLO  16908288
#define OFF_QTH   17039360
#define OFF_QTL   17072128
#define OFF_XBAR  17104896
#define OFF_MASK  17170432

// ---------------------------------------------------------------------------
__device__ __forceinline__ ushort_t f2bf(float x) {
    uint_t u = __float_as_uint(x);
    u = (u + 0x7fffu + ((u >> 16) & 1u)) >> 16;   // RNE
    return (ushort_t)u;
}
__device__ __forceinline__ float bf2f(ushort_t u) {
    return __uint_as_float(((uint_t)u) << 16);
}
__device__ __forceinline__ void gl2lds16(const void* g, void* l) {
    typedef const __attribute__((address_space(1))) uint32_t* gptr_t;
    typedef __attribute__((address_space(3))) uint32_t* lptr_t;
    __builtin_amdgcn_global_load_lds((gptr_t)(uintptr_t)g,
                                     (lptr_t)(uintptr_t)l, 16, 0, 0);
}

// ---------------------------------------------------------------------------
// Kernel 0: canonicalize mask (bool-bytes or int32)
__global__ void mask_canon_kernel(const unsigned char* __restrict__ mraw,
                                  int* __restrict__ mout) {
    __shared__ int cnt[256];
    int tid = threadIdx.x;
    int c = 0;
    for (int i = tid; i < 4096; i += 256)
        if ((i & 3) != 0 && mraw[i] != 0) c++;
    cnt[tid] = c;
    __syncthreads();
    for (int s = 128; s > 0; s >>= 1) {
        if (tid < s) cnt[tid] += cnt[tid + s];
        __syncthreads();
    }
    int isBool = cnt[0] > 16;
    if (isBool) {
        for (int i = tid; i < NB * NN; i += 256) mout[i] = mraw[i] ? 1 : 0;
    } else {
        const int* mi = (const int*)mraw;
        for (int i = tid; i < NB * NN; i += 256) mout[i] = mi[i] ? 1 : 0;
    }
}

// ---------------------------------------------------------------------------
// Kernel 1: split x -> bf16 hi/lo
__global__ __launch_bounds__(256) void split_x_kernel(
    const float* __restrict__ x, ushort_t* __restrict__ xhi,
    ushort_t* __restrict__ xlo) {
    int idx = blockIdx.x * 256 + threadIdx.x;     // one float4 each
    float4 v = ((const float4*)x)[idx];
    ushort4 h, l;
    h.x = f2bf(v.x); l.x = f2bf(v.x - bf2f(h.x));
    h.y = f2bf(v.y); l.y = f2bf(v.y - bf2f(h.y));
    h.z = f2bf(v.z); l.z = f2bf(v.z - bf2f(h.z));
    h.w = f2bf(v.w); l.w = f2bf(v.w - bf2f(h.w));
    ((ushort4*)xhi)[idx] = h;
    ((ushort4*)xlo)[idx] = l;
}

// Kernel 2: xbar = mean over batch of x  (256x256)
__global__ __launch_bounds__(256) void xbar_kernel(const float* __restrict__ x,
                                                   float* __restrict__ xbar) {
    int idx = blockIdx.x * 256 + threadIdx.x;
    float s = 0.f;
    for (int b = 0; b < NB; b++) s += x[(size_t)b * 65536 + idx];
    xbar[idx] = s * (1.0f / 64.0f);
}

// Kernel 3: build transposed+split weights BT[n][k]
__global__ __launch_bounds__(256) void wsplit_kernel(
    const float* __restrict__ Wkv, const float* __restrict__ Wg,
    const float* __restrict__ Wo, ushort_t* __restrict__ bthi,
    ushort_t* __restrict__ btlo) {
    int idx = blockIdx.x * 256 + threadIdx.x;     // 0..262143
    int n = idx >> 8, k = idx & 255;
    float v;
    if (n < 512)      v = Wkv[(size_t)k * 512 + n];
    else if (n < 768) v = Wg[(size_t)k * 256 + (n - 512)];
    else              v = Wo[(size_t)k * 256 + (n - 768)];
    ushort_t h = f2bf(v);
    bthi[idx] = h;
    btlo[idx] = f2bf(v - bf2f(h));
}

// Kernel 4: qt = xbar @ Wq * scale, output split bf16
__global__ __launch_bounds__(256) void qt_gemm(const float* __restrict__ xbar,
                                               const float* __restrict__ Wq,
                                               ushort_t* __restrict__ qth,
                                               ushort_t* __restrict__ qtl) {
    __shared__ float xrow[256];
    int i = blockIdx.x, t = threadIdx.x;
    xrow[t] = xbar[i * 256 + t];
    __syncthreads();
    float s = 0.f;
    for (int k = 0; k < 256; k++) s = fmaf(xrow[k], Wq[(size_t)k * 256 + t], s);
    s *= 0.17677669529663687f;   // 1/sqrt(32)
    ushort_t h = f2bf(s);
    qth[i * 256 + t] = h;
    qtl[i * 256 + t] = f2bf(s - bf2f(h));
}

// ---------------------------------------------------------------------------
// MFMA split-bf16 GEMM. EPI 0: proj (writes kh/kl, vth/vtl transposed, gates)
//                       EPI 1: out (C = acc + bias)
template <int EPI>
__global__ __launch_bounds__(256) void mfma_gemm(
    const ushort_t* __restrict__ Ahi, const ushort_t* __restrict__ Alo,
    const ushort_t* __restrict__ Bthi, const ushort_t* __restrict__ Btlo,
    const float* __restrict__ bias, float* __restrict__ C,
    ushort_t* __restrict__ kh, ushort_t* __restrict__ kl,
    ushort_t* __restrict__ vth, ushort_t* __restrict__ vtl,
    float* __restrict__ gates) {
    __shared__ ushort_t Ah[4096], Al[4096], Bh[4096], Bl[4096];  // [128][32]
    const int t = threadIdx.x;
    const int m0 = blockIdx.y * 128;
    const int n0 = blockIdx.x * 128;
    const int wid = t >> 6, lane = t & 63;
    const int wr = wid >> 1, wc = wid & 1;
    const int lr = lane & 15, lg = lane >> 4;

    f32x4 acc[4][4] = {};

    for (int ks = 0; ks < 8; ++ks) {
        const int k0 = ks * 32;
#pragma unroll
        for (int it = 0; it < 2; ++it) {
            int c = t + it * 256;                 // 0..511
            int row = c >> 2, sub = c & 3;
            size_t ga = (size_t)(m0 + row) * 256 + k0 + sub * 8;
            size_t gb = (size_t)(n0 + row) * 256 + k0 + sub * 8;
            gl2lds16(Ahi + ga, (char*)Ah + c * 16);
            gl2lds16(Alo + ga, (char*)Al + c * 16);
            gl2lds16(Bthi + gb, (char*)Bh + c * 16);
            gl2lds16(Btlo + gb, (char*)Bl + c * 16);
        }
        __syncthreads();

        short8v ah[4], al[4], bh[4], bl[4];
#pragma unroll
        for (int m = 0; m < 4; m++) {
            int off = (wr * 64 + m * 16 + lr) * 32 + lg * 8;
            ah[m] = *(const short8v*)&Ah[off];
            al[m] = *(const short8v*)&Al[off];
        }
#pragma unroll
        for (int n = 0; n < 4; n++) {
            int off = (wc * 64 + n * 16 + lr) * 32 + lg * 8;
            bh[n] = *(const short8v*)&Bh[off];
            bl[n] = *(const short8v*)&Bl[off];
        }
#pragma unroll
        for (int m = 0; m < 4; m++)
#pragma unroll
            for (int n = 0; n < 4; n++) {
                acc[m][n] = __builtin_amdgcn_mfma_f32_16x16x32_bf16(
                    ah[m], bh[n], acc[m][n], 0, 0, 0);
                acc[m][n] = __builtin_amdgcn_mfma_f32_16x16x32_bf16(
                    ah[m], bl[n], acc[m][n], 0, 0, 0);
                acc[m][n] = __builtin_amdgcn_mfma_f32_16x16x32_bf16(
                    al[m], bh[n], acc[m][n], 0, 0, 0);
            }
        __syncthreads();
    }

#pragma unroll
    for (int m = 0; m < 4; m++)
#pragma unroll
        for (int n = 0; n < 4; n++) {
            int gr0 = m0 + wr * 64 + m * 16 + lg * 4;
            int gc = n0 + wc * 64 + n * 16 + lr;
#pragma unroll
            for (int r = 0; r < 4; r++) {
                float v = acc[m][n][r];
                int gr = gr0 + r;
                if (EPI == 0) {
                    if (gc < 256) {
                        ushort_t hh = f2bf(v);
                        kh[(size_t)gr * 256 + gc] = hh;
                        kl[(size_t)gr * 256 + gc] = f2bf(v - bf2f(hh));
                    } else if (gc < 512) {
                        int cc = gc - 256;
                        size_t idx = (((size_t)(gr >> 8) * 8 + (cc >> 5)) * 32 +
                                      (cc & 31)) * 256 + (gr & 255);
                        ushort_t hh = f2bf(v);
                        vth[idx] = hh;
                        vtl[idx] = f2bf(v - bf2f(hh));
                    } else {
                        float g = 1.f / (1.f + __expf(-(v + bias[gc - 512])));
                        gates[(size_t)gr * 256 + (gc - 512)] = g;
                    }
                } else {
                    C[(size_t)gr * 256 + gc] = v + bias[gc];
                }
            }
        }
}

// ---------------------------------------------------------------------------
// MFMA flash attention. Block = (b,h), 4 waves x 64 q-rows, KV tiles of 64.
// S^T = K*Q^T (i in lane&15), softmax stats per-lane, PV as O^T = V^T * P^T.
__global__ __launch_bounds__(256) void attn_mfma_kernel(
    const ushort_t* __restrict__ qth, const ushort_t* __restrict__ qtl,
    const ushort_t* __restrict__ kh, const ushort_t* __restrict__ kl,
    const ushort_t* __restrict__ vth, const ushort_t* __restrict__ vtl,
    const float* __restrict__ gates, const float* __restrict__ bias,
    const int* __restrict__ mask,
    ushort_t* __restrict__ atthi, ushort_t* __restrict__ attlo) {
    const int b = blockIdx.x >> 3;
    const int h = blockIdx.x & 7;
    const int t = threadIdx.x;
    const int wid = t >> 6;
    const int lane = t & 63;
    const int lr = lane & 15, lg = lane >> 4;
    const int i0 = wid * 64;

    // per-wave P^T staging: [64 i][40 j-pad] ushort, hi & lo (rows 80B: 16B-
    // aligned for b128, 20-dword stride -> 2-way banks = free)
    __shared__ ushort_t PbH[4][64 * 40];
    __shared__ ushort_t PbL[4][64 * 40];
    ushort_t* pbh = PbH[wid];
    ushort_t* pbl = PbL[wid];

    // Q fragments (B-operand), nf indexes 16-i groups
    short8v qfh[4], qfl[4];
#pragma unroll
    for (int nf = 0; nf < 4; nf++) {
        size_t off = (size_t)(i0 + nf * 16 + lr) * 256 + h * 32 + lg * 8;
        qfh[nf] = *(const short8v*)(qth + off);
        qfl[nf] = *(const short8v*)(qtl + off);
    }
    int mi[4];
#pragma unroll
    for (int nf = 0; nf < 4; nf++)
        mi[nf] = mask[b * 256 + i0 + nf * 16 + lr];

    float m_run[4], l_run[4];
#pragma unroll
    for (int nf = 0; nf < 4; nf++) { m_run[nf] = NEG_MAX; l_run[nf] = 0.f; }
    f32x4 acc_o[2][4] = {};   // [mf_d][nf]: row d=mf_d*16+lg*4+r, col i

    for (int tile = 0; tile < 4; ++tile) {
        const int j0 = tile * 64;

        // K fragments (A-operand)
        short8v kfh[4], kfl[4];
#pragma unroll
        for (int mf = 0; mf < 4; mf++) {
            size_t off = (size_t)(b * 256 + j0 + mf * 16 + lr) * 256 + h * 32 + lg * 8;
            kfh[mf] = *(const short8v*)(kh + off);
            kfl[mf] = *(const short8v*)(kl + off);
        }
        // mask_j for this lane's rows: j = j0 + mf*16 + lg*4 + r
        int4 mj[4];
#pragma unroll
        for (int mf = 0; mf < 4; mf++)
            mj[mf] = *(const int4*)(mask + b * 256 + j0 + mf * 16 + lg * 4);

        // S^T = K * Q^T  (3-term split)
        f32x4 s[4][4];
#pragma unroll
        for (int mf = 0; mf < 4; mf++)
#pragma unroll
            for (int nf = 0; nf < 4; nf++) {
                f32x4 a = {};
                a = __builtin_amdgcn_mfma_f32_16x16x32_bf16(kfh[mf], qfh[nf], a, 0, 0, 0);
                a = __builtin_amdgcn_mfma_f32_16x16x32_bf16(kfh[mf], qfl[nf], a, 0, 0, 0);
                a = __builtin_amdgcn_mfma_f32_16x16x32_bf16(kfl[mf], qfh[nf], a, 0, 0, 0);
                s[mf][nf] = a;
            }

        // bias + mask
#pragma unroll
        for (int nf = 0; nf < 4; nf++) {
            int i = i0 + nf * 16 + lr;
            const float* bp = bias + ((size_t)h * 256 + i) * 256 + j0 + lg * 4;
#pragma unroll
            for (int mf = 0; mf < 4; mf++) {
                float4 bv = *(const float4*)(bp + mf * 16);
                int okn = mi[nf];
                s[mf][nf][0] = (okn && mj[mf].x) ? s[mf][nf][0] + bv.x : NEG_MAX;
                s[mf][nf][1] = (okn && mj[mf].y) ? s[mf][nf][1] + bv.y : NEG_MAX;
                s[mf][nf][2] = (okn && mj[mf].z) ? s[mf][nf][2] + bv.z : NEG_MAX;
                s[mf][nf][3] = (okn && mj[mf].w) ? s[mf][nf][3] + bv.w : NEG_MAX;
            }
        }

        // row max over j (in-lane 16 vals, then lanes ^16, ^32)
        float corr[4], mnew[4];
#pragma unroll
        for (int nf = 0; nf < 4; nf++) {
            float tm = s[0][nf][0];
#pragma unroll
            for (int mf = 0; mf < 4; mf++)
#pragma unroll
                for (int r = 0; r < 4; r++) tm = fmaxf(tm, s[mf][nf][r]);
            tm = fmaxf(tm, __shfl_xor(tm, 16));
            tm = fmaxf(tm, __shfl_xor(tm, 32));
            float mn = fmaxf(m_run[nf], tm);
            corr[nf] = __expf(m_run[nf] - mn);
            m_run[nf] = mn;
            mnew[nf] = mn;
        }
#pragma unroll
        for (int mf = 0; mf < 2; mf++)
#pragma unroll
            for (int nf = 0; nf < 4; nf++)
#pragma unroll
                for (int r = 0; r < 4; r++) acc_o[mf][nf][r] *= corr[nf];

        // w = exp(s - mnew), row sums
        float lsum[4] = {0.f, 0.f, 0.f, 0.f};
#pragma unroll
        for (int nf = 0; nf < 4; nf++) {
#pragma unroll
            for (int mf = 0; mf < 4; mf++)
#pragma unroll
                for (int r = 0; r < 4; r++) {
                    float w = __expf(s[mf][nf][r] - mnew[nf]);
                    s[mf][nf][r] = w;
                    lsum[nf] += w;
                }
            lsum[nf] += __shfl_xor(lsum[nf], 16);
            lsum[nf] += __shfl_xor(lsum[nf], 32);
            l_run[nf] = l_run[nf] * corr[nf] + lsum[nf];
        }

        // two 32-key halves: split P -> LDS, then PV MFMAs
#pragma unroll
        for (int hb = 0; hb < 2; ++hb) {
#pragma unroll
            for (int mq = 0; mq < 2; mq++) {
                int mf = hb * 2 + mq;
#pragma unroll
                for (int nf = 0; nf < 4; nf++) {
                    ushort_t h0 = f2bf(s[mf][nf][0]), h1 = f2bf(s[mf][nf][1]);
                    ushort_t h2 = f2bf(s[mf][nf][2]), h3 = f2bf(s[mf][nf][3]);
                    uint2 hv, lv;
                    hv.x = (uint_t)h0 | ((uint_t)h1 << 16);
                    hv.y = (uint_t)h2 | ((uint_t)h3 << 16);
                    lv.x = (uint_t)f2bf(s[mf][nf][0] - bf2f(h0)) |
                           ((uint_t)f2bf(s[mf][nf][1] - bf2f(h1)) << 16);
                    lv.y = (uint_t)f2bf(s[mf][nf][2] - bf2f(h2)) |
                           ((uint_t)f2bf(s[mf][nf][3] - bf2f(h3)) << 16);
                    int ad = (nf * 16 + lr) * 40 + mq * 16 + lg * 4;
                    *(uint2*)(pbh + ad) = hv;
                    *(uint2*)(pbl + ad) = lv;
                }
            }
            asm volatile("s_waitcnt lgkmcnt(0)" ::: "memory");

            // V^T fragments (A-operand): d = mf_d*16+lr, j = j0+hb*32+lg*8
            short8v vfh[2], vfl[2];
#pragma unroll
            for (int mf = 0; mf < 2; mf++) {
                size_t off = ((size_t)(b * 8 + h) * 32 + mf * 16 + lr) * 256 +
                             j0 + hb * 32 + lg * 8;
                vfh[mf] = *(const short8v*)(vth + off);
                vfl[mf] = *(const short8v*)(vtl + off);
            }
#pragma unroll
            for (int nf = 0; nf < 4; nf++) {
                int ad = (nf * 16 + lr) * 40 + lg * 8;
                short8v ph = *(const short8v*)(pbh + ad);
                short8v pl = *(const short8v*)(pbl + ad);
#pragma unroll
                for (int mf = 0; mf < 2; mf++) {
                    acc_o[mf][nf] = __builtin_amdgcn_mfma_f32_16x16x32_bf16(
                        vfh[mf], ph, acc_o[mf][nf], 0, 0, 0);
                    acc_o[mf][nf] = __builtin_amdgcn_mfma_f32_16x16x32_bf16(
                        vfh[mf], pl, acc_o[mf][nf], 0, 0, 0);
                    acc_o[mf][nf] = __builtin_amdgcn_mfma_f32_16x16x32_bf16(
                        vfl[mf], ph, acc_o[mf][nf], 0, 0, 0);
                }
            }
        }
    }

    // epilogue: O = acc_o / l * gate, split bf16, write
    float invl[4];
#pragma unroll
    for (int nf = 0; nf < 4; nf++) invl[nf] = 1.0f / l_run[nf];
#pragma unroll
    for (int mf = 0; mf < 2; mf++)
#pragma unroll
        for (int nf = 0; nf < 4; nf++) {
            int i = i0 + nf * 16 + lr;
            int d0 = mf * 16 + lg * 4;
            size_t base = ((size_t)(b * 256 + i)) * 256 + h * 32 + d0;
            float4 gv = *(const float4*)(gates + base);
            float v0 = acc_o[mf][nf][0] * invl[nf] * gv.x;
            float v1 = acc_o[mf][nf][1] * invl[nf] * gv.y;
            float v2 = acc_o[mf][nf][2] * invl[nf] * gv.z;
            float v3 = acc_o[mf][nf][3] * invl[nf] * gv.w;
            ushort4 hh, ll;
            hh.x = f2bf(v0); ll.x = f2bf(v0 - bf2f(hh.x));
            hh.y = f2bf(v1); ll.y = f2bf(v1 - bf2f(hh.y));
            hh.z = f2bf(v2); ll.z = f2bf(v2 - bf2f(hh.z));
            hh.w = f2bf(v3); ll.w = f2bf(v3 - bf2f(hh.w));
            *(ushort4*)(atthi + base) = hh;
            *(ushort4*)(attlo + base) = ll;
        }
}

// ---------------------------------------------------------------------------
extern "C" void kernel_launch(void* const* d_in, const int* in_sizes, int n_in,
                              void* d_out, int out_size, void* d_ws, size_t ws_size,
                              hipStream_t stream) {
    const float* x    = (const float*)d_in[0];
    const unsigned char* mraw = (const unsigned char*)d_in[1];
    const float* bias = (const float*)d_in[2];
    const float* Wq   = (const float*)d_in[3];
    const float* Wkv  = (const float*)d_in[4];
    const float* Wg   = (const float*)d_in[5];
    const float* bg   = (const float*)d_in[6];
    const float* Wo   = (const float*)d_in[7];
    const float* bo   = (const float*)d_in[8];

    float* ws = (float*)d_ws;
    ushort_t* kh    = (ushort_t*)(ws + OFF_KH);
    ushort_t* kl    = (ushort_t*)(ws + OFF_KL);
    ushort_t* vth   = (ushort_t*)(ws + OFF_VTH);
    ushort_t* vtl   = (ushort_t*)(ws + OFF_VTL);
    float*    gates = ws + OFF_GATES;
    ushort_t* xhi   = (ushort_t*)(ws + OFF_XHI);
    ushort_t* xlo   = (ushort_t*)(ws + OFF_XLO);
    ushort_t* atthi = (ushort_t*)(ws + OFF_ATTHI);   // aliases xhi (dead)
    ushort_t* attlo = (ushort_t*)(ws + OFF_ATTLO);
    ushort_t* bthi  = (ushort_t*)(ws + OFF_BTHI);
    ushort_t* btlo  = (ushort_t*)(ws + OFF_BTLO);
    ushort_t* qth   = (ushort_t*)(ws + OFF_QTH);
    ushort_t* qtl   = (ushort_t*)(ws + OFF_QTL);
    float*    xbar  = ws + OFF_XBAR;
    int*      maskc = (int*)(ws + OFF_MASK);

    hipLaunchKernelGGL(mask_canon_kernel, dim3(1), dim3(256), 0, stream, mraw, maskc);
    hipLaunchKernelGGL(split_x_kernel, dim3(4096), dim3(256), 0, stream, x, xhi, xlo);
    hipLaunchKernelGGL(xbar_kernel, dim3(256), dim3(256), 0, stream, x, xbar);
    hipLaunchKernelGGL(wsplit_kernel, dim3(1024), dim3(256), 0, stream,
                       Wkv, Wg, Wo, bthi, btlo);
    hipLaunchKernelGGL(qt_gemm, dim3(256), dim3(256), 0, stream, xbar, Wq, qth, qtl);
    // proj: M=16384, N=768 (k | v-transposed | gates)
    hipLaunchKernelGGL((mfma_gemm<0>), dim3(6, 128), dim3(256), 0, stream,
                       xhi, xlo, bthi, btlo, bg, (float*)nullptr,
                       kh, kl, vth, vtl, gates);
    hipLaunchKernelGGL(attn_mfma_kernel, dim3(512), dim3(256), 0, stream,
                       qth, qtl, kh, kl, vth, vtl, gates, bias, maskc,
                       atthi, attlo);
    // out = att @ Wo + bo : M=16384, N=256
    hipLaunchKernelGGL((mfma_gemm<1>), dim3(2, 128), dim3(256), 0, stream,
                       atthi, attlo, bthi + 768 * 256, btlo + 768 * 256, bo,
                       (float*)d_out, nullptr, nullptr, nullptr, nullptr, nullptr);
}

// Round 5
// 167.579 us; speedup vs baseline: 1.6845x; 1.2958x over previous
//
#include <hip/hip_runtime.h>
#include <math.h>

typedef unsigned short ushort_t;
typedef unsigned int uint_t;
typedef __attribute__((ext_vector_type(8))) short short8v;   // 8 bf16 (4 VGPR)
typedef __attribute__((ext_vector_type(4))) float f32x4;

#define HEADS 8
#define DH 32
#define NB 64        // batch B
#define NN 256       // sequence N
#define ND 256       // model dim D (= K of all GEMMs)
#define NEG_MAX (-3.402823466e+38f)

// -------- ws layout (float offsets) --------
#define OFF_KH    0
#define OFF_KL    2097152
#define OFF_VTH   4194304
#define OFF_VTL   6291456
#define OFF_GATES 8388608
#define OFF_XHI   12582912
#define OFF_XLO   14680064
#define OFF_ATTHI OFF_XHI
#define OFF_ATTLO OFF_XLO
#define OFF_BTHI  16777216
#define OFF_BTLO  16908288
#define OFF_QTH   17039360
#define OFF_QTL   17072128
#define OFF_XBAR  17104896
#define OFF_MASK  17170432

// ---------------------------------------------------------------------------
__device__ __forceinline__ ushort_t f2bf(float x) {
    uint_t u = __float_as_uint(x);
    u = (u + 0x7fffu + ((u >> 16) & 1u)) >> 16;   // RNE
    return (ushort_t)u;
}
__device__ __forceinline__ float bf2f(ushort_t u) {
    return __uint_as_float(((uint_t)u) << 16);
}
__device__ __forceinline__ void gl2lds16(const void* g, void* l) {
    typedef const __attribute__((address_space(1))) uint32_t* gptr_t;
    typedef __attribute__((address_space(3))) uint32_t* lptr_t;
    __builtin_amdgcn_global_load_lds((gptr_t)(uintptr_t)g,
                                     (lptr_t)(uintptr_t)l, 16, 0, 0);
}

// ---------------------------------------------------------------------------
// Kernel 0: canonicalize mask (bool-bytes or int32). 16 blocks, redundant
// detection per block.
__global__ void mask_canon_kernel(const unsigned char* __restrict__ mraw,
                                  int* __restrict__ mout) {
    __shared__ int cnt[256];
    int tid = threadIdx.x;
    int c = 0;
    for (int i = tid; i < 4096; i += 256)
        if ((i & 3) != 0 && mraw[i] != 0) c++;
    cnt[tid] = c;
    __syncthreads();
    for (int s = 128; s > 0; s >>= 1) {
        if (tid < s) cnt[tid] += cnt[tid + s];
        __syncthreads();
    }
    int isBool = cnt[0] > 16;
    int base = blockIdx.x * 1024;
    if (isBool) {
        for (int i = tid; i < 1024; i += 256)
            mout[base + i] = mraw[base + i] ? 1 : 0;
    } else {
        const int* mi = (const int*)mraw;
        for (int i = tid; i < 1024; i += 256)
            mout[base + i] = mi[base + i] ? 1 : 0;
    }
}

// ---------------------------------------------------------------------------
// Kernel 1: split x -> bf16 hi/lo
__global__ __launch_bounds__(256) void split_x_kernel(
    const float* __restrict__ x, ushort_t* __restrict__ xhi,
    ushort_t* __restrict__ xlo) {
    int idx = blockIdx.x * 256 + threadIdx.x;     // one float4 each
    float4 v = ((const float4*)x)[idx];
    ushort4 h, l;
    h.x = f2bf(v.x); l.x = f2bf(v.x - bf2f(h.x));
    h.y = f2bf(v.y); l.y = f2bf(v.y - bf2f(h.y));
    h.z = f2bf(v.z); l.z = f2bf(v.z - bf2f(h.z));
    h.w = f2bf(v.w); l.w = f2bf(v.w - bf2f(h.w));
    ((ushort4*)xhi)[idx] = h;
    ((ushort4*)xlo)[idx] = l;
}

// Kernel 2: xbar = mean over batch of x  (256x256)
__global__ __launch_bounds__(256) void xbar_kernel(const float* __restrict__ x,
                                                   float* __restrict__ xbar) {
    int idx = blockIdx.x * 256 + threadIdx.x;
    float s = 0.f;
    for (int b = 0; b < NB; b++) s += x[(size_t)b * 65536 + idx];
    xbar[idx] = s * (1.0f / 64.0f);
}

// Kernel 3: build transposed+split weights BT[n][k]
__global__ __launch_bounds__(256) void wsplit_kernel(
    const float* __restrict__ Wkv, const float* __restrict__ Wg,
    const float* __restrict__ Wo, ushort_t* __restrict__ bthi,
    ushort_t* __restrict__ btlo) {
    int idx = blockIdx.x * 256 + threadIdx.x;     // 0..262143
    int n = idx >> 8, k = idx & 255;
    float v;
    if (n < 512)      v = Wkv[(size_t)k * 512 + n];
    else if (n < 768) v = Wg[(size_t)k * 256 + (n - 512)];
    else              v = Wo[(size_t)k * 256 + (n - 768)];
    ushort_t h = f2bf(v);
    bthi[idx] = h;
    btlo[idx] = f2bf(v - bf2f(h));
}

// Kernel 4: qt = xbar @ Wq * scale, output split bf16
__global__ __launch_bounds__(256) void qt_gemm(const float* __restrict__ xbar,
                                               const float* __restrict__ Wq,
                                               ushort_t* __restrict__ qth,
                                               ushort_t* __restrict__ qtl) {
    __shared__ float xrow[256];
    int i = blockIdx.x, t = threadIdx.x;
    xrow[t] = xbar[i * 256 + t];
    __syncthreads();
    float s = 0.f;
    for (int k = 0; k < 256; k++) s = fmaf(xrow[k], Wq[(size_t)k * 256 + t], s);
    s *= 0.17677669529663687f;   // 1/sqrt(32)
    ushort_t h = f2bf(s);
    qth[i * 256 + t] = h;
    qtl[i * 256 + t] = f2bf(s - bf2f(h));
}

// ---------------------------------------------------------------------------
// MFMA split-bf16 GEMM, templated tile. Wave computes MT x NT frags of 16x16;
// block = 2x2 waves -> BM = MT*32, BN = NT*32.
// EPI 0: proj (writes kh/kl, vth/vtl transposed-packed, gates)
// EPI 1: out (C = acc + bias)
template <int EPI, int MT, int NT>
__global__ __launch_bounds__(256) void mfma_gemm(
    const ushort_t* __restrict__ Ahi, const ushort_t* __restrict__ Alo,
    const ushort_t* __restrict__ Bthi, const ushort_t* __restrict__ Btlo,
    const float* __restrict__ bias, float* __restrict__ C,
    ushort_t* __restrict__ kh, ushort_t* __restrict__ kl,
    ushort_t* __restrict__ vth, ushort_t* __restrict__ vtl,
    float* __restrict__ gates) {
    constexpr int BM = MT * 32, BN = NT * 32;
    __shared__ ushort_t Ah[BM * 32], Al[BM * 32], Bh[BN * 32], Bl[BN * 32];
    const int t = threadIdx.x;
    const int m0 = blockIdx.y * BM;
    const int n0 = blockIdx.x * BN;
    const int wid = t >> 6, lane = t & 63;
    const int wr = wid >> 1, wc = wid & 1;
    const int lr = lane & 15, lg = lane >> 4;

    f32x4 acc[MT][NT] = {};

    for (int ks = 0; ks < 8; ++ks) {
        const int k0 = ks * 32;
#pragma unroll
        for (int it = 0; it < BM / 64; ++it) {
            int c = t + it * 256;
            int row = c >> 2, sub = c & 3;
            size_t ga = (size_t)(m0 + row) * 256 + k0 + sub * 8;
            gl2lds16(Ahi + ga, (char*)Ah + c * 16);
            gl2lds16(Alo + ga, (char*)Al + c * 16);
        }
#pragma unroll
        for (int it = 0; it < BN / 64; ++it) {
            int c = t + it * 256;
            int row = c >> 2, sub = c & 3;
            size_t gb = (size_t)(n0 + row) * 256 + k0 + sub * 8;
            gl2lds16(Bthi + gb, (char*)Bh + c * 16);
            gl2lds16(Btlo + gb, (char*)Bl + c * 16);
        }
        __syncthreads();

        short8v ah[MT], al[MT], bh[NT], bl[NT];
#pragma unroll
        for (int m = 0; m < MT; m++) {
            int off = (wr * (MT * 16) + m * 16 + lr) * 32 + lg * 8;
            ah[m] = *(const short8v*)&Ah[off];
            al[m] = *(const short8v*)&Al[off];
        }
#pragma unroll
        for (int n = 0; n < NT; n++) {
            int off = (wc * (NT * 16) + n * 16 + lr) * 32 + lg * 8;
            bh[n] = *(const short8v*)&Bh[off];
            bl[n] = *(const short8v*)&Bl[off];
        }
#pragma unroll
        for (int m = 0; m < MT; m++)
#pragma unroll
            for (int n = 0; n < NT; n++) {
                acc[m][n] = __builtin_amdgcn_mfma_f32_16x16x32_bf16(
                    ah[m], bh[n], acc[m][n], 0, 0, 0);
                acc[m][n] = __builtin_amdgcn_mfma_f32_16x16x32_bf16(
                    ah[m], bl[n], acc[m][n], 0, 0, 0);
                acc[m][n] = __builtin_amdgcn_mfma_f32_16x16x32_bf16(
                    al[m], bh[n], acc[m][n], 0, 0, 0);
            }
        __syncthreads();
    }

#pragma unroll
    for (int m = 0; m < MT; m++)
#pragma unroll
        for (int n = 0; n < NT; n++) {
            int gr0 = m0 + wr * (MT * 16) + m * 16 + lg * 4;
            int gc = n0 + wc * (NT * 16) + n * 16 + lr;
            if (EPI == 0) {
                if (gc < 256) {
#pragma unroll
                    for (int r = 0; r < 4; r++) {
                        float v = acc[m][n][r];
                        ushort_t hh = f2bf(v);
                        kh[(size_t)(gr0 + r) * 256 + gc] = hh;
                        kl[(size_t)(gr0 + r) * 256 + gc] = f2bf(v - bf2f(hh));
                    }
                } else if (gc < 512) {
                    int cc = gc - 256;
                    size_t idx = (((size_t)(gr0 >> 8) * 8 + (cc >> 5)) * 32 +
                                  (cc & 31)) * 256 + (gr0 & 255);
                    ushort4 hh, ll;
                    float v0 = acc[m][n][0], v1 = acc[m][n][1];
                    float v2 = acc[m][n][2], v3 = acc[m][n][3];
                    hh.x = f2bf(v0); ll.x = f2bf(v0 - bf2f(hh.x));
                    hh.y = f2bf(v1); ll.y = f2bf(v1 - bf2f(hh.y));
                    hh.z = f2bf(v2); ll.z = f2bf(v2 - bf2f(hh.z));
                    hh.w = f2bf(v3); ll.w = f2bf(v3 - bf2f(hh.w));
                    *(ushort4*)(vth + idx) = hh;
                    *(ushort4*)(vtl + idx) = ll;
                } else {
#pragma unroll
                    for (int r = 0; r < 4; r++) {
                        float v = acc[m][n][r];
                        float g = 1.f / (1.f + __expf(-(v + bias[gc - 512])));
                        gates[(size_t)(gr0 + r) * 256 + (gc - 512)] = g;
                    }
                }
            } else {
#pragma unroll
                for (int r = 0; r < 4; r++)
                    C[(size_t)(gr0 + r) * 256 + gc] = acc[m][n][r] + bias[gc];
            }
        }
}

// ---------------------------------------------------------------------------
// Split-KV MFMA flash attention. Block = (b, h, q-block of 64); 4 waves,
// wave w handles KV tile w (64 keys). Single-tile softmax per wave (no
// online loop), block-level merge via LDS (stats -> scale -> sum).
__global__ __launch_bounds__(256) void attn_mfma_kernel(
    const ushort_t* __restrict__ qth, const ushort_t* __restrict__ qtl,
    const ushort_t* __restrict__ kh, const ushort_t* __restrict__ kl,
    const ushort_t* __restrict__ vth, const ushort_t* __restrict__ vtl,
    const float* __restrict__ gates, const float* __restrict__ bias,
    const int* __restrict__ mask,
    ushort_t* __restrict__ atthi, ushort_t* __restrict__ attlo) {
    __shared__ __align__(16) char lds[40960];
    // P stage: PbH at [wid*5120], PbL at [20480 + wid*5120]  (64 x 40 ushort)
    // combine: accb f32 [4][64][36] at 0..36864 ; mlb float2 [4][64] at 36864
    const int bid = blockIdx.x;
    const int sid = ((bid & 7) << 8) | (bid >> 3);   // XCD-chunked swizzle
    const int b = sid >> 5;
    const int h = (sid >> 2) & 7;
    const int qb = sid & 3;
    const int t = threadIdx.x;
    const int wid = t >> 6, lane = t & 63;
    const int lr = lane & 15, lg = lane >> 4;
    const int i0 = qb * 64;
    const int j0 = wid * 64;

    ushort_t* pbh = (ushort_t*)(lds + wid * 5120);
    ushort_t* pbl = (ushort_t*)(lds + 20480 + wid * 5120);
    float* accb = (float*)lds;
    float2* mlb = (float2*)(lds + 36864);

    // ---- loads (all independent, issue early) ----
    short8v qfh[4], qfl[4];
#pragma unroll
    for (int nf = 0; nf < 4; nf++) {
        size_t off = (size_t)(i0 + nf * 16 + lr) * 256 + h * 32 + lg * 8;
        qfh[nf] = *(const short8v*)(qth + off);
        qfl[nf] = *(const short8v*)(qtl + off);
    }
    short8v kfh[4], kfl[4];
#pragma unroll
    for (int mf = 0; mf < 4; mf++) {
        size_t off = (size_t)(b * 256 + j0 + mf * 16 + lr) * 256 + h * 32 + lg * 8;
        kfh[mf] = *(const short8v*)(kh + off);
        kfl[mf] = *(const short8v*)(kl + off);
    }
    short8v vfh[2][2], vfl[2][2];   // [hb][mf]
#pragma unroll
    for (int hb = 0; hb < 2; hb++)
#pragma unroll
        for (int mf = 0; mf < 2; mf++) {
            size_t off = ((size_t)(b * 8 + h) * 32 + mf * 16 + lr) * 256 +
                         j0 + hb * 32 + lg * 8;
            vfh[hb][mf] = *(const short8v*)(vth + off);
            vfl[hb][mf] = *(const short8v*)(vtl + off);
        }
    int mi[4];
#pragma unroll
    for (int nf = 0; nf < 4; nf++)
        mi[nf] = mask[b * 256 + i0 + nf * 16 + lr];
    int4 mj[4];
#pragma unroll
    for (int mf = 0; mf < 4; mf++)
        mj[mf] = *(const int4*)(mask + b * 256 + j0 + mf * 16 + lg * 4);

    // ---- S^T = K * Q^T (3-term split) ----
    f32x4 s[4][4];
#pragma unroll
    for (int mf = 0; mf < 4; mf++)
#pragma unroll
        for (int nf = 0; nf < 4; nf++) {
            f32x4 a = {};
            a = __builtin_amdgcn_mfma_f32_16x16x32_bf16(kfh[mf], qfh[nf], a, 0, 0, 0);
            a = __builtin_amdgcn_mfma_f32_16x16x32_bf16(kfh[mf], qfl[nf], a, 0, 0, 0);
            a = __builtin_amdgcn_mfma_f32_16x16x32_bf16(kfl[mf], qfh[nf], a, 0, 0, 0);
            s[mf][nf] = a;
        }

    // ---- bias + mask ----
#pragma unroll
    for (int nf = 0; nf < 4; nf++) {
        int i = i0 + nf * 16 + lr;
        const float* bp = bias + ((size_t)h * 256 + i) * 256 + j0 + lg * 4;
        int okn = mi[nf];
#pragma unroll
        for (int mf = 0; mf < 4; mf++) {
            float4 bv = *(const float4*)(bp + mf * 16);
            s[mf][nf][0] = (okn && mj[mf].x) ? s[mf][nf][0] + bv.x : NEG_MAX;
            s[mf][nf][1] = (okn && mj[mf].y) ? s[mf][nf][1] + bv.y : NEG_MAX;
            s[mf][nf][2] = (okn && mj[mf].z) ? s[mf][nf][2] + bv.z : NEG_MAX;
            s[mf][nf][3] = (okn && mj[mf].w) ? s[mf][nf][3] + bv.w : NEG_MAX;
        }
    }

    // ---- tile softmax (no history) ----
    float mnew[4], lsum[4];
#pragma unroll
    for (int nf = 0; nf < 4; nf++) {
        float tm = s[0][nf][0];
#pragma unroll
        for (int mf = 0; mf < 4; mf++)
#pragma unroll
            for (int r = 0; r < 4; r++) tm = fmaxf(tm, s[mf][nf][r]);
        tm = fmaxf(tm, __shfl_xor(tm, 16));
        tm = fmaxf(tm, __shfl_xor(tm, 32));
        mnew[nf] = tm;
    }
#pragma unroll
    for (int nf = 0; nf < 4; nf++) {
        float ls = 0.f;
#pragma unroll
        for (int mf = 0; mf < 4; mf++)
#pragma unroll
            for (int r = 0; r < 4; r++) {
                float w = __expf(s[mf][nf][r] - mnew[nf]);
                s[mf][nf][r] = w;
                ls += w;
            }
        ls += __shfl_xor(ls, 16);
        ls += __shfl_xor(ls, 32);
        lsum[nf] = ls;
    }

    // ---- PV: two 32-key halves, P split -> per-wave LDS, O^T = V^T P^T ----
    f32x4 acc_o[2][4] = {};
#pragma unroll
    for (int hb = 0; hb < 2; ++hb) {
#pragma unroll
        for (int mq = 0; mq < 2; mq++) {
            int mf = hb * 2 + mq;
#pragma unroll
            for (int nf = 0; nf < 4; nf++) {
                ushort_t h0 = f2bf(s[mf][nf][0]), h1 = f2bf(s[mf][nf][1]);
                ushort_t h2 = f2bf(s[mf][nf][2]), h3 = f2bf(s[mf][nf][3]);
                uint2 hv, lv;
                hv.x = (uint_t)h0 | ((uint_t)h1 << 16);
                hv.y = (uint_t)h2 | ((uint_t)h3 << 16);
                lv.x = (uint_t)f2bf(s[mf][nf][0] - bf2f(h0)) |
                       ((uint_t)f2bf(s[mf][nf][1] - bf2f(h1)) << 16);
                lv.y = (uint_t)f2bf(s[mf][nf][2] - bf2f(h2)) |
                       ((uint_t)f2bf(s[mf][nf][3] - bf2f(h3)) << 16);
                int ad = (nf * 16 + lr) * 40 + mq * 16 + lg * 4;
                *(uint2*)(pbh + ad) = hv;
                *(uint2*)(pbl + ad) = lv;
            }
        }
        asm volatile("s_waitcnt lgkmcnt(0)" ::: "memory");
        __builtin_amdgcn_sched_barrier(0);

#pragma unroll
        for (int nf = 0; nf < 4; nf++) {
            int ad = (nf * 16 + lr) * 40 + lg * 8;
            short8v ph = *(const short8v*)(pbh + ad);
            short8v pl = *(const short8v*)(pbl + ad);
#pragma unroll
            for (int mf = 0; mf < 2; mf++) {
                acc_o[mf][nf] = __builtin_amdgcn_mfma_f32_16x16x32_bf16(
                    vfh[hb][mf], ph, acc_o[mf][nf], 0, 0, 0);
                acc_o[mf][nf] = __builtin_amdgcn_mfma_f32_16x16x32_bf16(
                    vfh[hb][mf], pl, acc_o[mf][nf], 0, 0, 0);
                acc_o[mf][nf] = __builtin_amdgcn_mfma_f32_16x16x32_bf16(
                    vfl[hb][mf], ph, acc_o[mf][nf], 0, 0, 0);
            }
        }
    }

    // ---- block-level merge ----
    __syncthreads();                       // all P-buffer use done
    if (lg == 0) {
#pragma unroll
        for (int nf = 0; nf < 4; nf++)
            mlb[wid * 64 + nf * 16 + lr] = make_float2(mnew[nf], lsum[nf]);
    }
    __syncthreads();                       // stats visible

    float scale_own[4];
#pragma unroll
    for (int nf = 0; nf < 4; nf++) {
        float M = NEG_MAX;
#pragma unroll
        for (int w = 0; w < 4; w++)
            M = fmaxf(M, mlb[w * 64 + nf * 16 + lr].x);
        scale_own[nf] = __expf(mnew[nf] - M);
    }
#pragma unroll
    for (int mf = 0; mf < 2; mf++)
#pragma unroll
        for (int nf = 0; nf < 4; nf++) {
            f32x4 v = acc_o[mf][nf];
            v[0] *= scale_own[nf]; v[1] *= scale_own[nf];
            v[2] *= scale_own[nf]; v[3] *= scale_own[nf];
            *(f32x4*)&accb[(size_t)(wid * 64 + nf * 16 + lr) * 36 +
                           mf * 16 + lg * 4] = v;
        }
    __syncthreads();                       // scaled partials visible

    // ---- output: thread -> (q = t>>2, dgroup = t&3) ----
    {
        int q = t >> 2, dg = t & 3;
        float2 ml[4];
        float M = NEG_MAX;
#pragma unroll
        for (int w = 0; w < 4; w++) {
            ml[w] = mlb[w * 64 + q];
            M = fmaxf(M, ml[w].x);
        }
        float L = 0.f;
#pragma unroll
        for (int w = 0; w < 4; w++) L += ml[w].y * __expf(ml[w].x - M);
        float invL = 1.0f / L;
        f32x4 o0 = {}, o1 = {};
#pragma unroll
        for (int w = 0; w < 4; w++) {
            const float* p = &accb[(size_t)(w * 64 + q) * 36 + dg * 8];
            f32x4 a0 = *(const f32x4*)p;
            f32x4 a1 = *(const f32x4*)(p + 4);
            o0 += a0; o1 += a1;
        }
        size_t base = ((size_t)(b * 256 + i0 + q)) * 256 + h * 32 + dg * 8;
        float4 g0 = *(const float4*)(gates + base);
        float4 g1 = *(const float4*)(gates + base + 4);
        float v0 = o0[0] * invL * g0.x, v1 = o0[1] * invL * g0.y;
        float v2 = o0[2] * invL * g0.z, v3 = o0[3] * invL * g0.w;
        float v4 = o1[0] * invL * g1.x, v5 = o1[1] * invL * g1.y;
        float v6 = o1[2] * invL * g1.z, v7 = o1[3] * invL * g1.w;
        ushort4 hh0, ll0, hh1, ll1;
        hh0.x = f2bf(v0); ll0.x = f2bf(v0 - bf2f(hh0.x));
        hh0.y = f2bf(v1); ll0.y = f2bf(v1 - bf2f(hh0.y));
        hh0.z = f2bf(v2); ll0.z = f2bf(v2 - bf2f(hh0.z));
        hh0.w = f2bf(v3); ll0.w = f2bf(v3 - bf2f(hh0.w));
        hh1.x = f2bf(v4); ll1.x = f2bf(v4 - bf2f(hh1.x));
        hh1.y = f2bf(v5); ll1.y = f2bf(v5 - bf2f(hh1.y));
        hh1.z = f2bf(v6); ll1.z = f2bf(v6 - bf2f(hh1.z));
        hh1.w = f2bf(v7); ll1.w = f2bf(v7 - bf2f(hh1.w));
        *(ushort4*)(atthi + base) = hh0;
        *(ushort4*)(atthi + base + 4) = hh1;
        *(ushort4*)(attlo + base) = ll0;
        *(ushort4*)(attlo + base + 4) = ll1;
    }
}

// ---------------------------------------------------------------------------
extern "C" void kernel_launch(void* const* d_in, const int* in_sizes, int n_in,
                              void* d_out, int out_size, void* d_ws, size_t ws_size,
                              hipStream_t stream) {
    const float* x    = (const float*)d_in[0];
    const unsigned char* mraw = (const unsigned char*)d_in[1];
    const float* bias = (const float*)d_in[2];
    const float* Wq   = (const float*)d_in[3];
    const float* Wkv  = (const float*)d_in[4];
    const float* Wg   = (const float*)d_in[5];
    const float* bg   = (const float*)d_in[6];
    const float* Wo   = (const float*)d_in[7];
    const float* bo   = (const float*)d_in[8];

    float* ws = (float*)d_ws;
    ushort_t* kh    = (ushort_t*)(ws + OFF_KH);
    ushort_t* kl    = (ushort_t*)(ws + OFF_KL);
    ushort_t* vth   = (ushort_t*)(ws + OFF_VTH);
    ushort_t* vtl   = (ushort_t*)(ws + OFF_VTL);
    float*    gates = ws + OFF_GATES;
    ushort_t* xhi   = (ushort_t*)(ws + OFF_XHI);
    ushort_t* xlo   = (ushort_t*)(ws + OFF_XLO);
    ushort_t* atthi = (ushort_t*)(ws + OFF_ATTHI);   // aliases xhi (dead)
    ushort_t* attlo = (ushort_t*)(ws + OFF_ATTLO);
    ushort_t* bthi  = (ushort_t*)(ws + OFF_BTHI);
    ushort_t* btlo  = (ushort_t*)(ws + OFF_BTLO);
    ushort_t* qth   = (ushort_t*)(ws + OFF_QTH);
    ushort_t* qtl   = (ushort_t*)(ws + OFF_QTL);
    float*    xbar  = ws + OFF_XBAR;
    int*      maskc = (int*)(ws + OFF_MASK);

    hipLaunchKernelGGL(mask_canon_kernel, dim3(16), dim3(256), 0, stream, mraw, maskc);
    hipLaunchKernelGGL(split_x_kernel, dim3(4096), dim3(256), 0, stream, x, xhi, xlo);
    hipLaunchKernelGGL(xbar_kernel, dim3(256), dim3(256), 0, stream, x, xbar);
    hipLaunchKernelGGL(wsplit_kernel, dim3(1024), dim3(256), 0, stream,
                       Wkv, Wg, Wo, bthi, btlo);
    hipLaunchKernelGGL(qt_gemm, dim3(256), dim3(256), 0, stream, xbar, Wq, qth, qtl);
    // proj: M=16384, N=768 (k | v-transposed | gates), 128x128 tiles
    hipLaunchKernelGGL((mfma_gemm<0, 4, 4>), dim3(6, 128), dim3(256), 0, stream,
                       xhi, xlo, bthi, btlo, bg, (float*)nullptr,
                       kh, kl, vth, vtl, gates);
    hipLaunchKernelGGL(attn_mfma_kernel, dim3(2048), dim3(256), 0, stream,
                       qth, qtl, kh, kl, vth, vtl, gates, bias, maskc,
                       atthi, attlo);
    // out = att @ Wo + bo : M=16384, N=256, 64x64 tiles (1024 blocks)
    hipLaunchKernelGGL((mfma_gemm<1, 2, 2>), dim3(4, 256), dim3(256), 0, stream,
                       atthi, attlo, bthi + 768 * 256, btlo + 768 * 256, bo,
                       (float*)d_out, nullptr, nullptr, nullptr, nullptr, nullptr);
}

// Round 7
// 153.568 us; speedup vs baseline: 1.8382x; 1.0912x over previous
//
#include <hip/hip_runtime.h>
#include <math.h>

typedef unsigned short ushort_t;
typedef unsigned int uint_t;
typedef __attribute__((ext_vector_type(8))) short short8v;   // 8 bf16 (4 VGPR)
typedef __attribute__((ext_vector_type(4))) float f32x4;

#define HEADS 8
#define DH 32
#define NB 64        // batch B
#define NN 256       // sequence N
#define ND 256       // model dim D
#define NEG_MAX (-3.402823466e+38f)

// -------- ws layout (float offsets) --------
// khP/klP : K fragment-packed [b][h][jt][mf][lg][lr][e] ushort (8MB each)
// vP      : V^T fragment-packed [b][h][jt][hb][mf][lg][lr][e] ushort hi-only
// gatesbf : [16384][256] ushort (bf16 sigmoid gates)
// xhi/xlo : [16384][256] ushort -- ALIASED by att_hi/att_lo after proj
// bthi/lo : [1024][256] ushort (WkvT | WgT | WoT)
// qPh/qPl : Q fragment-packed [h][qb][nf][lg][lr][e] ushort
// biasP   : bias prepacked [h][qb][jt][nf*4+mf][lane][4] f32 (2MB)
#define OFF_KH    0
#define OFF_KL    2097152
#define OFF_VP    4194304
#define OFF_GATES 6291456
#define OFF_XHI   8388608
#define OFF_XLO   10485760
#define OFF_ATTHI OFF_XHI
#define OFF_ATTLO OFF_XLO
#define OFF_BTHI  12582912
#define OFF_BTLO  12713984
#define OFF_QTH   12845056
#define OFF_QTL   12877824
#define OFF_XBAR  12910592
#define OFF_BIASP 12976128
#define OFF_MASK  13500416

// ---------------------------------------------------------------------------
__device__ __forceinline__ ushort_t f2bf(float x) {
    uint_t u = __float_as_uint(x);
    u = (u + 0x7fffu + ((u >> 16) & 1u)) >> 16;   // RNE
    return (ushort_t)u;
}
__device__ __forceinline__ float bf2f(ushort_t u) {
    return __uint_as_float(((uint_t)u) << 16);
}
__device__ __forceinline__ void gl2lds16(const void* g, void* l) {
    typedef const __attribute__((address_space(1))) uint32_t* gptr_t;
    typedef __attribute__((address_space(3))) uint32_t* lptr_t;
    __builtin_amdgcn_global_load_lds((gptr_t)(uintptr_t)g,
                                     (lptr_t)(uintptr_t)l, 16, 0, 0);
}

// ---------------------------------------------------------------------------
// Kernel 0: canonicalize mask (bool-bytes or int32)
__global__ void mask_canon_kernel(const unsigned char* __restrict__ mraw,
                                  int* __restrict__ mout) {
    __shared__ int cnt[256];
    int tid = threadIdx.x;
    int c = 0;
    for (int i = tid; i < 4096; i += 256)
        if ((i & 3) != 0 && mraw[i] != 0) c++;
    cnt[tid] = c;
    __syncthreads();
    for (int s = 128; s > 0; s >>= 1) {
        if (tid < s) cnt[tid] += cnt[tid + s];
        __syncthreads();
    }
    int isBool = cnt[0] > 16;
    int base = blockIdx.x * 1024;
    if (isBool) {
        for (int i = tid; i < 1024; i += 256)
            mout[base + i] = mraw[base + i] ? 1 : 0;
    } else {
        const int* mi = (const int*)mraw;
        for (int i = tid; i < 1024; i += 256)
            mout[base + i] = mi[base + i] ? 1 : 0;
    }
}

// ---------------------------------------------------------------------------
// Kernel 1: split x -> bf16 hi/lo
__global__ __launch_bounds__(256) void split_x_kernel(
    const float* __restrict__ x, ushort_t* __restrict__ xhi,
    ushort_t* __restrict__ xlo) {
    int idx = blockIdx.x * 256 + threadIdx.x;
    float4 v = ((const float4*)x)[idx];
    ushort4 h, l;
    h.x = f2bf(v.x); l.x = f2bf(v.x - bf2f(h.x));
    h.y = f2bf(v.y); l.y = f2bf(v.y - bf2f(h.y));
    h.z = f2bf(v.z); l.z = f2bf(v.z - bf2f(h.z));
    h.w = f2bf(v.w); l.w = f2bf(v.w - bf2f(h.w));
    ((ushort4*)xhi)[idx] = h;
    ((ushort4*)xlo)[idx] = l;
}

// Kernel 2: xbar = mean over batch of x
__global__ __launch_bounds__(256) void xbar_kernel(const float* __restrict__ x,
                                                   float* __restrict__ xbar) {
    int idx = blockIdx.x * 256 + threadIdx.x;
    float s = 0.f;
    for (int b = 0; b < NB; b++) s += x[(size_t)b * 65536 + idx];
    xbar[idx] = s * (1.0f / 64.0f);
}

// Kernel 3: build transposed+split weights BT[n][k]
__global__ __launch_bounds__(256) void wsplit_kernel(
    const float* __restrict__ Wkv, const float* __restrict__ Wg,
    const float* __restrict__ Wo, ushort_t* __restrict__ bthi,
    ushort_t* __restrict__ btlo) {
    int idx = blockIdx.x * 256 + threadIdx.x;
    int n = idx >> 8, k = idx & 255;
    float v;
    if (n < 512)      v = Wkv[(size_t)k * 512 + n];
    else if (n < 768) v = Wg[(size_t)k * 256 + (n - 512)];
    else              v = Wo[(size_t)k * 256 + (n - 768)];
    ushort_t h = f2bf(v);
    bthi[idx] = h;
    btlo[idx] = f2bf(v - bf2f(h));
}

// Kernel 4: qt = xbar @ Wq * scale, fragment-packed split-bf16 output
__global__ __launch_bounds__(256) void qt_gemm(const float* __restrict__ xbar,
                                               const float* __restrict__ Wq,
                                               ushort_t* __restrict__ qPh,
                                               ushort_t* __restrict__ qPl) {
    __shared__ float xrow[256];
    int i = blockIdx.x, t = threadIdx.x;
    xrow[t] = xbar[i * 256 + t];
    __syncthreads();
    float s = 0.f;
    for (int k = 0; k < 256; k++) s = fmaf(xrow[k], Wq[(size_t)k * 256 + t], s);
    s *= 0.17677669529663687f;   // 1/sqrt(32)
    int h = t >> 5, d = t & 31, lg = d >> 3, e = d & 7;
    int qb = i >> 6, nf = (i >> 4) & 3, lr = i & 15;
    int a = ((((h * 4 + qb) * 4 + nf) * 4 + lg) * 16 + lr) * 8 + e;
    ushort_t hh = f2bf(s);
    qPh[a] = hh;
    qPl[a] = f2bf(s - bf2f(hh));
}

// Kernel 5: prepack bias into per-lane fragment order
__global__ __launch_bounds__(256) void bias_prepack(
    const float* __restrict__ bias, float* __restrict__ biasP) {
    int idx = blockIdx.x * 256 + threadIdx.x;   // 0..131071
    int lane = idx & 63, g = idx >> 6;
    int mf = g & 3, nf = (g >> 2) & 3, jt = (g >> 4) & 3;
    int qb = (g >> 6) & 3, h = g >> 8;
    int lr = lane & 15, lg = lane >> 4;
    float4 v = *(const float4*)(bias +
        (size_t)(h * 256 + qb * 64 + nf * 16 + lr) * 256 +
        jt * 64 + mf * 16 + lg * 4);
    *(float4*)(biasP + (size_t)idx * 4) = v;
}

// ---------------------------------------------------------------------------
// MFMA split-bf16 GEMM. EPI 0: proj (K/V fragment-packed, gates bf16)
//                       EPI 1: out (C = acc + bias)
template <int EPI, int MT, int NT>
__global__ __launch_bounds__(256) void mfma_gemm(
    const ushort_t* __restrict__ Ahi, const ushort_t* __restrict__ Alo,
    const ushort_t* __restrict__ Bthi, const ushort_t* __restrict__ Btlo,
    const float* __restrict__ bias, float* __restrict__ C,
    ushort_t* __restrict__ kh, ushort_t* __restrict__ kl,
    ushort_t* __restrict__ vP, ushort_t* __restrict__ gatesbf) {
    constexpr int BM = MT * 32, BN = NT * 32;
    __shared__ ushort_t Ah[BM * 32], Al[BM * 32], Bh[BN * 32], Bl[BN * 32];
    const int t = threadIdx.x;
    const int m0 = blockIdx.y * BM;
    const int n0 = blockIdx.x * BN;
    const int wid = t >> 6, lane = t & 63;
    const int wr = wid >> 1, wc = wid & 1;
    const int lr = lane & 15, lg = lane >> 4;

    f32x4 acc[MT][NT] = {};

    for (int ks = 0; ks < 8; ++ks) {
        const int k0 = ks * 32;
#pragma unroll
        for (int it = 0; it < BM / 64; ++it) {
            int c = t + it * 256;
            int row = c >> 2, sub = c & 3;
            size_t ga = (size_t)(m0 + row) * 256 + k0 + sub * 8;
            gl2lds16(Ahi + ga, (char*)Ah + c * 16);
            gl2lds16(Alo + ga, (char*)Al + c * 16);
        }
#pragma unroll
        for (int it = 0; it < BN / 64; ++it) {
            int c = t + it * 256;
            int row = c >> 2, sub = c & 3;
            size_t gb = (size_t)(n0 + row) * 256 + k0 + sub * 8;
            gl2lds16(Bthi + gb, (char*)Bh + c * 16);
            gl2lds16(Btlo + gb, (char*)Bl + c * 16);
        }
        __syncthreads();

        short8v ah[MT], al[MT], bh[NT], bl[NT];
#pragma unroll
        for (int m = 0; m < MT; m++) {
            int off = (wr * (MT * 16) + m * 16 + lr) * 32 + lg * 8;
            ah[m] = *(const short8v*)&Ah[off];
            al[m] = *(const short8v*)&Al[off];
        }
#pragma unroll
        for (int n = 0; n < NT; n++) {
            int off = (wc * (NT * 16) + n * 16 + lr) * 32 + lg * 8;
            bh[n] = *(const short8v*)&Bh[off];
            bl[n] = *(const short8v*)&Bl[off];
        }
#pragma unroll
        for (int m = 0; m < MT; m++)
#pragma unroll
            for (int n = 0; n < NT; n++) {
                acc[m][n] = __builtin_amdgcn_mfma_f32_16x16x32_bf16(
                    ah[m], bh[n], acc[m][n], 0, 0, 0);
                acc[m][n] = __builtin_amdgcn_mfma_f32_16x16x32_bf16(
                    ah[m], bl[n], acc[m][n], 0, 0, 0);
                acc[m][n] = __builtin_amdgcn_mfma_f32_16x16x32_bf16(
                    al[m], bh[n], acc[m][n], 0, 0, 0);
            }
        __syncthreads();
    }

#pragma unroll
    for (int m = 0; m < MT; m++)
#pragma unroll
        for (int n = 0; n < NT; n++) {
            int gr0 = m0 + wr * (MT * 16) + m * 16 + lg * 4;
            int gc = n0 + wc * (NT * 16) + n * 16 + lr;
            if (EPI == 0) {
                if (gc < 256) {          // K: fragment-packed hi/lo
                    int hh_ = gc >> 5, dk = gc & 31;
                    int lgk = dk >> 3, ek = dk & 7;
#pragma unroll
                    for (int r = 0; r < 4; r++) {
                        int gr = gr0 + r;
                        int bb = gr >> 8, j = gr & 255;
                        int jt = j >> 6, mfk = (j >> 4) & 3, lrk = j & 15;
                        size_t a =
                            (((((size_t)(bb * 8 + hh_) * 4 + jt) * 4 + mfk) * 4
                              + lgk) * 16 + lrk) * 8 + ek;
                        float v = acc[m][n][r];
                        ushort_t hv = f2bf(v);
                        kh[a] = hv;
                        kl[a] = f2bf(v - bf2f(hv));
                    }
                } else if (gc < 512) {   // V^T: fragment-packed hi only
                    int cc = gc - 256;
                    int hh_ = cc >> 5, dv = cc & 31;
                    int mfv = dv >> 4, lrv = dv & 15;
                    int gr = gr0;
                    int bb = gr >> 8, j = gr & 255;
                    int jt = j >> 6, hbv = (j >> 5) & 1;
                    int lgv = (j >> 3) & 3, ev = j & 7;
                    size_t a =
                        ((((((size_t)(bb * 8 + hh_) * 4 + jt) * 2 + hbv) * 2
                           + mfv) * 4 + lgv) * 16 + lrv) * 8 + ev;
                    ushort4 hv;
                    hv.x = f2bf(acc[m][n][0]);
                    hv.y = f2bf(acc[m][n][1]);
                    hv.z = f2bf(acc[m][n][2]);
                    hv.w = f2bf(acc[m][n][3]);
                    *(ushort4*)(vP + a) = hv;
                } else {                 // gates: bf16
#pragma unroll
                    for (int r = 0; r < 4; r++) {
                        float v = acc[m][n][r];
                        float g = 1.f / (1.f + __expf(-(v + bias[gc - 512])));
                        gatesbf[(size_t)(gr0 + r) * 256 + (gc - 512)] = f2bf(g);
                    }
                }
            } else {
#pragma unroll
                for (int r = 0; r < 4; r++)
                    C[(size_t)(gr0 + r) * 256 + gc] = acc[m][n][r] + bias[gc];
            }
        }
}

// ---------------------------------------------------------------------------
// Split-KV MFMA flash attention, fully-coalesced fragment loads.
__global__ __launch_bounds__(256) void attn_mfma_kernel(
    const ushort_t* __restrict__ qPh, const ushort_t* __restrict__ qPl,
    const ushort_t* __restrict__ kh, const ushort_t* __restrict__ kl,
    const ushort_t* __restrict__ vP, const ushort_t* __restrict__ gatesbf,
    const float* __restrict__ biasP, const int* __restrict__ mask,
    ushort_t* __restrict__ atthi, ushort_t* __restrict__ attlo) {
    __shared__ __align__(16) char lds[38912];
    // P stage (per wave, 64x40 ushort = 5120B) aliases accb region.
    // accb f32 [4][64][36] at 0..36864 ; mlb float2 [4][64] at 36864..38912
    const int bid = blockIdx.x;
    const int sid = ((bid & 7) << 8) | (bid >> 3);   // XCD-chunked swizzle
    const int b = sid >> 5;
    const int h = (sid >> 2) & 7;
    const int qb = sid & 3;
    const int t = threadIdx.x;
    const int wid = t >> 6, lane = t & 63;
    const int lr = lane & 15, lg = lane >> 4;
    const int i0 = qb * 64;

    ushort_t* pbh = (ushort_t*)(lds + wid * 5120);
    float* accb = (float*)lds;
    float2* mlb = (float2*)(lds + 36864);

    // ---- all global loads coalesced; issue early ----
    uint4 gatev;                         // epilogue gates (bf16 x8), hoisted
    {
        int q = t >> 2, dg = t & 3;
        size_t gbase = ((size_t)(b * 256 + i0 + q)) * 256 + h * 32 + dg * 8;
        gatev = *(const uint4*)(gatesbf + gbase);
    }
    short8v qfh[4], qfl[4];
#pragma unroll
    for (int nf = 0; nf < 4; nf++) {
        size_t off = ((((size_t)(h * 4 + qb) * 4 + nf) * 4 + lg) * 16 + lr) * 8;
        qfh[nf] = *(const short8v*)(qPh + off);
        qfl[nf] = *(const short8v*)(qPl + off);
    }
    short8v kfh[4], kfl[4];
#pragma unroll
    for (int mf = 0; mf < 4; mf++) {
        size_t off = ((((((size_t)(b * 8 + h)) * 4 + wid) * 4 + mf) * 4 + lg) * 16 + lr) * 8;
        kfh[mf] = *(const short8v*)(kh + off);
        kfl[mf] = *(const short8v*)(kl + off);
    }
    short8v vfh[2][2];
#pragma unroll
    for (int hb = 0; hb < 2; hb++)
#pragma unroll
        for (int mf = 0; mf < 2; mf++) {
            size_t off = (((((((size_t)(b * 8 + h)) * 4 + wid) * 2 + hb) * 2 + mf) * 4 + lg) * 16 + lr) * 8;
            vfh[hb][mf] = *(const short8v*)(vP + off);
        }
    int mi[4];
#pragma unroll
    for (int nf = 0; nf < 4; nf++)
        mi[nf] = mask[b * 256 + i0 + nf * 16 + lr];
    int4 mj[4];
#pragma unroll
    for (int mf = 0; mf < 4; mf++)
        mj[mf] = *(const int4*)(mask + b * 256 + wid * 64 + mf * 16 + lg * 4);

    // ---- S^T = K * Q^T (3-term split) ----
    f32x4 s[4][4];
#pragma unroll
    for (int mf = 0; mf < 4; mf++)
#pragma unroll
        for (int nf = 0; nf < 4; nf++) {
            f32x4 a = {};
            a = __builtin_amdgcn_mfma_f32_16x16x32_bf16(kfh[mf], qfh[nf], a, 0, 0, 0);
            a = __builtin_amdgcn_mfma_f32_16x16x32_bf16(kfh[mf], qfl[nf], a, 0, 0, 0);
            a = __builtin_amdgcn_mfma_f32_16x16x32_bf16(kfl[mf], qfh[nf], a, 0, 0, 0);
            s[mf][nf] = a;
        }

    // ---- bias (prepacked, coalesced) + mask ----
    const float* bbase = biasP +
        ((size_t)((h * 4 + qb) * 4 + wid) * 16) * 256 + lane * 4;
#pragma unroll
    for (int nf = 0; nf < 4; nf++) {
        int okn = mi[nf];
#pragma unroll
        for (int mf = 0; mf < 4; mf++) {
            float4 bv = *(const float4*)(bbase + (size_t)(nf * 4 + mf) * 256);
            s[mf][nf][0] = (okn && mj[mf].x) ? s[mf][nf][0] + bv.x : NEG_MAX;
            s[mf][nf][1] = (okn && mj[mf].y) ? s[mf][nf][1] + bv.y : NEG_MAX;
            s[mf][nf][2] = (okn && mj[mf].z) ? s[mf][nf][2] + bv.z : NEG_MAX;
            s[mf][nf][3] = (okn && mj[mf].w) ? s[mf][nf][3] + bv.w : NEG_MAX;
        }
    }

    // ---- tile softmax ----
    float mnew[4], lsum[4];
#pragma unroll
    for (int nf = 0; nf < 4; nf++) {
        float tm = s[0][nf][0];
#pragma unroll
        for (int mf = 0; mf < 4; mf++)
#pragma unroll
            for (int r = 0; r < 4; r++) tm = fmaxf(tm, s[mf][nf][r]);
        tm = fmaxf(tm, __shfl_xor(tm, 16));
        tm = fmaxf(tm, __shfl_xor(tm, 32));
        mnew[nf] = tm;
    }
#pragma unroll
    for (int nf = 0; nf < 4; nf++) {
        float ls = 0.f;
#pragma unroll
        for (int mf = 0; mf < 4; mf++)
#pragma unroll
            for (int r = 0; r < 4; r++) {
                float w = __expf(s[mf][nf][r] - mnew[nf]);
                s[mf][nf][r] = w;
                ls += w;
            }
        ls += __shfl_xor(ls, 16);
        ls += __shfl_xor(ls, 32);
        lsum[nf] = ls;
    }

    // ---- PV: P (bf16, hi only) via per-wave LDS, O^T = V^T P^T ----
    f32x4 acc_o[2][4] = {};
#pragma unroll
    for (int hb = 0; hb < 2; ++hb) {
#pragma unroll
        for (int mq = 0; mq < 2; mq++) {
            int mf = hb * 2 + mq;
#pragma unroll
            for (int nf = 0; nf < 4; nf++) {
                uint2 hv;
                hv.x = (uint_t)f2bf(s[mf][nf][0]) | ((uint_t)f2bf(s[mf][nf][1]) << 16);
                hv.y = (uint_t)f2bf(s[mf][nf][2]) | ((uint_t)f2bf(s[mf][nf][3]) << 16);
                *(uint2*)(pbh + (nf * 16 + lr) * 40 + mq * 16 + lg * 4) = hv;
            }
        }
        asm volatile("s_waitcnt lgkmcnt(0)" ::: "memory");
        __builtin_amdgcn_sched_barrier(0);
#pragma unroll
        for (int nf = 0; nf < 4; nf++) {
            short8v ph = *(const short8v*)(pbh + (nf * 16 + lr) * 40 + lg * 8);
#pragma unroll
            for (int mf = 0; mf < 2; mf++)
                acc_o[mf][nf] = __builtin_amdgcn_mfma_f32_16x16x32_bf16(
                    vfh[hb][mf], ph, acc_o[mf][nf], 0, 0, 0);
        }
    }

    // ---- block-level merge ----
    __syncthreads();
    if (lg == 0) {
#pragma unroll
        for (int nf = 0; nf < 4; nf++)
            mlb[wid * 64 + nf * 16 + lr] = make_float2(mnew[nf], lsum[nf]);
    }
    __syncthreads();

    float scale_own[4];
#pragma unroll
    for (int nf = 0; nf < 4; nf++) {
        float M = NEG_MAX;
#pragma unroll
        for (int w = 0; w < 4; w++)
            M = fmaxf(M, mlb[w * 64 + nf * 16 + lr].x);
        scale_own[nf] = __expf(mnew[nf] - M);
    }
#pragma unroll
    for (int mf = 0; mf < 2; mf++)
#pragma unroll
        for (int nf = 0; nf < 4; nf++) {
            f32x4 v = acc_o[mf][nf];
            v[0] *= scale_own[nf]; v[1] *= scale_own[nf];
            v[2] *= scale_own[nf]; v[3] *= scale_own[nf];
            *(f32x4*)&accb[(size_t)(wid * 64 + nf * 16 + lr) * 36 +
                           mf * 16 + lg * 4] = v;
        }
    __syncthreads();

    // ---- output: thread -> (q = t>>2, dgroup = t&3) ----
    {
        int q = t >> 2, dg = t & 3;
        float2 ml[4];
        float M = NEG_MAX;
#pragma unroll
        for (int w = 0; w < 4; w++) {
            ml[w] = mlb[w * 64 + q];
            M = fmaxf(M, ml[w].x);
        }
        float L = 0.f;
#pragma unroll
        for (int w = 0; w < 4; w++) L += ml[w].y * __expf(ml[w].x - M);
        float invL = 1.0f / L;
        f32x4 o0 = {}, o1 = {};
#pragma unroll
        for (int w = 0; w < 4; w++) {
            const float* p = &accb[(size_t)(w * 64 + q) * 36 + dg * 8];
            o0 += *(const f32x4*)p;
            o1 += *(const f32x4*)(p + 4);
        }
        float g[8];
        g[0] = bf2f((ushort_t)(gatev.x & 0xffff));
        g[1] = bf2f((ushort_t)(gatev.x >> 16));
        g[2] = bf2f((ushort_t)(gatev.y & 0xffff));
        g[3] = bf2f((ushort_t)(gatev.y >> 16));
        g[4] = bf2f((ushort_t)(gatev.z & 0xffff));
        g[5] = bf2f((ushort_t)(gatev.z >> 16));
        g[6] = bf2f((ushort_t)(gatev.w & 0xffff));
        g[7] = bf2f((ushort_t)(gatev.w >> 16));
        float v0 = o0[0] * invL * g[0], v1 = o0[1] * invL * g[1];
        float v2 = o0[2] * invL * g[2], v3 = o0[3] * invL * g[3];
        float v4 = o1[0] * invL * g[4], v5 = o1[1] * invL * g[5];
        float v6 = o1[2] * invL * g[6], v7 = o1[3] * invL * g[7];
        size_t base = ((size_t)(b * 256 + i0 + q)) * 256 + h * 32 + dg * 8;
        ushort4 hh0, ll0, hh1, ll1;
        hh0.x = f2bf(v0); ll0.x = f2bf(v0 - bf2f(hh0.x));
        hh0.y = f2bf(v1); ll0.y = f2bf(v1 - bf2f(hh0.y));
        hh0.z = f2bf(v2); ll0.z = f2bf(v2 - bf2f(hh0.z));
        hh0.w = f2bf(v3); ll0.w = f2bf(v3 - bf2f(hh0.w));
        hh1.x = f2bf(v4); ll1.x = f2bf(v4 - bf2f(hh1.x));
        hh1.y = f2bf(v5); ll1.y = f2bf(v5 - bf2f(hh1.y));
        hh1.z = f2bf(v6); ll1.z = f2bf(v6 - bf2f(hh1.z));
        hh1.w = f2bf(v7); ll1.w = f2bf(v7 - bf2f(hh1.w));
        *(ushort4*)(atthi + base) = hh0;
        *(ushort4*)(atthi + base + 4) = hh1;
        *(ushort4*)(attlo + base) = ll0;
        *(ushort4*)(attlo + base + 4) = ll1;
    }
}

// ---------------------------------------------------------------------------
extern "C" void kernel_launch(void* const* d_in, const int* in_sizes, int n_in,
                              void* d_out, int out_size, void* d_ws, size_t ws_size,
                              hipStream_t stream) {
    const float* x    = (const float*)d_in[0];
    const unsigned char* mraw = (const unsigned char*)d_in[1];
    const float* bias = (const float*)d_in[2];
    const float* Wq   = (const float*)d_in[3];
    const float* Wkv  = (const float*)d_in[4];
    const float* Wg   = (const float*)d_in[5];
    const float* bg   = (const float*)d_in[6];
    const float* Wo   = (const float*)d_in[7];
    const float* bo   = (const float*)d_in[8];

    float* ws = (float*)d_ws;
    ushort_t* kh     = (ushort_t*)(ws + OFF_KH);
    ushort_t* kl     = (ushort_t*)(ws + OFF_KL);
    ushort_t* vP     = (ushort_t*)(ws + OFF_VP);
    ushort_t* gatesb = (ushort_t*)(ws + OFF_GATES);
    ushort_t* xhi    = (ushort_t*)(ws + OFF_XHI);
    ushort_t* xlo    = (ushort_t*)(ws + OFF_XLO);
    ushort_t* atthi  = (ushort_t*)(ws + OFF_ATTHI);  // aliases xhi (dead)
    ushort_t* attlo  = (ushort_t*)(ws + OFF_ATTLO);
    ushort_t* bthi   = (ushort_t*)(ws + OFF_BTHI);
    ushort_t* btlo   = (ushort_t*)(ws + OFF_BTLO);
    ushort_t* qPh    = (ushort_t*)(ws + OFF_QTH);
    ushort_t* qPl    = (ushort_t*)(ws + OFF_QTL);
    float*    xbar   = ws + OFF_XBAR;
    float*    biasP  = ws + OFF_BIASP;
    int*      maskc  = (int*)(ws + OFF_MASK);

    hipLaunchKernelGGL(mask_canon_kernel, dim3(16), dim3(256), 0, stream, mraw, maskc);
    hipLaunchKernelGGL(split_x_kernel, dim3(4096), dim3(256), 0, stream, x, xhi, xlo);
    hipLaunchKernelGGL(xbar_kernel, dim3(256), dim3(256), 0, stream, x, xbar);
    hipLaunchKernelGGL(wsplit_kernel, dim3(1024), dim3(256), 0, stream,
                       Wkv, Wg, Wo, bthi, btlo);
    hipLaunchKernelGGL(qt_gemm, dim3(256), dim3(256), 0, stream, xbar, Wq, qPh, qPl);
    hipLaunchKernelGGL(bias_prepack, dim3(512), dim3(256), 0, stream, bias, biasP);
    // proj: M=16384, N=768 (K | V^T | gates), 128x128 tiles
    hipLaunchKernelGGL((mfma_gemm<0, 4, 4>), dim3(6, 128), dim3(256), 0, stream,
                       xhi, xlo, bthi, btlo, bg, (float*)nullptr,
                       kh, kl, vP, gatesb);
    hipLaunchKernelGGL(attn_mfma_kernel, dim3(2048), dim3(256), 0, stream,
                       qPh, qPl, kh, kl, vP, gatesb, biasP, maskc,
                       atthi, attlo);
    // out = att @ Wo + bo : M=16384, N=256, 64x64 tiles
    hipLaunchKernelGGL((mfma_gemm<1, 2, 2>), dim3(4, 256), dim3(256), 0, stream,
                       atthi, attlo, bthi + 768 * 256, btlo + 768 * 256, bo,
                       (float*)d_out, nullptr, nullptr, nullptr, nullptr);
}

// Round 8
// 129.032 us; speedup vs baseline: 2.1878x; 1.1902x over previous
//
#include <hip/hip_runtime.h>
#include <math.h>

typedef unsigned short ushort_t;
typedef unsigned int uint_t;
typedef __attribute__((ext_vector_type(8))) short short8v;   // 8 bf16 (4 VGPR)
typedef __attribute__((ext_vector_type(4))) float f32x4;

#define HEADS 8
#define DH 32
#define NB 64        // batch B
#define NN 256       // sequence N
#define ND 256       // model dim D
#define NEG_MAX (-3.402823466e+38f)

// -------- ws layout (float offsets) --------
#define OFF_KH    0
#define OFF_KL    2097152            // (unused now)
#define OFF_VP    4194304
#define OFF_GATES 6291456
#define OFF_XHI   8388608
#define OFF_XLO   10485760
#define OFF_ATTHI OFF_XHI
#define OFF_ATTLO OFF_XLO
#define OFF_BTHI  12582912
#define OFF_BTLO  12713984
#define OFF_QTH   12845056
#define OFF_QTL   12877824
#define OFF_XBAR  12910592
#define OFF_BIASP 12976128
#define OFF_MASK  13500416

// ---------------------------------------------------------------------------
__device__ __forceinline__ ushort_t f2bf(float x) {
    uint_t u = __float_as_uint(x);
    u = (u + 0x7fffu + ((u >> 16) & 1u)) >> 16;   // RNE
    return (ushort_t)u;
}
__device__ __forceinline__ float bf2f(ushort_t u) {
    return __uint_as_float(((uint_t)u) << 16);
}
__device__ __forceinline__ void gl2lds16(const void* g, void* l) {
    typedef const __attribute__((address_space(1))) uint32_t* gptr_t;
    typedef __attribute__((address_space(3))) uint32_t* lptr_t;
    __builtin_amdgcn_global_load_lds((gptr_t)(uintptr_t)g,
                                     (lptr_t)(uintptr_t)l, 16, 0, 0);
}

// ---------------------------------------------------------------------------
// Kernel 0: canonicalize mask (bool-bytes or int32)
__global__ void mask_canon_kernel(const unsigned char* __restrict__ mraw,
                                  int* __restrict__ mout) {
    __shared__ int cnt[256];
    int tid = threadIdx.x;
    int c = 0;
    for (int i = tid; i < 4096; i += 256)
        if ((i & 3) != 0 && mraw[i] != 0) c++;
    cnt[tid] = c;
    __syncthreads();
    for (int s = 128; s > 0; s >>= 1) {
        if (tid < s) cnt[tid] += cnt[tid + s];
        __syncthreads();
    }
    int isBool = cnt[0] > 16;
    int base = blockIdx.x * 1024;
    if (isBool) {
        for (int i = tid; i < 1024; i += 256)
            mout[base + i] = mraw[base + i] ? 1 : 0;
    } else {
        const int* mi = (const int*)mraw;
        for (int i = tid; i < 1024; i += 256)
            mout[base + i] = mi[base + i] ? 1 : 0;
    }
}

// ---------------------------------------------------------------------------
// Kernel 1: split x -> bf16 hi/lo
__global__ __launch_bounds__(256) void split_x_kernel(
    const float* __restrict__ x, ushort_t* __restrict__ xhi,
    ushort_t* __restrict__ xlo) {
    int idx = blockIdx.x * 256 + threadIdx.x;
    float4 v = ((const float4*)x)[idx];
    ushort4 h, l;
    h.x = f2bf(v.x); l.x = f2bf(v.x - bf2f(h.x));
    h.y = f2bf(v.y); l.y = f2bf(v.y - bf2f(h.y));
    h.z = f2bf(v.z); l.z = f2bf(v.z - bf2f(h.z));
    h.w = f2bf(v.w); l.w = f2bf(v.w - bf2f(h.w));
    ((ushort4*)xhi)[idx] = h;
    ((ushort4*)xlo)[idx] = l;
}

// Kernel 2: xbar = mean over batch of x
__global__ __launch_bounds__(256) void xbar_kernel(const float* __restrict__ x,
                                                   float* __restrict__ xbar) {
    int idx = blockIdx.x * 256 + threadIdx.x;
    float s = 0.f;
    for (int b = 0; b < NB; b++) s += x[(size_t)b * 65536 + idx];
    xbar[idx] = s * (1.0f / 64.0f);
}

// Kernel 3: build transposed+split weights BT[n][k]
__global__ __launch_bounds__(256) void wsplit_kernel(
    const float* __restrict__ Wkv, const float* __restrict__ Wg,
    const float* __restrict__ Wo, ushort_t* __restrict__ bthi,
    ushort_t* __restrict__ btlo) {
    int idx = blockIdx.x * 256 + threadIdx.x;
    int n = idx >> 8, k = idx & 255;
    float v;
    if (n < 512)      v = Wkv[(size_t)k * 512 + n];
    else if (n < 768) v = Wg[(size_t)k * 256 + (n - 512)];
    else              v = Wo[(size_t)k * 256 + (n - 768)];
    ushort_t h = f2bf(v);
    bthi[idx] = h;
    btlo[idx] = f2bf(v - bf2f(h));
}

// Kernel 4: qt = xbar @ Wq * scale, fragment-packed bf16 (hi only)
__global__ __launch_bounds__(256) void qt_gemm(const float* __restrict__ xbar,
                                               const float* __restrict__ Wq,
                                               ushort_t* __restrict__ qPh) {
    __shared__ float xrow[256];
    int i = blockIdx.x, t = threadIdx.x;
    xrow[t] = xbar[i * 256 + t];
    __syncthreads();
    float s = 0.f;
    for (int k = 0; k < 256; k++) s = fmaf(xrow[k], Wq[(size_t)k * 256 + t], s);
    s *= 0.17677669529663687f;   // 1/sqrt(32)
    int h = t >> 5, d = t & 31, lg = d >> 3, e = d & 7;
    int qb = i >> 6, nf = (i >> 4) & 3, lr = i & 15;
    int a = ((((h * 4 + qb) * 4 + nf) * 4 + lg) * 16 + lr) * 8 + e;
    qPh[a] = f2bf(s);
}

// Kernel 5: prepack bias into per-lane fragment order
__global__ __launch_bounds__(256) void bias_prepack(
    const float* __restrict__ bias, float* __restrict__ biasP) {
    int idx = blockIdx.x * 256 + threadIdx.x;   // 0..131071
    int lane = idx & 63, g = idx >> 6;
    int mf = g & 3, nf = (g >> 2) & 3, jt = (g >> 4) & 3;
    int qb = (g >> 6) & 3, h = g >> 8;
    int lr = lane & 15, lg = lane >> 4;
    float4 v = *(const float4*)(bias +
        (size_t)(h * 256 + qb * 64 + nf * 16 + lr) * 256 +
        jt * 64 + mf * 16 + lg * 4);
    *(float4*)(biasP + (size_t)idx * 4) = v;
}

// ---------------------------------------------------------------------------
// Double-buffered MFMA split-bf16 GEMM (T3-minimum 2-phase pipeline).
// TERMS=2: ah*bh + al*bh  |  TERMS=3: + ah*bl
// EPI 0: proj epilogue (K hi fragment-packed, V^T packed, gates bf16)
// EPI 1: out epilogue (C = acc + bias)
template <int EPI, int MT, int NT, int TERMS>
__global__ __launch_bounds__(256) void mfma_gemm(
    const ushort_t* __restrict__ Ahi, const ushort_t* __restrict__ Alo,
    const ushort_t* __restrict__ Bthi, const ushort_t* __restrict__ Btlo,
    const float* __restrict__ bias, float* __restrict__ C,
    ushort_t* __restrict__ kh, ushort_t* __restrict__ vP,
    ushort_t* __restrict__ gatesbf) {
    constexpr int BM = MT * 32, BN = NT * 32;
    constexpr int ASZ = BM * 32 * 2;    // bytes per A buffer
    constexpr int BSZ = BN * 32 * 2;
    constexpr int SMEM_BYTES = 4 * ASZ + 2 * BSZ +
                               ((TERMS >= 3) ? 2 * BSZ : 0);
    __shared__ __align__(16) char smem[SMEM_BYTES];
    char* aH = smem;                     // [2][ASZ]
    char* aL = smem + 2 * ASZ;           // [2][ASZ]
    char* bH = smem + 4 * ASZ;           // [2][BSZ]
    char* bL = smem + 4 * ASZ + 2 * BSZ; // [2][BSZ] (TERMS>=3)

    const int t = threadIdx.x;
    const int m0 = blockIdx.y * BM;
    const int n0 = blockIdx.x * BN;
    const int wid = t >> 6, lane = t & 63;
    const int wr = wid >> 1, wc = wid & 1;
    const int lr = lane & 15, lg = lane >> 4;

    auto STAGE = [&](int d, int ks) {
        const int k0 = ks * 32;
#pragma unroll
        for (int it = 0; it < BM / 64; ++it) {
            int c = t + it * 256;
            int row = c >> 2, sub = c & 3;
            size_t ga = (size_t)(m0 + row) * 256 + k0 + sub * 8;
            gl2lds16(Ahi + ga, aH + d * ASZ + c * 16);
            gl2lds16(Alo + ga, aL + d * ASZ + c * 16);
        }
#pragma unroll
        for (int it = 0; it < BN / 64; ++it) {
            int c = t + it * 256;
            int row = c >> 2, sub = c & 3;
            size_t gb = (size_t)(n0 + row) * 256 + k0 + sub * 8;
            gl2lds16(Bthi + gb, bH + d * BSZ + c * 16);
            if constexpr (TERMS >= 3)
                gl2lds16(Btlo + gb, bL + d * BSZ + c * 16);
        }
    };

    f32x4 acc[MT][NT] = {};

    STAGE(0, 0);
    asm volatile("s_waitcnt vmcnt(0)" ::: "memory");
    __syncthreads();

    int cur = 0;
    for (int ks = 0; ks < 8; ++ks) {
        if (ks < 7) STAGE(cur ^ 1, ks + 1);

        const ushort_t* Ap = (const ushort_t*)(aH + cur * ASZ);
        const ushort_t* ALp = (const ushort_t*)(aL + cur * ASZ);
        const ushort_t* Bp = (const ushort_t*)(bH + cur * BSZ);
        const ushort_t* BLp = (const ushort_t*)(bL + cur * BSZ);

        short8v ah[MT], al[MT], bh[NT], bl[NT];
#pragma unroll
        for (int m = 0; m < MT; m++) {
            int off = (wr * (MT * 16) + m * 16 + lr) * 32 + lg * 8;
            ah[m] = *(const short8v*)&Ap[off];
            al[m] = *(const short8v*)&ALp[off];
        }
#pragma unroll
        for (int n = 0; n < NT; n++) {
            int off = (wc * (NT * 16) + n * 16 + lr) * 32 + lg * 8;
            bh[n] = *(const short8v*)&Bp[off];
            if constexpr (TERMS >= 3) bl[n] = *(const short8v*)&BLp[off];
        }
#pragma unroll
        for (int m = 0; m < MT; m++)
#pragma unroll
            for (int n = 0; n < NT; n++) {
                acc[m][n] = __builtin_amdgcn_mfma_f32_16x16x32_bf16(
                    ah[m], bh[n], acc[m][n], 0, 0, 0);
                acc[m][n] = __builtin_amdgcn_mfma_f32_16x16x32_bf16(
                    al[m], bh[n], acc[m][n], 0, 0, 0);
                if constexpr (TERMS >= 3)
                    acc[m][n] = __builtin_amdgcn_mfma_f32_16x16x32_bf16(
                        ah[m], bl[n], acc[m][n], 0, 0, 0);
            }

        if (ks < 7) {
            asm volatile("s_waitcnt vmcnt(0)" ::: "memory");
            __syncthreads();
        }
        cur ^= 1;
    }

#pragma unroll
    for (int m = 0; m < MT; m++)
#pragma unroll
        for (int n = 0; n < NT; n++) {
            int gr0 = m0 + wr * (MT * 16) + m * 16 + lg * 4;
            int gc = n0 + wc * (NT * 16) + n * 16 + lr;
            if (EPI == 0) {
                if (gc < 256) {          // K: fragment-packed, hi only
                    int hh_ = gc >> 5, dk = gc & 31;
                    int lgk = dk >> 3, ek = dk & 7;
#pragma unroll
                    for (int r = 0; r < 4; r++) {
                        int gr = gr0 + r;
                        int bb = gr >> 8, j = gr & 255;
                        int jt = j >> 6, mfk = (j >> 4) & 3, lrk = j & 15;
                        size_t a =
                            (((((size_t)(bb * 8 + hh_) * 4 + jt) * 4 + mfk) * 4
                              + lgk) * 16 + lrk) * 8 + ek;
                        kh[a] = f2bf(acc[m][n][r]);
                    }
                } else if (gc < 512) {   // V^T: fragment-packed hi only
                    int cc = gc - 256;
                    int hh_ = cc >> 5, dv = cc & 31;
                    int mfv = dv >> 4, lrv = dv & 15;
                    int gr = gr0;
                    int bb = gr >> 8, j = gr & 255;
                    int jt = j >> 6, hbv = (j >> 5) & 1;
                    int lgv = (j >> 3) & 3, ev = j & 7;
                    size_t a =
                        ((((((size_t)(bb * 8 + hh_) * 4 + jt) * 2 + hbv) * 2
                           + mfv) * 4 + lgv) * 16 + lrv) * 8 + ev;
                    ushort4 hv;
                    hv.x = f2bf(acc[m][n][0]);
                    hv.y = f2bf(acc[m][n][1]);
                    hv.z = f2bf(acc[m][n][2]);
                    hv.w = f2bf(acc[m][n][3]);
                    *(ushort4*)(vP + a) = hv;
                } else {                 // gates: bf16
#pragma unroll
                    for (int r = 0; r < 4; r++) {
                        float v = acc[m][n][r];
                        float g = 1.f / (1.f + __expf(-(v + bias[gc - 512])));
                        gatesbf[(size_t)(gr0 + r) * 256 + (gc - 512)] = f2bf(g);
                    }
                }
            } else {
#pragma unroll
                for (int r = 0; r < 4; r++)
                    C[(size_t)(gr0 + r) * 256 + gc] = acc[m][n][r] + bias[gc];
            }
        }
}

// ---------------------------------------------------------------------------
// Split-KV MFMA flash attention, fully-coalesced fragment loads.
// QK^T 1-term (scores are bias-dominated; q_tied is tiny after 64-row mean).
__global__ __launch_bounds__(256) void attn_mfma_kernel(
    const ushort_t* __restrict__ qPh, const ushort_t* __restrict__ kh,
    const ushort_t* __restrict__ vP, const ushort_t* __restrict__ gatesbf,
    const float* __restrict__ biasP, const int* __restrict__ mask,
    ushort_t* __restrict__ atthi, ushort_t* __restrict__ attlo) {
    __shared__ __align__(16) char lds[38912];
    const int bid = blockIdx.x;
    const int sid = ((bid & 7) << 8) | (bid >> 3);   // XCD-chunked swizzle
    const int b = sid >> 5;
    const int h = (sid >> 2) & 7;
    const int qb = sid & 3;
    const int t = threadIdx.x;
    const int wid = t >> 6, lane = t & 63;
    const int lr = lane & 15, lg = lane >> 4;
    const int i0 = qb * 64;

    ushort_t* pbh = (ushort_t*)(lds + wid * 5120);
    float* accb = (float*)lds;
    float2* mlb = (float2*)(lds + 36864);

    // ---- all global loads coalesced; issue early ----
    uint4 gatev;
    {
        int q = t >> 2, dg = t & 3;
        size_t gbase = ((size_t)(b * 256 + i0 + q)) * 256 + h * 32 + dg * 8;
        gatev = *(const uint4*)(gatesbf + gbase);
    }
    short8v qfh[4];
#pragma unroll
    for (int nf = 0; nf < 4; nf++) {
        size_t off = ((((size_t)(h * 4 + qb) * 4 + nf) * 4 + lg) * 16 + lr) * 8;
        qfh[nf] = *(const short8v*)(qPh + off);
    }
    short8v kfh[4];
#pragma unroll
    for (int mf = 0; mf < 4; mf++) {
        size_t off = ((((((size_t)(b * 8 + h)) * 4 + wid) * 4 + mf) * 4 + lg) * 16 + lr) * 8;
        kfh[mf] = *(const short8v*)(kh + off);
    }
    short8v vfh[2][2];
#pragma unroll
    for (int hb = 0; hb < 2; hb++)
#pragma unroll
        for (int mf = 0; mf < 2; mf++) {
            size_t off = (((((((size_t)(b * 8 + h)) * 4 + wid) * 2 + hb) * 2 + mf) * 4 + lg) * 16 + lr) * 8;
            vfh[hb][mf] = *(const short8v*)(vP + off);
        }
    int mi[4];
#pragma unroll
    for (int nf = 0; nf < 4; nf++)
        mi[nf] = mask[b * 256 + i0 + nf * 16 + lr];
    int4 mj[4];
#pragma unroll
    for (int mf = 0; mf < 4; mf++)
        mj[mf] = *(const int4*)(mask + b * 256 + wid * 64 + mf * 16 + lg * 4);

    // ---- S^T = K * Q^T (1-term) ----
    f32x4 s[4][4];
#pragma unroll
    for (int mf = 0; mf < 4; mf++)
#pragma unroll
        for (int nf = 0; nf < 4; nf++) {
            f32x4 a = {};
            s[mf][nf] = __builtin_amdgcn_mfma_f32_16x16x32_bf16(
                kfh[mf], qfh[nf], a, 0, 0, 0);
        }

    // ---- bias (prepacked, coalesced) + mask ----
    const float* bbase = biasP +
        ((size_t)((h * 4 + qb) * 4 + wid) * 16) * 256 + lane * 4;
#pragma unroll
    for (int nf = 0; nf < 4; nf++) {
        int okn = mi[nf];
#pragma unroll
        for (int mf = 0; mf < 4; mf++) {
            float4 bv = *(const float4*)(bbase + (size_t)(nf * 4 + mf) * 256);
            s[mf][nf][0] = (okn && mj[mf].x) ? s[mf][nf][0] + bv.x : NEG_MAX;
            s[mf][nf][1] = (okn && mj[mf].y) ? s[mf][nf][1] + bv.y : NEG_MAX;
            s[mf][nf][2] = (okn && mj[mf].z) ? s[mf][nf][2] + bv.z : NEG_MAX;
            s[mf][nf][3] = (okn && mj[mf].w) ? s[mf][nf][3] + bv.w : NEG_MAX;
        }
    }

    // ---- tile softmax ----
    float mnew[4], lsum[4];
#pragma unroll
    for (int nf = 0; nf < 4; nf++) {
        float tm = s[0][nf][0];
#pragma unroll
        for (int mf = 0; mf < 4; mf++)
#pragma unroll
            for (int r = 0; r < 4; r++) tm = fmaxf(tm, s[mf][nf][r]);
        tm = fmaxf(tm, __shfl_xor(tm, 16));
        tm = fmaxf(tm, __shfl_xor(tm, 32));
        mnew[nf] = tm;
    }
#pragma unroll
    for (int nf = 0; nf < 4; nf++) {
        float ls = 0.f;
#pragma unroll
        for (int mf = 0; mf < 4; mf++)
#pragma unroll
            for (int r = 0; r < 4; r++) {
                float w = __expf(s[mf][nf][r] - mnew[nf]);
                s[mf][nf][r] = w;
                ls += w;
            }
        ls += __shfl_xor(ls, 16);
        ls += __shfl_xor(ls, 32);
        lsum[nf] = ls;
    }

    // ---- PV: P (bf16 hi) via per-wave LDS, O^T = V^T P^T ----
    f32x4 acc_o[2][4] = {};
#pragma unroll
    for (int hb = 0; hb < 2; ++hb) {
#pragma unroll
        for (int mq = 0; mq < 2; mq++) {
            int mf = hb * 2 + mq;
#pragma unroll
            for (int nf = 0; nf < 4; nf++) {
                uint2 hv;
                hv.x = (uint_t)f2bf(s[mf][nf][0]) | ((uint_t)f2bf(s[mf][nf][1]) << 16);
                hv.y = (uint_t)f2bf(s[mf][nf][2]) | ((uint_t)f2bf(s[mf][nf][3]) << 16);
                *(uint2*)(pbh + (nf * 16 + lr) * 40 + mq * 16 + lg * 4) = hv;
            }
        }
        asm volatile("s_waitcnt lgkmcnt(0)" ::: "memory");
        __builtin_amdgcn_sched_barrier(0);
#pragma unroll
        for (int nf = 0; nf < 4; nf++) {
            short8v ph = *(const short8v*)(pbh + (nf * 16 + lr) * 40 + lg * 8);
#pragma unroll
            for (int mf = 0; mf < 2; mf++)
                acc_o[mf][nf] = __builtin_amdgcn_mfma_f32_16x16x32_bf16(
                    vfh[hb][mf], ph, acc_o[mf][nf], 0, 0, 0);
        }
    }

    // ---- block-level merge ----
    __syncthreads();
    if (lg == 0) {
#pragma unroll
        for (int nf = 0; nf < 4; nf++)
            mlb[wid * 64 + nf * 16 + lr] = make_float2(mnew[nf], lsum[nf]);
    }
    __syncthreads();

    float scale_own[4];
#pragma unroll
    for (int nf = 0; nf < 4; nf++) {
        float M = NEG_MAX;
#pragma unroll
        for (int w = 0; w < 4; w++)
            M = fmaxf(M, mlb[w * 64 + nf * 16 + lr].x);
        scale_own[nf] = __expf(mnew[nf] - M);
    }
#pragma unroll
    for (int mf = 0; mf < 2; mf++)
#pragma unroll
        for (int nf = 0; nf < 4; nf++) {
            f32x4 v = acc_o[mf][nf];
            v[0] *= scale_own[nf]; v[1] *= scale_own[nf];
            v[2] *= scale_own[nf]; v[3] *= scale_own[nf];
            *(f32x4*)&accb[(size_t)(wid * 64 + nf * 16 + lr) * 36 +
                           mf * 16 + lg * 4] = v;
        }
    __syncthreads();

    // ---- output: thread -> (q = t>>2, dgroup = t&3) ----
    {
        int q = t >> 2, dg = t & 3;
        float2 ml[4];
        float M = NEG_MAX;
#pragma unroll
        for (int w = 0; w < 4; w++) {
            ml[w] = mlb[w * 64 + q];
            M = fmaxf(M, ml[w].x);
        }
        float L = 0.f;
#pragma unroll
        for (int w = 0; w < 4; w++) L += ml[w].y * __expf(ml[w].x - M);
        float invL = 1.0f / L;
        f32x4 o0 = {}, o1 = {};
#pragma unroll
        for (int w = 0; w < 4; w++) {
            const float* p = &accb[(size_t)(w * 64 + q) * 36 + dg * 8];
            o0 += *(const f32x4*)p;
            o1 += *(const f32x4*)(p + 4);
        }
        float g[8];
        g[0] = bf2f((ushort_t)(gatev.x & 0xffff));
        g[1] = bf2f((ushort_t)(gatev.x >> 16));
        g[2] = bf2f((ushort_t)(gatev.y & 0xffff));
        g[3] = bf2f((ushort_t)(gatev.y >> 16));
        g[4] = bf2f((ushort_t)(gatev.z & 0xffff));
        g[5] = bf2f((ushort_t)(gatev.z >> 16));
        g[6] = bf2f((ushort_t)(gatev.w & 0xffff));
        g[7] = bf2f((ushort_t)(gatev.w >> 16));
        float v0 = o0[0] * invL * g[0], v1 = o0[1] * invL * g[1];
        float v2 = o0[2] * invL * g[2], v3 = o0[3] * invL * g[3];
        float v4 = o1[0] * invL * g[4], v5 = o1[1] * invL * g[5];
        float v6 = o1[2] * invL * g[6], v7 = o1[3] * invL * g[7];
        size_t base = ((size_t)(b * 256 + i0 + q)) * 256 + h * 32 + dg * 8;
        ushort4 hh0, ll0, hh1, ll1;
        hh0.x = f2bf(v0); ll0.x = f2bf(v0 - bf2f(hh0.x));
        hh0.y = f2bf(v1); ll0.y = f2bf(v1 - bf2f(hh0.y));
        hh0.z = f2bf(v2); ll0.z = f2bf(v2 - bf2f(hh0.z));
        hh0.w = f2bf(v3); ll0.w = f2bf(v3 - bf2f(hh0.w));
        hh1.x = f2bf(v4); ll1.x = f2bf(v4 - bf2f(hh1.x));
        hh1.y = f2bf(v5); ll1.y = f2bf(v5 - bf2f(hh1.y));
        hh1.z = f2bf(v6); ll1.z = f2bf(v6 - bf2f(hh1.z));
        hh1.w = f2bf(v7); ll1.w = f2bf(v7 - bf2f(hh1.w));
        *(ushort4*)(atthi + base) = hh0;
        *(ushort4*)(atthi + base + 4) = hh1;
        *(ushort4*)(attlo + base) = ll0;
        *(ushort4*)(attlo + base + 4) = ll1;
    }
}

// ---------------------------------------------------------------------------
extern "C" void kernel_launch(void* const* d_in, const int* in_sizes, int n_in,
                              void* d_out, int out_size, void* d_ws, size_t ws_size,
                              hipStream_t stream) {
    const float* x    = (const float*)d_in[0];
    const unsigned char* mraw = (const unsigned char*)d_in[1];
    const float* bias = (const float*)d_in[2];
    const float* Wq   = (const float*)d_in[3];
    const float* Wkv  = (const float*)d_in[4];
    const float* Wg   = (const float*)d_in[5];
    const float* bg   = (const float*)d_in[6];
    const float* Wo   = (const float*)d_in[7];
    const float* bo   = (const float*)d_in[8];

    float* ws = (float*)d_ws;
    ushort_t* kh     = (ushort_t*)(ws + OFF_KH);
    ushort_t* vP     = (ushort_t*)(ws + OFF_VP);
    ushort_t* gatesb = (ushort_t*)(ws + OFF_GATES);
    ushort_t* xhi    = (ushort_t*)(ws + OFF_XHI);
    ushort_t* xlo    = (ushort_t*)(ws + OFF_XLO);
    ushort_t* atthi  = (ushort_t*)(ws + OFF_ATTHI);  // aliases xhi (dead)
    ushort_t* attlo  = (ushort_t*)(ws + OFF_ATTLO);
    ushort_t* bthi   = (ushort_t*)(ws + OFF_BTHI);
    ushort_t* btlo   = (ushort_t*)(ws + OFF_BTLO);
    ushort_t* qPh    = (ushort_t*)(ws + OFF_QTH);
    float*    xbar   = ws + OFF_XBAR;
    float*    biasP  = ws + OFF_BIASP;
    int*      maskc  = (int*)(ws + OFF_MASK);

    hipLaunchKernelGGL(mask_canon_kernel, dim3(16), dim3(256), 0, stream, mraw, maskc);
    hipLaunchKernelGGL(split_x_kernel, dim3(4096), dim3(256), 0, stream, x, xhi, xlo);
    hipLaunchKernelGGL(xbar_kernel, dim3(256), dim3(256), 0, stream, x, xbar);
    hipLaunchKernelGGL(wsplit_kernel, dim3(1024), dim3(256), 0, stream,
                       Wkv, Wg, Wo, bthi, btlo);
    hipLaunchKernelGGL(qt_gemm, dim3(256), dim3(256), 0, stream, xbar, Wq, qPh);
    hipLaunchKernelGGL(bias_prepack, dim3(512), dim3(256), 0, stream, bias, biasP);
    // proj: M=16384, N=768 (K | V^T | gates), 128x128 tiles, 2-term, dbuf
    hipLaunchKernelGGL((mfma_gemm<0, 4, 4, 2>), dim3(6, 128), dim3(256), 0, stream,
                       xhi, xlo, bthi, btlo, bg, (float*)nullptr,
                       kh, vP, gatesb);
    hipLaunchKernelGGL(attn_mfma_kernel, dim3(2048), dim3(256), 0, stream,
                       qPh, kh, vP, gatesb, biasP, maskc, atthi, attlo);
    // out = att @ Wo + bo : M=16384, N=256, 64x64 tiles, 3-term, dbuf
    hipLaunchKernelGGL((mfma_gemm<1, 2, 2, 3>), dim3(4, 256), dim3(256), 0, stream,
                       atthi, attlo, bthi + 768 * 256, btlo + 768 * 256, bo,
                       (float*)d_out, nullptr, nullptr, nullptr);
}

// Round 10
// 111.422 us; speedup vs baseline: 2.5335x; 1.1580x over previous
//
#include <hip/hip_runtime.h>
#include <math.h>

typedef unsigned short ushort_t;
typedef unsigned int uint_t;
typedef __attribute__((ext_vector_type(8))) short short8v;   // 8 bf16 (4 VGPR)
typedef __attribute__((ext_vector_type(4))) float f32x4;

#define NEG_MAX (-3.402823466e+38f)

// -------- ws layout (float offsets) --------
#define OFF_KH    0
#define OFF_VP    4194304
#define OFF_GATES 6291456
#define OFF_XHI   8388608
#define OFF_XLO   10485760
#define OFF_ATTHI OFF_XHI
#define OFF_ATTLO OFF_XLO
#define OFF_BTHI  12582912
#define OFF_BTLO  12713984
#define OFF_QTH   12845056
#define OFF_XBAR  12910592
#define OFF_BIASP 12976128
#define OFF_MASK  13500416

// ---------------------------------------------------------------------------
__device__ __forceinline__ ushort_t f2bf(float x) {
    uint_t u = __float_as_uint(x);
    u = (u + 0x7fffu + ((u >> 16) & 1u)) >> 16;   // RNE
    return (ushort_t)u;
}
__device__ __forceinline__ float bf2f(ushort_t u) {
    return __uint_as_float(((uint_t)u) << 16);
}
__device__ __forceinline__ void gl2lds16(const void* g, void* l) {
    typedef const __attribute__((address_space(1))) uint32_t* gptr_t;
    typedef __attribute__((address_space(3))) uint32_t* lptr_t;
    __builtin_amdgcn_global_load_lds((gptr_t)(uintptr_t)g,
                                     (lptr_t)(uintptr_t)l, 16, 0, 0);
}

// ---------------------------------------------------------------------------
// Fused prep kernel. Block ranges:
// [0,4096) split_x | [4096,4112) mask canon | [4112,5136) wsplit
// [5136,5648) bias_prepack | [5648,5904) xbar
__global__ __launch_bounds__(256) void prep_kernel(
    const float* __restrict__ x, const unsigned char* __restrict__ mraw,
    const float* __restrict__ bias, const float* __restrict__ Wkv,
    const float* __restrict__ Wg, const float* __restrict__ Wo,
    ushort_t* __restrict__ xhi, ushort_t* __restrict__ xlo,
    int* __restrict__ maskc, float* __restrict__ xbar,
    ushort_t* __restrict__ bthi, ushort_t* __restrict__ btlo,
    float* __restrict__ biasP) {
    __shared__ int cnt[256];
    const int bid = blockIdx.x, t = threadIdx.x;
    if (bid < 4096) {                         // ---- split_x ----
        int idx = bid * 256 + t;
        float4 v = ((const float4*)x)[idx];
        ushort4 h, l;
        h.x = f2bf(v.x); l.x = f2bf(v.x - bf2f(h.x));
        h.y = f2bf(v.y); l.y = f2bf(v.y - bf2f(h.y));
        h.z = f2bf(v.z); l.z = f2bf(v.z - bf2f(h.z));
        h.w = f2bf(v.w); l.w = f2bf(v.w - bf2f(h.w));
        ((ushort4*)xhi)[idx] = h;
        ((ushort4*)xlo)[idx] = l;
    } else if (bid < 4112) {                  // ---- mask canon ----
        int c = 0;
        for (int i = t; i < 4096; i += 256)
            if ((i & 3) != 0 && mraw[i] != 0) c++;
        cnt[t] = c;
        __syncthreads();
        for (int s = 128; s > 0; s >>= 1) {
            if (t < s) cnt[t] += cnt[t + s];
            __syncthreads();
        }
        int isBool = cnt[0] > 16;
        int base = (bid - 4096) * 1024;
        if (isBool) {
            for (int i = t; i < 1024; i += 256)
                maskc[base + i] = mraw[base + i] ? 1 : 0;
        } else {
            const int* mi = (const int*)mraw;
            for (int i = t; i < 1024; i += 256)
                maskc[base + i] = mi[base + i] ? 1 : 0;
        }
    } else if (bid < 5136) {                  // ---- wsplit ----
        int idx = (bid - 4112) * 256 + t;
        int n = idx >> 8, k = idx & 255;
        float v;
        if (n < 512)      v = Wkv[(size_t)k * 512 + n];
        else if (n < 768) v = Wg[(size_t)k * 256 + (n - 512)];
        else              v = Wo[(size_t)k * 256 + (n - 768)];
        ushort_t h = f2bf(v);
        bthi[idx] = h;
        btlo[idx] = f2bf(v - bf2f(h));
    } else if (bid < 5648) {                  // ---- bias prepack ----
        int idx = (bid - 5136) * 256 + t;     // 0..131071
        int lane = idx & 63, g2 = idx >> 6;   // g2 0..2047
        int mf = g2 & 3, nf = (g2 >> 2) & 1, jt = (g2 >> 3) & 3;
        int iq = (g2 >> 5) & 7, h = g2 >> 8;
        int lr = lane & 15, lg = lane >> 4;
        float4 v = *(const float4*)(bias +
            (size_t)(h * 256 + iq * 32 + nf * 16 + lr) * 256 +
            jt * 64 + mf * 16 + lg * 4);
        *(float4*)(biasP + (size_t)idx * 4) = v;
    } else {                                  // ---- xbar ----
        int idx = (bid - 5648) * 256 + t;
        float s0 = 0.f, s1 = 0.f, s2 = 0.f, s3 = 0.f;
#pragma unroll
        for (int b8 = 0; b8 < 64; b8 += 4) {
            s0 += x[(size_t)b8 * 65536 + idx];
            s1 += x[(size_t)(b8 + 1) * 65536 + idx];
            s2 += x[(size_t)(b8 + 2) * 65536 + idx];
            s3 += x[(size_t)(b8 + 3) * 65536 + idx];
        }
        xbar[idx] = ((s0 + s1) + (s2 + s3)) * (1.0f / 64.0f);
    }
}

// ---------------------------------------------------------------------------
// qt = xbar @ Wq * scale, fragment-packed bf16 hi
__global__ __launch_bounds__(256) void qt_gemm(const float* __restrict__ xbar,
                                               const float* __restrict__ Wq,
                                               ushort_t* __restrict__ qPh) {
    __shared__ float xrow[256];
    int i = blockIdx.x, t = threadIdx.x;
    xrow[t] = xbar[i * 256 + t];
    __syncthreads();
    float s = 0.f;
    for (int k = 0; k < 256; k++) s = fmaf(xrow[k], Wq[(size_t)k * 256 + t], s);
    s *= 0.17677669529663687f;   // 1/sqrt(32)
    int h = t >> 5, d = t & 31, lg = d >> 3, e = d & 7;
    int g = i >> 4, lr = i & 15;                 // g = i>>4 (0..15)
    int a = (((h * 16 + g) * 4 + lg) * 16 + lr) * 8 + e;
    qPh[a] = f2bf(s);
}

// ---------------------------------------------------------------------------
// Double-buffered MFMA split-bf16 GEMM, 1-D XCD-swizzled grid.
// TERMS=2: ah*bh + al*bh | TERMS=3: + ah*bl
template <int EPI, int MT, int NT, int TERMS>
__global__ __launch_bounds__(256) void mfma_gemm(
    const ushort_t* __restrict__ Ahi, const ushort_t* __restrict__ Alo,
    const ushort_t* __restrict__ Bthi, const ushort_t* __restrict__ Btlo,
    const float* __restrict__ bias, float* __restrict__ C,
    ushort_t* __restrict__ kh, ushort_t* __restrict__ vP,
    ushort_t* __restrict__ gatesbf, int gridn) {
    constexpr int BM = MT * 32, BN = NT * 32;
    constexpr int ASZ = BM * 32 * 2;
    constexpr int BSZ = BN * 32 * 2;
    constexpr int SMEM_BYTES = 4 * ASZ + 2 * BSZ + ((TERMS >= 3) ? 2 * BSZ : 0);
    __shared__ __align__(16) char smem[SMEM_BYTES];
    char* aH = smem;
    char* aL = smem + 2 * ASZ;
    char* bH = smem + 4 * ASZ;
    char* bL = smem + 4 * ASZ + 2 * BSZ;

    const int t = threadIdx.x;
    const int nwg = gridDim.x, cpx = nwg >> 3;
    const int bid = blockIdx.x;
    const int sid = (bid & 7) * cpx + (bid >> 3);   // XCD-chunked
    const int m0 = (sid / gridn) * BM;
    const int n0 = (sid % gridn) * BN;
    const int wid = t >> 6, lane = t & 63;
    const int wr = wid >> 1, wc = wid & 1;
    const int lr = lane & 15, lg = lane >> 4;

    auto STAGE = [&](int d, int ks) {
        const int k0 = ks * 32;
#pragma unroll
        for (int it = 0; it < BM / 64; ++it) {
            int c = t + it * 256;
            int row = c >> 2, sub = c & 3;
            size_t ga = (size_t)(m0 + row) * 256 + k0 + sub * 8;
            gl2lds16(Ahi + ga, aH + d * ASZ + c * 16);
            gl2lds16(Alo + ga, aL + d * ASZ + c * 16);
        }
#pragma unroll
        for (int it = 0; it < BN / 64; ++it) {
            int c = t + it * 256;
            int row = c >> 2, sub = c & 3;
            size_t gb = (size_t)(n0 + row) * 256 + k0 + sub * 8;
            gl2lds16(Bthi + gb, bH + d * BSZ + c * 16);
            if constexpr (TERMS >= 3)
                gl2lds16(Btlo + gb, bL + d * BSZ + c * 16);
        }
    };

    f32x4 acc[MT][NT] = {};

    STAGE(0, 0);
    asm volatile("s_waitcnt vmcnt(0)" ::: "memory");
    __syncthreads();

    int cur = 0;
    for (int ks = 0; ks < 8; ++ks) {
        if (ks < 7) STAGE(cur ^ 1, ks + 1);

        const ushort_t* Ap = (const ushort_t*)(aH + cur * ASZ);
        const ushort_t* ALp = (const ushort_t*)(aL + cur * ASZ);
        const ushort_t* Bp = (const ushort_t*)(bH + cur * BSZ);
        const ushort_t* BLp = (const ushort_t*)(bL + cur * BSZ);

        short8v ah[MT], al[MT], bh[NT], bl[NT];
#pragma unroll
        for (int m = 0; m < MT; m++) {
            int off = (wr * (MT * 16) + m * 16 + lr) * 32 + lg * 8;
            ah[m] = *(const short8v*)&Ap[off];
            al[m] = *(const short8v*)&ALp[off];
        }
#pragma unroll
        for (int n = 0; n < NT; n++) {
            int off = (wc * (NT * 16) + n * 16 + lr) * 32 + lg * 8;
            bh[n] = *(const short8v*)&Bp[off];
            if constexpr (TERMS >= 3) bl[n] = *(const short8v*)&BLp[off];
        }
#pragma unroll
        for (int m = 0; m < MT; m++)
#pragma unroll
            for (int n = 0; n < NT; n++) {
                acc[m][n] = __builtin_amdgcn_mfma_f32_16x16x32_bf16(
                    ah[m], bh[n], acc[m][n], 0, 0, 0);
                acc[m][n] = __builtin_amdgcn_mfma_f32_16x16x32_bf16(
                    al[m], bh[n], acc[m][n], 0, 0, 0);
                if constexpr (TERMS >= 3)
                    acc[m][n] = __builtin_amdgcn_mfma_f32_16x16x32_bf16(
                        ah[m], bl[n], acc[m][n], 0, 0, 0);
            }

        if (ks < 7) {
            asm volatile("s_waitcnt vmcnt(0)" ::: "memory");
            __syncthreads();
        }
        cur ^= 1;
    }

#pragma unroll
    for (int m = 0; m < MT; m++)
#pragma unroll
        for (int n = 0; n < NT; n++) {
            int gr0 = m0 + wr * (MT * 16) + m * 16 + lg * 4;
            int gc = n0 + wc * (NT * 16) + n * 16 + lr;
            if (EPI == 0) {
                if (gc < 256) {          // K fragment-packed, hi only
                    int hh_ = gc >> 5, dk = gc & 31;
                    int lgk = dk >> 3, ek = dk & 7;
#pragma unroll
                    for (int r = 0; r < 4; r++) {
                        int gr = gr0 + r;
                        int bb = gr >> 8, j = gr & 255;
                        int jt = j >> 6, mfk = (j >> 4) & 3, lrk = j & 15;
                        size_t a =
                            (((((size_t)(bb * 8 + hh_) * 4 + jt) * 4 + mfk) * 4
                              + lgk) * 16 + lrk) * 8 + ek;
                        kh[a] = f2bf(acc[m][n][r]);
                    }
                } else if (gc < 512) {   // V^T fragment-packed hi only
                    int cc = gc - 256;
                    int hh_ = cc >> 5, dv = cc & 31;
                    int mfv = dv >> 4, lrv = dv & 15;
                    int gr = gr0;
                    int bb = gr >> 8, j = gr & 255;
                    int jt = j >> 6, hbv = (j >> 5) & 1;
                    int lgv = (j >> 3) & 3, ev = j & 7;
                    size_t a =
                        ((((((size_t)(bb * 8 + hh_) * 4 + jt) * 2 + hbv) * 2
                           + mfv) * 4 + lgv) * 16 + lrv) * 8 + ev;
                    ushort4 hv;
                    hv.x = f2bf(acc[m][n][0]);
                    hv.y = f2bf(acc[m][n][1]);
                    hv.z = f2bf(acc[m][n][2]);
                    hv.w = f2bf(acc[m][n][3]);
                    *(ushort4*)(vP + a) = hv;
                } else {                 // gates bf16
#pragma unroll
                    for (int r = 0; r < 4; r++) {
                        float v = acc[m][n][r];
                        float g = 1.f / (1.f + __expf(-(v + bias[gc - 512])));
                        gatesbf[(size_t)(gr0 + r) * 256 + (gc - 512)] = f2bf(g);
                    }
                }
            } else {
#pragma unroll
                for (int r = 0; r < 4; r++)
                    C[(size_t)(gr0 + r) * 256 + gc] = acc[m][n][r] + bias[gc];
            }
        }
}

// ---------------------------------------------------------------------------
// Per-wave online MFMA flash attention. Block = (b, h, q-half of 128);
// wave w owns 32 q-rows, loops 4 KV tiles with online softmax. NO barriers.
__global__ __launch_bounds__(256) void attn_mfma_kernel(
    const ushort_t* __restrict__ qPh, const ushort_t* __restrict__ kh,
    const ushort_t* __restrict__ vP, const ushort_t* __restrict__ gatesbf,
    const float* __restrict__ biasP, const int* __restrict__ mask,
    ushort_t* __restrict__ atthi, ushort_t* __restrict__ attlo) {
    __shared__ __align__(16) ushort_t Pb[4][32 * 40];
    const int bid = blockIdx.x;
    const int sid = ((bid & 7) << 7) | (bid >> 3);   // 1024 = 8*128
    const int b = sid >> 4;
    const int h = (sid >> 1) & 7;
    const int qh = sid & 1;
    const int t = threadIdx.x;
    const int w = t >> 6, lane = t & 63;
    const int lr = lane & 15, lg = lane >> 4;
    const int i0 = qh * 128 + w * 32;
    const int iq = i0 >> 5;                          // qh*4 + w
    ushort_t* pbh = Pb[w];

    short8v qfh[2];
#pragma unroll
    for (int nf = 0; nf < 2; nf++) {
        int g = qh * 8 + w * 2 + nf;                 // i>>4 group (0..15)
        size_t off = ((((size_t)h * 16 + g) * 4 + lg) * 16 + lr) * 8;
        qfh[nf] = *(const short8v*)(qPh + off);
    }
    int mi[2];
#pragma unroll
    for (int nf = 0; nf < 2; nf++)
        mi[nf] = mask[b * 256 + i0 + nf * 16 + lr];

    float m_run[2] = {NEG_MAX, NEG_MAX};
    float l_run[2] = {0.f, 0.f};
    f32x4 acc_o[2][2] = {};

    for (int jt = 0; jt < 4; ++jt) {
        short8v kfh[4];
#pragma unroll
        for (int mf = 0; mf < 4; mf++) {
            size_t off = (((((size_t)(b * 8 + h) * 4 + jt) * 4 + mf) * 4 + lg)
                          * 16 + lr) * 8;
            kfh[mf] = *(const short8v*)(kh + off);
        }
        int4 mj[4];
#pragma unroll
        for (int mf = 0; mf < 4; mf++)
            mj[mf] = *(const int4*)(mask + b * 256 + jt * 64 + mf * 16 + lg * 4);

        // S^T = K * Q^T (1-term)
        f32x4 s[4][2];
#pragma unroll
        for (int mf = 0; mf < 4; mf++)
#pragma unroll
            for (int nf = 0; nf < 2; nf++) {
                f32x4 a = {};
                s[mf][nf] = __builtin_amdgcn_mfma_f32_16x16x32_bf16(
                    kfh[mf], qfh[nf], a, 0, 0, 0);
            }

        // bias (prepacked) + mask. biasP float offset = g2*256 + lane*4,
        // g2 = h*256 + iq*32 + jt*8 + nf*4 + mf
        const float* bb = biasP +
            ((size_t)(((h * 8 + iq) * 4 + jt) * 8) * 256 + (size_t)lane * 4);
#pragma unroll
        for (int nf = 0; nf < 2; nf++) {
            int okn = mi[nf];
#pragma unroll
            for (int mf = 0; mf < 4; mf++) {
                float4 bv = *(const float4*)(bb + (size_t)(nf * 4 + mf) * 256);
                s[mf][nf][0] = (okn && mj[mf].x) ? s[mf][nf][0] + bv.x : NEG_MAX;
                s[mf][nf][1] = (okn && mj[mf].y) ? s[mf][nf][1] + bv.y : NEG_MAX;
                s[mf][nf][2] = (okn && mj[mf].z) ? s[mf][nf][2] + bv.z : NEG_MAX;
                s[mf][nf][3] = (okn && mj[mf].w) ? s[mf][nf][3] + bv.w : NEG_MAX;
            }
        }

        // online softmax update
        float mnew[2], corr[2];
#pragma unroll
        for (int nf = 0; nf < 2; nf++) {
            float tm = s[0][nf][0];
#pragma unroll
            for (int mf = 0; mf < 4; mf++)
#pragma unroll
                for (int r = 0; r < 4; r++) tm = fmaxf(tm, s[mf][nf][r]);
            tm = fmaxf(tm, __shfl_xor(tm, 16));
            tm = fmaxf(tm, __shfl_xor(tm, 32));
            mnew[nf] = fmaxf(m_run[nf], tm);
            corr[nf] = __expf(m_run[nf] - mnew[nf]);
            m_run[nf] = mnew[nf];
        }
#pragma unroll
        for (int md = 0; md < 2; md++)
#pragma unroll
            for (int nf = 0; nf < 2; nf++)
#pragma unroll
                for (int r = 0; r < 4; r++) acc_o[md][nf][r] *= corr[nf];
#pragma unroll
        for (int nf = 0; nf < 2; nf++) {
            float ls = 0.f;
#pragma unroll
            for (int mf = 0; mf < 4; mf++)
#pragma unroll
                for (int r = 0; r < 4; r++) {
                    float wv = __expf(s[mf][nf][r] - mnew[nf]);
                    s[mf][nf][r] = wv;
                    ls += wv;
                }
            ls += __shfl_xor(ls, 16);
            ls += __shfl_xor(ls, 32);
            l_run[nf] = l_run[nf] * corr[nf] + ls;
        }

        // PV: two 32-key halves through per-wave LDS
#pragma unroll
        for (int hb = 0; hb < 2; ++hb) {
#pragma unroll
            for (int mq = 0; mq < 2; mq++) {
                int mf = hb * 2 + mq;
#pragma unroll
                for (int nf = 0; nf < 2; nf++) {
                    uint2 hv;
                    hv.x = (uint_t)f2bf(s[mf][nf][0]) |
                           ((uint_t)f2bf(s[mf][nf][1]) << 16);
                    hv.y = (uint_t)f2bf(s[mf][nf][2]) |
                           ((uint_t)f2bf(s[mf][nf][3]) << 16);
                    *(uint2*)(pbh + (nf * 16 + lr) * 40 + mq * 16 + lg * 4) = hv;
                }
            }
            asm volatile("s_waitcnt lgkmcnt(0)" ::: "memory");
            __builtin_amdgcn_sched_barrier(0);
            short8v vf[2];
#pragma unroll
            for (int mv = 0; mv < 2; mv++) {
                size_t off = ((((((size_t)(b * 8 + h) * 4 + jt) * 2 + hb) * 2
                               + mv) * 4 + lg) * 16 + lr) * 8;
                vf[mv] = *(const short8v*)(vP + off);
            }
#pragma unroll
            for (int nf = 0; nf < 2; nf++) {
                short8v ph = *(const short8v*)(pbh + (nf * 16 + lr) * 40 + lg * 8);
                acc_o[0][nf] = __builtin_amdgcn_mfma_f32_16x16x32_bf16(
                    vf[0], ph, acc_o[0][nf], 0, 0, 0);
                acc_o[1][nf] = __builtin_amdgcn_mfma_f32_16x16x32_bf16(
                    vf[1], ph, acc_o[1][nf], 0, 0, 0);
            }
        }
    }

    // epilogue: O = acc/l * gate, split bf16
    float invl[2] = {1.0f / l_run[0], 1.0f / l_run[1]};
#pragma unroll
    for (int md = 0; md < 2; md++)
#pragma unroll
        for (int nf = 0; nf < 2; nf++) {
            int i = i0 + nf * 16 + lr;
            int d0 = md * 16 + lg * 4;
            size_t base = ((size_t)(b * 256 + i)) * 256 + h * 32 + d0;
            uint2 gv = *(const uint2*)(gatesbf + base);
            float g0 = bf2f((ushort_t)(gv.x & 0xffff));
            float g1 = bf2f((ushort_t)(gv.x >> 16));
            float g2 = bf2f((ushort_t)(gv.y & 0xffff));
            float g3 = bf2f((ushort_t)(gv.y >> 16));
            float v0 = acc_o[md][nf][0] * invl[nf] * g0;
            float v1 = acc_o[md][nf][1] * invl[nf] * g1;
            float v2 = acc_o[md][nf][2] * invl[nf] * g2;
            float v3 = acc_o[md][nf][3] * invl[nf] * g3;
            ushort4 hh, ll;
            hh.x = f2bf(v0); ll.x = f2bf(v0 - bf2f(hh.x));
            hh.y = f2bf(v1); ll.y = f2bf(v1 - bf2f(hh.y));
            hh.z = f2bf(v2); ll.z = f2bf(v2 - bf2f(hh.z));
            hh.w = f2bf(v3); ll.w = f2bf(v3 - bf2f(hh.w));
            *(ushort4*)(atthi + base) = hh;
            *(ushort4*)(attlo + base) = ll;
        }
}

// ---------------------------------------------------------------------------
extern "C" void kernel_launch(void* const* d_in, const int* in_sizes, int n_in,
                              void* d_out, int out_size, void* d_ws, size_t ws_size,
                              hipStream_t stream) {
    const float* x    = (const float*)d_in[0];
    const unsigned char* mraw = (const unsigned char*)d_in[1];
    const float* bias = (const float*)d_in[2];
    const float* Wq   = (const float*)d_in[3];
    const float* Wkv  = (const float*)d_in[4];
    const float* Wg   = (const float*)d_in[5];
    const float* bg   = (const float*)d_in[6];
    const float* Wo   = (const float*)d_in[7];
    const float* bo   = (const float*)d_in[8];

    float* ws = (float*)d_ws;
    ushort_t* kh     = (ushort_t*)(ws + OFF_KH);
    ushort_t* vP     = (ushort_t*)(ws + OFF_VP);
    ushort_t* gatesb = (ushort_t*)(ws + OFF_GATES);
    ushort_t* xhi    = (ushort_t*)(ws + OFF_XHI);
    ushort_t* xlo    = (ushort_t*)(ws + OFF_XLO);
    ushort_t* atthi  = (ushort_t*)(ws + OFF_ATTHI);  // aliases xhi (dead)
    ushort_t* attlo  = (ushort_t*)(ws + OFF_ATTLO);
    ushort_t* bthi   = (ushort_t*)(ws + OFF_BTHI);
    ushort_t* btlo   = (ushort_t*)(ws + OFF_BTLO);
    ushort_t* qPh    = (ushort_t*)(ws + OFF_QTH);
    float*    xbar   = ws + OFF_XBAR;
    float*    biasP  = ws + OFF_BIASP;
    int*      maskc  = (int*)(ws + OFF_MASK);

    hipLaunchKernelGGL(prep_kernel, dim3(5904), dim3(256), 0, stream,
                       x, mraw, bias, Wkv, Wg, Wo,
                       xhi, xlo, maskc, xbar, bthi, btlo, biasP);
    hipLaunchKernelGGL(qt_gemm, dim3(256), dim3(256), 0, stream, xbar, Wq, qPh);
    // proj: M=16384, N=768, 128x128 tiles, 2-term, dbuf, XCD swizzle
    hipLaunchKernelGGL((mfma_gemm<0, 4, 4, 2>), dim3(768), dim3(256), 0, stream,
                       xhi, xlo, bthi, btlo, bg, (float*)nullptr,
                       kh, vP, gatesb, 6);
    hipLaunchKernelGGL(attn_mfma_kernel, dim3(1024), dim3(256), 0, stream,
                       qPh, kh, vP, gatesb, biasP, maskc, atthi, attlo);
    // out = att @ Wo + bo : M=16384, N=256, 64x64 tiles, 3-term, dbuf
    hipLaunchKernelGGL((mfma_gemm<1, 2, 2, 3>), dim3(1024), dim3(256), 0, stream,
                       atthi, attlo, bthi + 768 * 256, btlo + 768 * 256, bo,
                       (float*)d_out, nullptr, nullptr, nullptr, 4);
}

// Round 11
// 91.645 us; speedup vs baseline: 3.0803x; 1.2158x over previous
//
#include <hip/hip_runtime.h>
#include <math.h>

typedef unsigned short ushort_t;
typedef unsigned int uint_t;
typedef __attribute__((ext_vector_type(8))) short short8v;   // 8 bf16 (4 VGPR)
typedef __attribute__((ext_vector_type(4))) float f32x4;

#define NEG_MAX (-3.402823466e+38f)

// -------- ws layout (float offsets) --------
#define OFF_KH    0
#define OFF_VP    4194304
#define OFF_GATES 6291456
#define OFF_XHI   8388608
#define OFF_XLO   10485760
#define OFF_ATTHI OFF_XHI
#define OFF_ATTLO OFF_XLO
#define OFF_BTHI  12582912
#define OFF_BTLO  12713984
#define OFF_QTH   12845056
#define OFF_XBAR  12910592
#define OFF_BIASP 12976128
#define OFF_MASK  13500416

// ---------------------------------------------------------------------------
__device__ __forceinline__ ushort_t f2bf(float x) {
    uint_t u = __float_as_uint(x);
    u = (u + 0x7fffu + ((u >> 16) & 1u)) >> 16;   // RNE
    return (ushort_t)u;
}
__device__ __forceinline__ float bf2f(ushort_t u) {
    return __uint_as_float(((uint_t)u) << 16);
}
__device__ __forceinline__ void gl2lds16(const void* g, void* l) {
    typedef const __attribute__((address_space(1))) uint32_t* gptr_t;
    typedef __attribute__((address_space(3))) uint32_t* lptr_t;
    __builtin_amdgcn_global_load_lds((gptr_t)(uintptr_t)g,
                                     (lptr_t)(uintptr_t)l, 16, 0, 0);
}

// ---------------------------------------------------------------------------
// Fused prep kernel. Block ranges:
// [0,4096) split_x | [4096,4112) mask canon | [4112,5136) wsplit
// [5136,5648) bias_prepack | [5648,5904) xbar
__global__ __launch_bounds__(256) void prep_kernel(
    const float* __restrict__ x, const unsigned char* __restrict__ mraw,
    const float* __restrict__ bias, const float* __restrict__ Wkv,
    const float* __restrict__ Wg, const float* __restrict__ Wo,
    ushort_t* __restrict__ xhi, ushort_t* __restrict__ xlo,
    int* __restrict__ maskc, float* __restrict__ xbar,
    ushort_t* __restrict__ bthi, ushort_t* __restrict__ btlo,
    float* __restrict__ biasP) {
    __shared__ int cnt[256];
    const int bid = blockIdx.x, t = threadIdx.x;
    if (bid < 4096) {                         // ---- split_x ----
        int idx = bid * 256 + t;
        float4 v = ((const float4*)x)[idx];
        ushort4 h, l;
        h.x = f2bf(v.x); l.x = f2bf(v.x - bf2f(h.x));
        h.y = f2bf(v.y); l.y = f2bf(v.y - bf2f(h.y));
        h.z = f2bf(v.z); l.z = f2bf(v.z - bf2f(h.z));
        h.w = f2bf(v.w); l.w = f2bf(v.w - bf2f(h.w));
        ((ushort4*)xhi)[idx] = h;
        ((ushort4*)xlo)[idx] = l;
    } else if (bid < 4112) {                  // ---- mask canon ----
        int c = 0;
        for (int i = t; i < 4096; i += 256)
            if ((i & 3) != 0 && mraw[i] != 0) c++;
        cnt[t] = c;
        __syncthreads();
        for (int s = 128; s > 0; s >>= 1) {
            if (t < s) cnt[t] += cnt[t + s];
            __syncthreads();
        }
        int isBool = cnt[0] > 16;
        int base = (bid - 4096) * 1024;
        if (isBool) {
            for (int i = t; i < 1024; i += 256)
                maskc[base + i] = mraw[base + i] ? 1 : 0;
        } else {
            const int* mi = (const int*)mraw;
            for (int i = t; i < 1024; i += 256)
                maskc[base + i] = mi[base + i] ? 1 : 0;
        }
    } else if (bid < 5136) {                  // ---- wsplit ----
        int idx = (bid - 4112) * 256 + t;
        int n = idx >> 8, k = idx & 255;
        float v;
        if (n < 512)      v = Wkv[(size_t)k * 512 + n];
        else if (n < 768) v = Wg[(size_t)k * 256 + (n - 512)];
        else              v = Wo[(size_t)k * 256 + (n - 768)];
        ushort_t h = f2bf(v);
        bthi[idx] = h;
        btlo[idx] = f2bf(v - bf2f(h));
    } else if (bid < 5648) {                  // ---- bias prepack ----
        int idx = (bid - 5136) * 256 + t;     // 0..131071
        int lane = idx & 63, g2 = idx >> 6;   // g2 0..2047
        int mf = g2 & 3, nf = (g2 >> 2) & 1, jt = (g2 >> 3) & 3;
        int iq = (g2 >> 5) & 7, h = g2 >> 8;
        int lr = lane & 15, lg = lane >> 4;
        float4 v = *(const float4*)(bias +
            (size_t)(h * 256 + iq * 32 + nf * 16 + lr) * 256 +
            jt * 64 + mf * 16 + lg * 4);
        *(float4*)(biasP + (size_t)idx * 4) = v;
    } else {                                  // ---- xbar ----
        int idx = (bid - 5648) * 256 + t;
        float s0 = 0.f, s1 = 0.f, s2 = 0.f, s3 = 0.f;
#pragma unroll
        for (int b8 = 0; b8 < 64; b8 += 4) {
            s0 += x[(size_t)b8 * 65536 + idx];
            s1 += x[(size_t)(b8 + 1) * 65536 + idx];
            s2 += x[(size_t)(b8 + 2) * 65536 + idx];
            s3 += x[(size_t)(b8 + 3) * 65536 + idx];
        }
        xbar[idx] = ((s0 + s1) + (s2 + s3)) * (1.0f / 64.0f);
    }
}

// ---------------------------------------------------------------------------
// qt = xbar @ Wq * scale, fragment-packed bf16 hi
__global__ __launch_bounds__(256) void qt_gemm(const float* __restrict__ xbar,
                                               const float* __restrict__ Wq,
                                               ushort_t* __restrict__ qPh) {
    __shared__ float xrow[256];
    int i = blockIdx.x, t = threadIdx.x;
    xrow[t] = xbar[i * 256 + t];
    __syncthreads();
    float s = 0.f;
    for (int k = 0; k < 256; k++) s = fmaf(xrow[k], Wq[(size_t)k * 256 + t], s);
    s *= 0.17677669529663687f;   // 1/sqrt(32)
    int h = t >> 5, d = t & 31, lg = d >> 3, e = d & 7;
    int g = i >> 4, lr = i & 15;                 // g = i>>4 (0..15)
    int a = (((h * 16 + g) * 4 + lg) * 16 + lr) * 8 + e;
    qPh[a] = f2bf(s);
}

// ---------------------------------------------------------------------------
// Double-buffered MFMA split-bf16 GEMM, 1-D XCD-swizzled grid.
// TERMS=2: ah*bh + al*bh | TERMS=3: + ah*bl
template <int EPI, int MT, int NT, int TERMS>
__global__ __launch_bounds__(256) void mfma_gemm(
    const ushort_t* __restrict__ Ahi, const ushort_t* __restrict__ Alo,
    const ushort_t* __restrict__ Bthi, const ushort_t* __restrict__ Btlo,
    const float* __restrict__ bias, float* __restrict__ C,
    ushort_t* __restrict__ kh, ushort_t* __restrict__ vP,
    ushort_t* __restrict__ gatesP, int gridn) {
    constexpr int BM = MT * 32, BN = NT * 32;
    constexpr int ASZ = BM * 32 * 2;
    constexpr int BSZ = BN * 32 * 2;
    constexpr int SMEM_BYTES = 4 * ASZ + 2 * BSZ + ((TERMS >= 3) ? 2 * BSZ : 0);
    __shared__ __align__(16) char smem[SMEM_BYTES];
    char* aH = smem;
    char* aL = smem + 2 * ASZ;
    char* bH = smem + 4 * ASZ;
    char* bL = smem + 4 * ASZ + 2 * BSZ;

    const int t = threadIdx.x;
    const int nwg = gridDim.x, cpx = nwg >> 3;
    const int bid = blockIdx.x;
    const int sid = (bid & 7) * cpx + (bid >> 3);   // XCD-chunked
    const int m0 = (sid / gridn) * BM;
    const int n0 = (sid % gridn) * BN;
    const int wid = t >> 6, lane = t & 63;
    const int wr = wid >> 1, wc = wid & 1;
    const int lr = lane & 15, lg = lane >> 4;

    auto STAGE = [&](int d, int ks) {
        const int k0 = ks * 32;
#pragma unroll
        for (int it = 0; it < BM / 64; ++it) {
            int c = t + it * 256;
            int row = c >> 2, sub = c & 3;
            size_t ga = (size_t)(m0 + row) * 256 + k0 + sub * 8;
            gl2lds16(Ahi + ga, aH + d * ASZ + c * 16);
            gl2lds16(Alo + ga, aL + d * ASZ + c * 16);
        }
#pragma unroll
        for (int it = 0; it < BN / 64; ++it) {
            int c = t + it * 256;
            int row = c >> 2, sub = c & 3;
            size_t gb = (size_t)(n0 + row) * 256 + k0 + sub * 8;
            gl2lds16(Bthi + gb, bH + d * BSZ + c * 16);
            if constexpr (TERMS >= 3)
                gl2lds16(Btlo + gb, bL + d * BSZ + c * 16);
        }
    };

    f32x4 acc[MT][NT] = {};

    STAGE(0, 0);
    asm volatile("s_waitcnt vmcnt(0)" ::: "memory");
    __syncthreads();

    int cur = 0;
    for (int ks = 0; ks < 8; ++ks) {
        if (ks < 7) STAGE(cur ^ 1, ks + 1);

        const ushort_t* Ap = (const ushort_t*)(aH + cur * ASZ);
        const ushort_t* ALp = (const ushort_t*)(aL + cur * ASZ);
        const ushort_t* Bp = (const ushort_t*)(bH + cur * BSZ);
        const ushort_t* BLp = (const ushort_t*)(bL + cur * BSZ);

        short8v ah[MT], al[MT], bh[NT], bl[NT];
#pragma unroll
        for (int m = 0; m < MT; m++) {
            int off = (wr * (MT * 16) + m * 16 + lr) * 32 + lg * 8;
            ah[m] = *(const short8v*)&Ap[off];
            al[m] = *(const short8v*)&ALp[off];
        }
#pragma unroll
        for (int n = 0; n < NT; n++) {
            int off = (wc * (NT * 16) + n * 16 + lr) * 32 + lg * 8;
            bh[n] = *(const short8v*)&Bp[off];
            if constexpr (TERMS >= 3) bl[n] = *(const short8v*)&BLp[off];
        }
#pragma unroll
        for (int m = 0; m < MT; m++)
#pragma unroll
            for (int n = 0; n < NT; n++) {
                acc[m][n] = __builtin_amdgcn_mfma_f32_16x16x32_bf16(
                    ah[m], bh[n], acc[m][n], 0, 0, 0);
                acc[m][n] = __builtin_amdgcn_mfma_f32_16x16x32_bf16(
                    al[m], bh[n], acc[m][n], 0, 0, 0);
                if constexpr (TERMS >= 3)
                    acc[m][n] = __builtin_amdgcn_mfma_f32_16x16x32_bf16(
                        ah[m], bl[n], acc[m][n], 0, 0, 0);
            }

        if (ks < 7) {
            asm volatile("s_waitcnt vmcnt(0)" ::: "memory");
            __syncthreads();
        }
        cur ^= 1;
    }

#pragma unroll
    for (int m = 0; m < MT; m++)
#pragma unroll
        for (int n = 0; n < NT; n++) {
            int gr0 = m0 + wr * (MT * 16) + m * 16 + lg * 4;
            int gc = n0 + wc * (NT * 16) + n * 16 + lr;
            if (EPI == 0) {
                if (gc < 256) {          // K fragment-packed, hi only
                    int hh_ = gc >> 5, dk = gc & 31;
                    int lgk = dk >> 3, ek = dk & 7;
#pragma unroll
                    for (int r = 0; r < 4; r++) {
                        int gr = gr0 + r;
                        int bb = gr >> 8, j = gr & 255;
                        int jt = j >> 6, mfk = (j >> 4) & 3, lrk = j & 15;
                        size_t a =
                            (((((size_t)(bb * 8 + hh_) * 4 + jt) * 4 + mfk) * 4
                              + lgk) * 16 + lrk) * 8 + ek;
                        kh[a] = f2bf(acc[m][n][r]);
                    }
                } else if (gc < 512) {   // V^T fragment-packed hi only
                    int cc = gc - 256;
                    int hh_ = cc >> 5, dv = cc & 31;
                    int mfv = dv >> 4, lrv = dv & 15;
                    int gr = gr0;
                    int bb = gr >> 8, j = gr & 255;
                    int jt = j >> 6, hbv = (j >> 5) & 1;
                    int lgv = (j >> 3) & 3, ev = j & 7;
                    size_t a =
                        ((((((size_t)(bb * 8 + hh_) * 4 + jt) * 2 + hbv) * 2
                           + mfv) * 4 + lgv) * 16 + lrv) * 8 + ev;
                    ushort4 hv;
                    hv.x = f2bf(acc[m][n][0]);
                    hv.y = f2bf(acc[m][n][1]);
                    hv.z = f2bf(acc[m][n][2]);
                    hv.w = f2bf(acc[m][n][3]);
                    *(ushort4*)(vP + a) = hv;
                } else {                 // gates bf16, attn-epilogue-fragment order
                    int c = gc - 512;
                    int hh_ = c >> 5, d = c & 31;
                    int mdv = d >> 4, lga = (d >> 2) & 3, ev = d & 3;
#pragma unroll
                    for (int r = 0; r < 4; r++) {
                        int gr = gr0 + r;
                        int bb = gr >> 8, i = gr & 255;
                        int i16 = i >> 4, lra = i & 15;
                        size_t a =
                            ((((size_t)(bb * 8 + hh_) * 16 + i16) * 2 + mdv)
                             * 64 + lga * 16 + lra) * 4 + ev;
                        float v = acc[m][n][r];
                        float g = 1.f / (1.f + __expf(-(v + bias[gc - 512])));
                        gatesP[a] = f2bf(g);
                    }
                }
            } else {
#pragma unroll
                for (int r = 0; r < 4; r++)
                    C[(size_t)(gr0 + r) * 256 + gc] = acc[m][n][r] + bias[gc];
            }
        }
}

// ---------------------------------------------------------------------------
// Per-wave online MFMA flash attention, 16 q-rows per wave, depth-2 prefetch.
// Block = (b, h, q-quarter of 64); wave w owns rows [qq*64+w*16, +16).
__global__ __launch_bounds__(256) void attn_mfma_kernel(
    const ushort_t* __restrict__ qPh, const ushort_t* __restrict__ kh,
    const ushort_t* __restrict__ vP, const ushort_t* __restrict__ gatesP,
    const float* __restrict__ biasP, const int* __restrict__ mask,
    ushort_t* __restrict__ atthi, ushort_t* __restrict__ attlo) {
    __shared__ __align__(16) ushort_t Pb[4][640];   // per-wave 16x40
    const int bid = blockIdx.x;
    const int sid = ((bid & 7) << 8) | (bid >> 3);  // 2048 = 8*256
    const int b = sid >> 5;
    const int h = (sid >> 2) & 7;
    const int qq = sid & 3;
    const int t = threadIdx.x;
    const int w = t >> 6, lane = t & 63;
    const int lr = lane & 15, lg = lane >> 4;
    const int i0 = qq * 64 + w * 16;
    const int i16 = qq * 4 + w;
    ushort_t* pbh = Pb[w];

    short8v qf;
    {
        size_t off = ((((size_t)h * 16 + i16) * 4 + lg) * 16 + lr) * 8;
        qf = *(const short8v*)(qPh + off);
    }
    const int mi = mask[b * 256 + i0 + lr];

    // biasP float offset = g2*256 + lane*4, g2 = h*256+(i16>>1)*32+(i16&1)*4
    //                                            + jt*8 + mf
    const float* bbase = biasP +
        (size_t)(h * 256 + (i16 >> 1) * 32 + (i16 & 1) * 4) * 256 +
        (size_t)lane * 4;

    float m_run = NEG_MAX, l_run = 0.f;
    f32x4 acc_o[2] = {};

    // prefetch tile 0 K + bias
    short8v kf[2][4];
    float4 bf[2][4];
#pragma unroll
    for (int mf = 0; mf < 4; mf++) {
        size_t off = ((((size_t)(b * 8 + h) * 4 + 0) * 4 + mf) * 4 + lg);
        kf[0][mf] = *(const short8v*)(kh + (off * 16 + lr) * 8);
        bf[0][mf] = *(const float4*)(bbase + (size_t)mf * 256);
    }

#pragma unroll
    for (int jt = 0; jt < 4; ++jt) {
        const int cur = jt & 1, nxt = cur ^ 1;
        if (jt < 3) {
#pragma unroll
            for (int mf = 0; mf < 4; mf++) {
                size_t off = ((((size_t)(b * 8 + h) * 4 + (jt + 1)) * 4 + mf)
                              * 4 + lg);
                kf[nxt][mf] = *(const short8v*)(kh + (off * 16 + lr) * 8);
                bf[nxt][mf] = *(const float4*)(bbase +
                                               (size_t)((jt + 1) * 8 + mf) * 256);
            }
        }
        // V for current tile
        short8v vf[2][2];
#pragma unroll
        for (int hb = 0; hb < 2; hb++)
#pragma unroll
            for (int mv = 0; mv < 2; mv++) {
                size_t off = ((((((size_t)(b * 8 + h) * 4 + jt) * 2 + hb) * 2
                               + mv) * 4 + lg) * 16 + lr) * 8;
                vf[hb][mv] = *(const short8v*)(vP + off);
            }
        int4 mj[4];
#pragma unroll
        for (int mf = 0; mf < 4; mf++)
            mj[mf] = *(const int4*)(mask + b * 256 + jt * 64 + mf * 16 + lg * 4);

        // S^T = K * Q^T (1-term)
        f32x4 s[4];
#pragma unroll
        for (int mf = 0; mf < 4; mf++) {
            f32x4 a = {};
            s[mf] = __builtin_amdgcn_mfma_f32_16x16x32_bf16(
                kf[cur][mf], qf, a, 0, 0, 0);
        }
        // bias + mask
#pragma unroll
        for (int mf = 0; mf < 4; mf++) {
            float4 bv = bf[cur][mf];
            s[mf][0] = (mi && mj[mf].x) ? s[mf][0] + bv.x : NEG_MAX;
            s[mf][1] = (mi && mj[mf].y) ? s[mf][1] + bv.y : NEG_MAX;
            s[mf][2] = (mi && mj[mf].z) ? s[mf][2] + bv.z : NEG_MAX;
            s[mf][3] = (mi && mj[mf].w) ? s[mf][3] + bv.w : NEG_MAX;
        }

        // online softmax
        float tm = s[0][0];
#pragma unroll
        for (int mf = 0; mf < 4; mf++)
#pragma unroll
            for (int r = 0; r < 4; r++) tm = fmaxf(tm, s[mf][r]);
        tm = fmaxf(tm, __shfl_xor(tm, 16));
        tm = fmaxf(tm, __shfl_xor(tm, 32));
        float mnew = fmaxf(m_run, tm);
        float corr = __expf(m_run - mnew);
        m_run = mnew;
#pragma unroll
        for (int md = 0; md < 2; md++)
#pragma unroll
            for (int r = 0; r < 4; r++) acc_o[md][r] *= corr;
        float ls = 0.f;
#pragma unroll
        for (int mf = 0; mf < 4; mf++)
#pragma unroll
            for (int r = 0; r < 4; r++) {
                float wv = __expf(s[mf][r] - mnew);
                s[mf][r] = wv;
                ls += wv;
            }
        ls += __shfl_xor(ls, 16);
        ls += __shfl_xor(ls, 32);
        l_run = l_run * corr + ls;

        // PV: two 32-key halves via per-wave LDS
#pragma unroll
        for (int hb = 0; hb < 2; ++hb) {
#pragma unroll
            for (int mq = 0; mq < 2; mq++) {
                int mf = hb * 2 + mq;
                uint2 hv;
                hv.x = (uint_t)f2bf(s[mf][0]) | ((uint_t)f2bf(s[mf][1]) << 16);
                hv.y = (uint_t)f2bf(s[mf][2]) | ((uint_t)f2bf(s[mf][3]) << 16);
                *(uint2*)(pbh + lr * 40 + mq * 16 + lg * 4) = hv;
            }
            asm volatile("s_waitcnt lgkmcnt(0)" ::: "memory");
            __builtin_amdgcn_sched_barrier(0);
            short8v ph = *(const short8v*)(pbh + lr * 40 + lg * 8);
            acc_o[0] = __builtin_amdgcn_mfma_f32_16x16x32_bf16(
                vf[hb][0], ph, acc_o[0], 0, 0, 0);
            acc_o[1] = __builtin_amdgcn_mfma_f32_16x16x32_bf16(
                vf[hb][1], ph, acc_o[1], 0, 0, 0);
        }
    }

    // epilogue: O = acc/l * gate (gates coalesced), split bf16
    float invl = 1.0f / l_run;
#pragma unroll
    for (int md = 0; md < 2; md++) {
        size_t ga = ((((size_t)(b * 8 + h) * 16 + i16) * 2 + md) * 64 + lane) * 4;
        uint2 gv = *(const uint2*)(gatesP + ga);
        float g0 = bf2f((ushort_t)(gv.x & 0xffff));
        float g1 = bf2f((ushort_t)(gv.x >> 16));
        float g2 = bf2f((ushort_t)(gv.y & 0xffff));
        float g3 = bf2f((ushort_t)(gv.y >> 16));
        int i = i0 + lr;
        int d0 = md * 16 + lg * 4;
        size_t base = ((size_t)(b * 256 + i)) * 256 + h * 32 + d0;
        float v0 = acc_o[md][0] * invl * g0;
        float v1 = acc_o[md][1] * invl * g1;
        float v2 = acc_o[md][2] * invl * g2;
        float v3 = acc_o[md][3] * invl * g3;
        ushort4 hh, ll;
        hh.x = f2bf(v0); ll.x = f2bf(v0 - bf2f(hh.x));
        hh.y = f2bf(v1); ll.y = f2bf(v1 - bf2f(hh.y));
        hh.z = f2bf(v2); ll.z = f2bf(v2 - bf2f(hh.z));
        hh.w = f2bf(v3); ll.w = f2bf(v3 - bf2f(hh.w));
        *(ushort4*)(atthi + base) = hh;
        *(ushort4*)(attlo + base) = ll;
    }
}

// ---------------------------------------------------------------------------
extern "C" void kernel_launch(void* const* d_in, const int* in_sizes, int n_in,
                              void* d_out, int out_size, void* d_ws, size_t ws_size,
                              hipStream_t stream) {
    const float* x    = (const float*)d_in[0];
    const unsigned char* mraw = (const unsigned char*)d_in[1];
    const float* bias = (const float*)d_in[2];
    const float* Wq   = (const float*)d_in[3];
    const float* Wkv  = (const float*)d_in[4];
    const float* Wg   = (const float*)d_in[5];
    const float* bg   = (const float*)d_in[6];
    const float* Wo   = (const float*)d_in[7];
    const float* bo   = (const float*)d_in[8];

    float* ws = (float*)d_ws;
    ushort_t* kh     = (ushort_t*)(ws + OFF_KH);
    ushort_t* vP     = (ushort_t*)(ws + OFF_VP);
    ushort_t* gatesP = (ushort_t*)(ws + OFF_GATES);
    ushort_t* xhi    = (ushort_t*)(ws + OFF_XHI);
    ushort_t* xlo    = (ushort_t*)(ws + OFF_XLO);
    ushort_t* atthi  = (ushort_t*)(ws + OFF_ATTHI);  // aliases xhi (dead)
    ushort_t* attlo  = (ushort_t*)(ws + OFF_ATTLO);
    ushort_t* bthi   = (ushort_t*)(ws + OFF_BTHI);
    ushort_t* btlo   = (ushort_t*)(ws + OFF_BTLO);
    ushort_t* qPh    = (ushort_t*)(ws + OFF_QTH);
    float*    xbar   = ws + OFF_XBAR;
    float*    biasP  = ws + OFF_BIASP;
    int*      maskc  = (int*)(ws + OFF_MASK);

    hipLaunchKernelGGL(prep_kernel, dim3(5904), dim3(256), 0, stream,
                       x, mraw, bias, Wkv, Wg, Wo,
                       xhi, xlo, maskc, xbar, bthi, btlo, biasP);
    hipLaunchKernelGGL(qt_gemm, dim3(256), dim3(256), 0, stream, xbar, Wq, qPh);
    // proj: M=16384, N=768, 128x128 tiles, 2-term, dbuf, XCD swizzle
    hipLaunchKernelGGL((mfma_gemm<0, 4, 4, 2>), dim3(768), dim3(256), 0, stream,
                       xhi, xlo, bthi, btlo, bg, (float*)nullptr,
                       kh, vP, gatesP, 6);
    hipLaunchKernelGGL(attn_mfma_kernel, dim3(2048), dim3(256), 0, stream,
                       qPh, kh, vP, gatesP, biasP, maskc, atthi, attlo);
    // out = att @ Wo + bo : M=16384, N=256, 64x64 tiles, 3-term, dbuf
    hipLaunchKernelGGL((mfma_gemm<1, 2, 2, 3>), dim3(1024), dim3(256), 0, stream,
                       atthi, attlo, bthi + 768 * 256, btlo + 768 * 256, bo,
                       (float*)d_out, nullptr, nullptr, nullptr, 4);
}

// Round 12
// 85.543 us; speedup vs baseline: 3.3000x; 1.0713x over previous
//
#include <hip/hip_runtime.h>
#include <math.h>

typedef unsigned short ushort_t;
typedef unsigned int uint_t;
typedef __attribute__((ext_vector_type(8))) short short8v;   // 8 bf16 (4 VGPR)
typedef __attribute__((ext_vector_type(4))) float f32x4;

#define NEG_MAX (-3.402823466e+38f)

// -------- ws layout (float offsets) --------
#define OFF_KH    0
#define OFF_VP    4194304
#define OFF_GATES 6291456
#define OFF_XHI   8388608
#define OFF_XLO   10485760
#define OFF_ATTHI OFF_XHI
#define OFF_ATTLO OFF_XLO
#define OFF_BTHI  12582912
#define OFF_BTLO  12713984
#define OFF_QTH   12845056
#define OFF_XBAR  12910592
#define OFF_BIASP 12976128
#define OFF_MASK  13500416

// ---------------------------------------------------------------------------
__device__ __forceinline__ ushort_t f2bf(float x) {
    uint_t u = __float_as_uint(x);
    u = (u + 0x7fffu + ((u >> 16) & 1u)) >> 16;   // RNE
    return (ushort_t)u;
}
__device__ __forceinline__ float bf2f(ushort_t u) {
    return __uint_as_float(((uint_t)u) << 16);
}
__device__ __forceinline__ void gl2lds16(const void* g, void* l) {
    typedef const __attribute__((address_space(1))) uint32_t* gptr_t;
    typedef __attribute__((address_space(3))) uint32_t* lptr_t;
    __builtin_amdgcn_global_load_lds((gptr_t)(uintptr_t)g,
                                     (lptr_t)(uintptr_t)l, 16, 0, 0);
}

// ---------------------------------------------------------------------------
// Fused prep kernel. Block ranges:
// [0,4096) split_x (hi only) | [4096,4112) mask canon | [4112,5136) wsplit
// [5136,5648) bias_prepack | [5648,5904) xbar
__global__ __launch_bounds__(256) void prep_kernel(
    const float* __restrict__ x, const unsigned char* __restrict__ mraw,
    const float* __restrict__ bias, const float* __restrict__ Wkv,
    const float* __restrict__ Wg, const float* __restrict__ Wo,
    ushort_t* __restrict__ xhi,
    int* __restrict__ maskc, float* __restrict__ xbar,
    ushort_t* __restrict__ bthi, ushort_t* __restrict__ btlo,
    float* __restrict__ biasP) {
    __shared__ int cnt[256];
    const int bid = blockIdx.x, t = threadIdx.x;
    if (bid < 4096) {                         // ---- split_x (hi only) ----
        int idx = bid * 256 + t;
        float4 v = ((const float4*)x)[idx];
        ushort4 h;
        h.x = f2bf(v.x);
        h.y = f2bf(v.y);
        h.z = f2bf(v.z);
        h.w = f2bf(v.w);
        ((ushort4*)xhi)[idx] = h;
    } else if (bid < 4112) {                  // ---- mask canon ----
        int c = 0;
        for (int i = t; i < 4096; i += 256)
            if ((i & 3) != 0 && mraw[i] != 0) c++;
        cnt[t] = c;
        __syncthreads();
        for (int s = 128; s > 0; s >>= 1) {
            if (t < s) cnt[t] += cnt[t + s];
            __syncthreads();
        }
        int isBool = cnt[0] > 16;
        int base = (bid - 4096) * 1024;
        if (isBool) {
            for (int i = t; i < 1024; i += 256)
                maskc[base + i] = mraw[base + i] ? 1 : 0;
        } else {
            const int* mi = (const int*)mraw;
            for (int i = t; i < 1024; i += 256)
                maskc[base + i] = mi[base + i] ? 1 : 0;
        }
    } else if (bid < 5136) {                  // ---- wsplit ----
        int idx = (bid - 4112) * 256 + t;
        int n = idx >> 8, k = idx & 255;
        float v;
        if (n < 512)      v = Wkv[(size_t)k * 512 + n];
        else if (n < 768) v = Wg[(size_t)k * 256 + (n - 512)];
        else              v = Wo[(size_t)k * 256 + (n - 768)];
        ushort_t h = f2bf(v);
        bthi[idx] = h;
        btlo[idx] = f2bf(v - bf2f(h));
    } else if (bid < 5648) {                  // ---- bias prepack ----
        int idx = (bid - 5136) * 256 + t;     // 0..131071
        int lane = idx & 63, g2 = idx >> 6;   // g2 0..2047
        int mf = g2 & 3, nf = (g2 >> 2) & 1, jt = (g2 >> 3) & 3;
        int iq = (g2 >> 5) & 7, h = g2 >> 8;
        int lr = lane & 15, lg = lane >> 4;
        float4 v = *(const float4*)(bias +
            (size_t)(h * 256 + iq * 32 + nf * 16 + lr) * 256 +
            jt * 64 + mf * 16 + lg * 4);
        *(float4*)(biasP + (size_t)idx * 4) = v;
    } else {                                  // ---- xbar ----
        int idx = (bid - 5648) * 256 + t;
        float s0 = 0.f, s1 = 0.f, s2 = 0.f, s3 = 0.f;
#pragma unroll
        for (int b8 = 0; b8 < 64; b8 += 4) {
            s0 += x[(size_t)b8 * 65536 + idx];
            s1 += x[(size_t)(b8 + 1) * 65536 + idx];
            s2 += x[(size_t)(b8 + 2) * 65536 + idx];
            s3 += x[(size_t)(b8 + 3) * 65536 + idx];
        }
        xbar[idx] = ((s0 + s1) + (s2 + s3)) * (1.0f / 64.0f);
    }
}

// ---------------------------------------------------------------------------
// qt = xbar @ Wq * scale, fragment-packed bf16 hi
__global__ __launch_bounds__(256) void qt_gemm(const float* __restrict__ xbar,
                                               const float* __restrict__ Wq,
                                               ushort_t* __restrict__ qPh) {
    __shared__ float xrow[256];
    int i = blockIdx.x, t = threadIdx.x;
    xrow[t] = xbar[i * 256 + t];
    __syncthreads();
    float s = 0.f;
    for (int k = 0; k < 256; k++) s = fmaf(xrow[k], Wq[(size_t)k * 256 + t], s);
    s *= 0.17677669529663687f;   // 1/sqrt(32)
    int h = t >> 5, d = t & 31, lg = d >> 3, e = d & 7;
    int g = i >> 4, lr = i & 15;                 // g = i>>4 (0..15)
    int a = (((h * 16 + g) * 4 + lg) * 16 + lr) * 8 + e;
    qPh[a] = f2bf(s);
}

// ---------------------------------------------------------------------------
// Double-buffered MFMA split-bf16 GEMM, 1-D XCD-swizzled grid.
// TERMS=1: ah*bh | TERMS=2: + al*bh | TERMS=3: + ah*bl
template <int EPI, int MT, int NT, int TERMS>
__global__ __launch_bounds__(256) void mfma_gemm(
    const ushort_t* __restrict__ Ahi, const ushort_t* __restrict__ Alo,
    const ushort_t* __restrict__ Bthi, const ushort_t* __restrict__ Btlo,
    const float* __restrict__ bias, float* __restrict__ C,
    ushort_t* __restrict__ kh, ushort_t* __restrict__ vP,
    ushort_t* __restrict__ gatesP, int gridn) {
    constexpr int BM = MT * 32, BN = NT * 32;
    constexpr int ASZ = BM * 32 * 2;
    constexpr int BSZ = BN * 32 * 2;
    constexpr bool HAS_AL = (TERMS >= 2);
    constexpr bool HAS_BL = (TERMS >= 3);
    constexpr int AL_OFF = 2 * ASZ;
    constexpr int BH_OFF = AL_OFF + (HAS_AL ? 2 * ASZ : 0);
    constexpr int BL_OFF = BH_OFF + 2 * BSZ;
    constexpr int SMEM_BYTES = BL_OFF + (HAS_BL ? 2 * BSZ : 0);
    __shared__ __align__(16) char smem[SMEM_BYTES];
    char* aH = smem;
    char* aL = smem + AL_OFF;
    char* bH = smem + BH_OFF;
    char* bL = smem + BL_OFF;

    const int t = threadIdx.x;
    const int nwg = gridDim.x, cpx = nwg >> 3;
    const int bid = blockIdx.x;
    const int sid = (bid & 7) * cpx + (bid >> 3);   // XCD-chunked
    const int m0 = (sid / gridn) * BM;
    const int n0 = (sid % gridn) * BN;
    const int wid = t >> 6, lane = t & 63;
    const int wr = wid >> 1, wc = wid & 1;
    const int lr = lane & 15, lg = lane >> 4;

    auto STAGE = [&](int d, int ks) {
        const int k0 = ks * 32;
#pragma unroll
        for (int it = 0; it < BM / 64; ++it) {
            int c = t + it * 256;
            int row = c >> 2, sub = c & 3;
            size_t ga = (size_t)(m0 + row) * 256 + k0 + sub * 8;
            gl2lds16(Ahi + ga, aH + d * ASZ + c * 16);
            if constexpr (HAS_AL)
                gl2lds16(Alo + ga, aL + d * ASZ + c * 16);
        }
#pragma unroll
        for (int it = 0; it < BN / 64; ++it) {
            int c = t + it * 256;
            int row = c >> 2, sub = c & 3;
            size_t gb = (size_t)(n0 + row) * 256 + k0 + sub * 8;
            gl2lds16(Bthi + gb, bH + d * BSZ + c * 16);
            if constexpr (HAS_BL)
                gl2lds16(Btlo + gb, bL + d * BSZ + c * 16);
        }
    };

    f32x4 acc[MT][NT] = {};

    STAGE(0, 0);
    asm volatile("s_waitcnt vmcnt(0)" ::: "memory");
    __syncthreads();

    int cur = 0;
    for (int ks = 0; ks < 8; ++ks) {
        if (ks < 7) STAGE(cur ^ 1, ks + 1);

        const ushort_t* Ap = (const ushort_t*)(aH + cur * ASZ);
        const ushort_t* ALp = (const ushort_t*)(aL + cur * ASZ);
        const ushort_t* Bp = (const ushort_t*)(bH + cur * BSZ);
        const ushort_t* BLp = (const ushort_t*)(bL + cur * BSZ);

        short8v ah[MT], al[MT], bh[NT], bl[NT];
#pragma unroll
        for (int m = 0; m < MT; m++) {
            int off = (wr * (MT * 16) + m * 16 + lr) * 32 + lg * 8;
            ah[m] = *(const short8v*)&Ap[off];
            if constexpr (HAS_AL) al[m] = *(const short8v*)&ALp[off];
        }
#pragma unroll
        for (int n = 0; n < NT; n++) {
            int off = (wc * (NT * 16) + n * 16 + lr) * 32 + lg * 8;
            bh[n] = *(const short8v*)&Bp[off];
            if constexpr (HAS_BL) bl[n] = *(const short8v*)&BLp[off];
        }
#pragma unroll
        for (int m = 0; m < MT; m++)
#pragma unroll
            for (int n = 0; n < NT; n++) {
                acc[m][n] = __builtin_amdgcn_mfma_f32_16x16x32_bf16(
                    ah[m], bh[n], acc[m][n], 0, 0, 0);
                if constexpr (HAS_AL)
                    acc[m][n] = __builtin_amdgcn_mfma_f32_16x16x32_bf16(
                        al[m], bh[n], acc[m][n], 0, 0, 0);
                if constexpr (HAS_BL)
                    acc[m][n] = __builtin_amdgcn_mfma_f32_16x16x32_bf16(
                        ah[m], bl[n], acc[m][n], 0, 0, 0);
            }

        if (ks < 7) {
            asm volatile("s_waitcnt vmcnt(0)" ::: "memory");
            __syncthreads();
        }
        cur ^= 1;
    }

#pragma unroll
    for (int m = 0; m < MT; m++)
#pragma unroll
        for (int n = 0; n < NT; n++) {
            int gr0 = m0 + wr * (MT * 16) + m * 16 + lg * 4;
            int gc = n0 + wc * (NT * 16) + n * 16 + lr;
            if (EPI == 0) {
                if (gc < 256) {          // K fragment-packed, hi only
                    int hh_ = gc >> 5, dk = gc & 31;
                    int lgk = dk >> 3, ek = dk & 7;
#pragma unroll
                    for (int r = 0; r < 4; r++) {
                        int gr = gr0 + r;
                        int bb = gr >> 8, j = gr & 255;
                        int jt = j >> 6, mfk = (j >> 4) & 3, lrk = j & 15;
                        size_t a =
                            (((((size_t)(bb * 8 + hh_) * 4 + jt) * 4 + mfk) * 4
                              + lgk) * 16 + lrk) * 8 + ek;
                        kh[a] = f2bf(acc[m][n][r]);
                    }
                } else if (gc < 512) {   // V^T fragment-packed hi only
                    int cc = gc - 256;
                    int hh_ = cc >> 5, dv = cc & 31;
                    int mfv = dv >> 4, lrv = dv & 15;
                    int gr = gr0;
                    int bb = gr >> 8, j = gr & 255;
                    int jt = j >> 6, hbv = (j >> 5) & 1;
                    int lgv = (j >> 3) & 3, ev = j & 7;
                    size_t a =
                        ((((((size_t)(bb * 8 + hh_) * 4 + jt) * 2 + hbv) * 2
                           + mfv) * 4 + lgv) * 16 + lrv) * 8 + ev;
                    ushort4 hv;
                    hv.x = f2bf(acc[m][n][0]);
                    hv.y = f2bf(acc[m][n][1]);
                    hv.z = f2bf(acc[m][n][2]);
                    hv.w = f2bf(acc[m][n][3]);
                    *(ushort4*)(vP + a) = hv;
                } else {                 // gates bf16, attn-epilogue-fragment order
                    int c = gc - 512;
                    int hh_ = c >> 5, d = c & 31;
                    int mdv = d >> 4, lga = (d >> 2) & 3, ev = d & 3;
#pragma unroll
                    for (int r = 0; r < 4; r++) {
                        int gr = gr0 + r;
                        int bb = gr >> 8, i = gr & 255;
                        int i16 = i >> 4, lra = i & 15;
                        size_t a =
                            ((((size_t)(bb * 8 + hh_) * 16 + i16) * 2 + mdv)
                             * 64 + lga * 16 + lra) * 4 + ev;
                        float v = acc[m][n][r];
                        float g = 1.f / (1.f + __expf(-(v + bias[gc - 512])));
                        gatesP[a] = f2bf(g);
                    }
                }
            } else {
#pragma unroll
                for (int r = 0; r < 4; r++)
                    C[(size_t)(gr0 + r) * 256 + gc] = acc[m][n][r] + bias[gc];
            }
        }
}

// ---------------------------------------------------------------------------
// Per-wave online MFMA flash attention, 16 q-rows per wave, depth-2 prefetch.
// Block = (b, h, q-quarter of 64); wave w owns rows [qq*64+w*16, +16).
__global__ __launch_bounds__(256) void attn_mfma_kernel(
    const ushort_t* __restrict__ qPh, const ushort_t* __restrict__ kh,
    const ushort_t* __restrict__ vP, const ushort_t* __restrict__ gatesP,
    const float* __restrict__ biasP, const int* __restrict__ mask,
    ushort_t* __restrict__ atthi, ushort_t* __restrict__ attlo) {
    __shared__ __align__(16) ushort_t Pb[4][640];   // per-wave 16x40
    const int bid = blockIdx.x;
    const int sid = ((bid & 7) << 8) | (bid >> 3);  // 2048 = 8*256
    const int b = sid >> 5;
    const int h = (sid >> 2) & 7;
    const int qq = sid & 3;
    const int t = threadIdx.x;
    const int w = t >> 6, lane = t & 63;
    const int lr = lane & 15, lg = lane >> 4;
    const int i0 = qq * 64 + w * 16;
    const int i16 = qq * 4 + w;
    ushort_t* pbh = Pb[w];

    short8v qf;
    {
        size_t off = ((((size_t)h * 16 + i16) * 4 + lg) * 16 + lr) * 8;
        qf = *(const short8v*)(qPh + off);
    }
    const int mi = mask[b * 256 + i0 + lr];

    // biasP float offset = g2*256 + lane*4, g2 = h*256+(i16>>1)*32+(i16&1)*4
    //                                            + jt*8 + mf
    const float* bbase = biasP +
        (size_t)(h * 256 + (i16 >> 1) * 32 + (i16 & 1) * 4) * 256 +
        (size_t)lane * 4;

    float m_run = NEG_MAX, l_run = 0.f;
    f32x4 acc_o[2] = {};

    // prefetch tile 0 K + bias
    short8v kf[2][4];
    float4 bf[2][4];
#pragma unroll
    for (int mf = 0; mf < 4; mf++) {
        size_t off = ((((size_t)(b * 8 + h) * 4 + 0) * 4 + mf) * 4 + lg);
        kf[0][mf] = *(const short8v*)(kh + (off * 16 + lr) * 8);
        bf[0][mf] = *(const float4*)(bbase + (size_t)mf * 256);
    }

#pragma unroll
    for (int jt = 0; jt < 4; ++jt) {
        const int cur = jt & 1, nxt = cur ^ 1;
        if (jt < 3) {
#pragma unroll
            for (int mf = 0; mf < 4; mf++) {
                size_t off = ((((size_t)(b * 8 + h) * 4 + (jt + 1)) * 4 + mf)
                              * 4 + lg);
                kf[nxt][mf] = *(const short8v*)(kh + (off * 16 + lr) * 8);
                bf[nxt][mf] = *(const float4*)(bbase +
                                               (size_t)((jt + 1) * 8 + mf) * 256);
            }
        }
        // V for current tile
        short8v vf[2][2];
#pragma unroll
        for (int hb = 0; hb < 2; hb++)
#pragma unroll
            for (int mv = 0; mv < 2; mv++) {
                size_t off = ((((((size_t)(b * 8 + h) * 4 + jt) * 2 + hb) * 2
                               + mv) * 4 + lg) * 16 + lr) * 8;
                vf[hb][mv] = *(const short8v*)(vP + off);
            }
        int4 mj[4];
#pragma unroll
        for (int mf = 0; mf < 4; mf++)
            mj[mf] = *(const int4*)(mask + b * 256 + jt * 64 + mf * 16 + lg * 4);

        // S^T = K * Q^T (1-term)
        f32x4 s[4];
#pragma unroll
        for (int mf = 0; mf < 4; mf++) {
            f32x4 a = {};
            s[mf] = __builtin_amdgcn_mfma_f32_16x16x32_bf16(
                kf[cur][mf], qf, a, 0, 0, 0);
        }
        // bias + mask
#pragma unroll
        for (int mf = 0; mf < 4; mf++) {
            float4 bv = bf[cur][mf];
            s[mf][0] = (mi && mj[mf].x) ? s[mf][0] + bv.x : NEG_MAX;
            s[mf][1] = (mi && mj[mf].y) ? s[mf][1] + bv.y : NEG_MAX;
            s[mf][2] = (mi && mj[mf].z) ? s[mf][2] + bv.z : NEG_MAX;
            s[mf][3] = (mi && mj[mf].w) ? s[mf][3] + bv.w : NEG_MAX;
        }

        // online softmax
        float tm = s[0][0];
#pragma unroll
        for (int mf = 0; mf < 4; mf++)
#pragma unroll
            for (int r = 0; r < 4; r++) tm = fmaxf(tm, s[mf][r]);
        tm = fmaxf(tm, __shfl_xor(tm, 16));
        tm = fmaxf(tm, __shfl_xor(tm, 32));
        float mnew = fmaxf(m_run, tm);
        float corr = __expf(m_run - mnew);
        m_run = mnew;
#pragma unroll
        for (int md = 0; md < 2; md++)
#pragma unroll
            for (int r = 0; r < 4; r++) acc_o[md][r] *= corr;
        float ls = 0.f;
#pragma unroll
        for (int mf = 0; mf < 4; mf++)
#pragma unroll
            for (int r = 0; r < 4; r++) {
                float wv = __expf(s[mf][r] - mnew);
                s[mf][r] = wv;
                ls += wv;
            }
        ls += __shfl_xor(ls, 16);
        ls += __shfl_xor(ls, 32);
        l_run = l_run * corr + ls;

        // PV: two 32-key halves via per-wave LDS
#pragma unroll
        for (int hb = 0; hb < 2; ++hb) {
#pragma unroll
            for (int mq = 0; mq < 2; mq++) {
                int mf = hb * 2 + mq;
                uint2 hv;
                hv.x = (uint_t)f2bf(s[mf][0]) | ((uint_t)f2bf(s[mf][1]) << 16);
                hv.y = (uint_t)f2bf(s[mf][2]) | ((uint_t)f2bf(s[mf][3]) << 16);
                *(uint2*)(pbh + lr * 40 + mq * 16 + lg * 4) = hv;
            }
            asm volatile("s_waitcnt lgkmcnt(0)" ::: "memory");
            __builtin_amdgcn_sched_barrier(0);
            short8v ph = *(const short8v*)(pbh + lr * 40 + lg * 8);
            acc_o[0] = __builtin_amdgcn_mfma_f32_16x16x32_bf16(
                vf[hb][0], ph, acc_o[0], 0, 0, 0);
            acc_o[1] = __builtin_amdgcn_mfma_f32_16x16x32_bf16(
                vf[hb][1], ph, acc_o[1], 0, 0, 0);
        }
    }

    // epilogue: O = acc/l * gate (gates coalesced), split bf16
    float invl = 1.0f / l_run;
#pragma unroll
    for (int md = 0; md < 2; md++) {
        size_t ga = ((((size_t)(b * 8 + h) * 16 + i16) * 2 + md) * 64 + lane) * 4;
        uint2 gv = *(const uint2*)(gatesP + ga);
        float g0 = bf2f((ushort_t)(gv.x & 0xffff));
        float g1 = bf2f((ushort_t)(gv.x >> 16));
        float g2 = bf2f((ushort_t)(gv.y & 0xffff));
        float g3 = bf2f((ushort_t)(gv.y >> 16));
        int i = i0 + lr;
        int d0 = md * 16 + lg * 4;
        size_t base = ((size_t)(b * 256 + i)) * 256 + h * 32 + d0;
        float v0 = acc_o[md][0] * invl * g0;
        float v1 = acc_o[md][1] * invl * g1;
        float v2 = acc_o[md][2] * invl * g2;
        float v3 = acc_o[md][3] * invl * g3;
        ushort4 hh, ll;
        hh.x = f2bf(v0); ll.x = f2bf(v0 - bf2f(hh.x));
        hh.y = f2bf(v1); ll.y = f2bf(v1 - bf2f(hh.y));
        hh.z = f2bf(v2); ll.z = f2bf(v2 - bf2f(hh.z));
        hh.w = f2bf(v3); ll.w = f2bf(v3 - bf2f(hh.w));
        *(ushort4*)(atthi + base) = hh;
        *(ushort4*)(attlo + base) = ll;
    }
}

// ---------------------------------------------------------------------------
extern "C" void kernel_launch(void* const* d_in, const int* in_sizes, int n_in,
                              void* d_out, int out_size, void* d_ws, size_t ws_size,
                              hipStream_t stream) {
    const float* x    = (const float*)d_in[0];
    const unsigned char* mraw = (const unsigned char*)d_in[1];
    const float* bias = (const float*)d_in[2];
    const float* Wq   = (const float*)d_in[3];
    const float* Wkv  = (const float*)d_in[4];
    const float* Wg   = (const float*)d_in[5];
    const float* bg   = (const float*)d_in[6];
    const float* Wo   = (const float*)d_in[7];
    const float* bo   = (const float*)d_in[8];

    float* ws = (float*)d_ws;
    ushort_t* kh     = (ushort_t*)(ws + OFF_KH);
    ushort_t* vP     = (ushort_t*)(ws + OFF_VP);
    ushort_t* gatesP = (ushort_t*)(ws + OFF_GATES);
    ushort_t* xhi    = (ushort_t*)(ws + OFF_XHI);
    ushort_t* atthi  = (ushort_t*)(ws + OFF_ATTHI);  // aliases xhi (dead)
    ushort_t* attlo  = (ushort_t*)(ws + OFF_ATTLO);
    ushort_t* bthi   = (ushort_t*)(ws + OFF_BTHI);
    ushort_t* btlo   = (ushort_t*)(ws + OFF_BTLO);
    ushort_t* qPh    = (ushort_t*)(ws + OFF_QTH);
    float*    xbar   = ws + OFF_XBAR;
    float*    biasP  = ws + OFF_BIASP;
    int*      maskc  = (int*)(ws + OFF_MASK);

    hipLaunchKernelGGL(prep_kernel, dim3(5904), dim3(256), 0, stream,
                       x, mraw, bias, Wkv, Wg, Wo,
                       xhi, maskc, xbar, bthi, btlo, biasP);
    hipLaunchKernelGGL(qt_gemm, dim3(256), dim3(256), 0, stream, xbar, Wq, qPh);
    // proj: M=16384, N=768, 128x128 tiles, 1-term, dbuf, XCD swizzle
    hipLaunchKernelGGL((mfma_gemm<0, 4, 4, 1>), dim3(768), dim3(256), 0, stream,
                       xhi, xhi, bthi, btlo, bg, (float*)nullptr,
                       kh, vP, gatesP, 6);
    hipLaunchKernelGGL(attn_mfma_kernel, dim3(2048), dim3(256), 0, stream,
                       qPh, kh, vP, gatesP, biasP, maskc, atthi, attlo);
    // out = att @ Wo + bo : M=16384, N=256, 64x64 tiles, 3-term, dbuf
    hipLaunchKernelGGL((mfma_gemm<1, 2, 2, 3>), dim3(1024), dim3(256), 0, stream,
                       atthi, attlo, bthi + 768 * 256, btlo + 768 * 256, bo,
                       (float*)d_out, nullptr, nullptr, nullptr, 4);
}

// Round 13
// 81.199 us; speedup vs baseline: 3.4765x; 1.0535x over previous
//
#include <hip/hip_runtime.h>
#include <math.h>

typedef unsigned short ushort_t;
typedef unsigned int uint_t;
typedef __attribute__((ext_vector_type(8))) short short8v;   // 8 bf16 (4 VGPR)
typedef __attribute__((ext_vector_type(4))) float f32x4;

#define NEG_MAX (-3.402823466e+38f)

// -------- ws layout (float offsets) --------
#define OFF_KH    0
#define OFF_VP    4194304
#define OFF_GATES 6291456
#define OFF_XHI   8388608
#define OFF_ATTHI OFF_XHI                  // aliases xhi (dead after proj)
#define OFF_BTHI  12582912
#define OFF_BTLO  12713984
#define OFF_QTH   12845056
#define OFF_BIASP 12976128
#define OFF_MASK  13500416

// ---------------------------------------------------------------------------
__device__ __forceinline__ ushort_t f2bf(float x) {
    uint_t u = __float_as_uint(x);
    u = (u + 0x7fffu + ((u >> 16) & 1u)) >> 16;   // RNE
    return (ushort_t)u;
}
__device__ __forceinline__ float bf2f(ushort_t u) {
    return __uint_as_float(((uint_t)u) << 16);
}
__device__ __forceinline__ void gl2lds16(const void* g, void* l) {
    typedef const __attribute__((address_space(1))) uint32_t* gptr_t;
    typedef __attribute__((address_space(3))) uint32_t* lptr_t;
    __builtin_amdgcn_global_load_lds((gptr_t)(uintptr_t)g,
                                     (lptr_t)(uintptr_t)l, 16, 0, 0);
}

// ---------------------------------------------------------------------------
// Fused prep kernel. Block ranges:
// [0,4096) split_x (hi only) | [4096,4112) mask canon | [4112,5136) wsplit
// [5136,5648) bias_prepack
__global__ __launch_bounds__(256) void prep_kernel(
    const float* __restrict__ x, const unsigned char* __restrict__ mraw,
    const float* __restrict__ bias, const float* __restrict__ Wkv,
    const float* __restrict__ Wg, const float* __restrict__ Wo,
    ushort_t* __restrict__ xhi,
    int* __restrict__ maskc,
    ushort_t* __restrict__ bthi, ushort_t* __restrict__ btlo,
    float* __restrict__ biasP) {
    __shared__ int cnt[256];
    const int bid = blockIdx.x, t = threadIdx.x;
    if (bid < 4096) {                         // ---- split_x (hi only) ----
        int idx = bid * 256 + t;
        float4 v = ((const float4*)x)[idx];
        ushort4 h;
        h.x = f2bf(v.x);
        h.y = f2bf(v.y);
        h.z = f2bf(v.z);
        h.w = f2bf(v.w);
        ((ushort4*)xhi)[idx] = h;
    } else if (bid < 4112) {                  // ---- mask canon ----
        int c = 0;
        for (int i = t; i < 4096; i += 256)
            if ((i & 3) != 0 && mraw[i] != 0) c++;
        cnt[t] = c;
        __syncthreads();
        for (int s = 128; s > 0; s >>= 1) {
            if (t < s) cnt[t] += cnt[t + s];
            __syncthreads();
        }
        int isBool = cnt[0] > 16;
        int base = (bid - 4096) * 1024;
        if (isBool) {
            for (int i = t; i < 1024; i += 256)
                maskc[base + i] = mraw[base + i] ? 1 : 0;
        } else {
            const int* mi = (const int*)mraw;
            for (int i = t; i < 1024; i += 256)
                maskc[base + i] = mi[base + i] ? 1 : 0;
        }
    } else if (bid < 5136) {                  // ---- wsplit ----
        int idx = (bid - 4112) * 256 + t;
        int n = idx >> 8, k = idx & 255;
        float v;
        if (n < 512)      v = Wkv[(size_t)k * 512 + n];
        else if (n < 768) v = Wg[(size_t)k * 256 + (n - 512)];
        else              v = Wo[(size_t)k * 256 + (n - 768)];
        ushort_t h = f2bf(v);
        bthi[idx] = h;
        btlo[idx] = f2bf(v - bf2f(h));
    } else {                                  // ---- bias prepack ----
        int idx = (bid - 5136) * 256 + t;     // 0..131071
        int lane = idx & 63, g2 = idx >> 6;   // g2 0..2047
        int mf = g2 & 3, nf = (g2 >> 2) & 1, jt = (g2 >> 3) & 3;
        int iq = (g2 >> 5) & 7, h = g2 >> 8;
        int lr = lane & 15, lg = lane >> 4;
        float4 v = *(const float4*)(bias +
            (size_t)(h * 256 + iq * 32 + nf * 16 + lr) * 256 +
            jt * 64 + mf * 16 + lg * 4);
        *(float4*)(biasP + (size_t)idx * 4) = v;
    }
}

// ---------------------------------------------------------------------------
// qt = mean_b(xhi) @ Wq * scale (xbar fused), fragment-packed bf16 hi
__global__ __launch_bounds__(256) void qt_gemm(const ushort_t* __restrict__ xhi,
                                               const float* __restrict__ Wq,
                                               ushort_t* __restrict__ qPh) {
    __shared__ float xrow[256];
    int i = blockIdx.x, t = threadIdx.x;
    float s0 = 0.f, s1 = 0.f, s2 = 0.f, s3 = 0.f;
#pragma unroll
    for (int b8 = 0; b8 < 64; b8 += 4) {
        s0 += bf2f(xhi[(size_t)(b8 * 256 + i) * 256 + t]);
        s1 += bf2f(xhi[(size_t)((b8 + 1) * 256 + i) * 256 + t]);
        s2 += bf2f(xhi[(size_t)((b8 + 2) * 256 + i) * 256 + t]);
        s3 += bf2f(xhi[(size_t)((b8 + 3) * 256 + i) * 256 + t]);
    }
    xrow[t] = ((s0 + s1) + (s2 + s3)) * (1.0f / 64.0f);
    __syncthreads();
    float s = 0.f;
    for (int k = 0; k < 256; k++) s = fmaf(xrow[k], Wq[(size_t)k * 256 + t], s);
    s *= 0.17677669529663687f;   // 1/sqrt(32)
    int h = t >> 5, d = t & 31, lg = d >> 3, e = d & 7;
    int g = i >> 4, lr = i & 15;
    int a = (((h * 16 + g) * 4 + lg) * 16 + lr) * 8 + e;
    qPh[a] = f2bf(s);
}

// ---------------------------------------------------------------------------
// Double-buffered MFMA split-bf16 GEMM, 1-D XCD-swizzled grid.
// TERMS=1: ah*bh | 2: + al*bh | 3: + al*bh + ah*bl | 4: ah*bh + ah*bl
template <int EPI, int MT, int NT, int TERMS>
__global__ __launch_bounds__(256) void mfma_gemm(
    const ushort_t* __restrict__ Ahi, const ushort_t* __restrict__ Alo,
    const ushort_t* __restrict__ Bthi, const ushort_t* __restrict__ Btlo,
    const float* __restrict__ bias, float* __restrict__ C,
    ushort_t* __restrict__ kh, ushort_t* __restrict__ vP,
    ushort_t* __restrict__ gatesP, int gridn) {
    constexpr int BM = MT * 32, BN = NT * 32;
    constexpr int ASZ = BM * 32 * 2;
    constexpr int BSZ = BN * 32 * 2;
    constexpr bool HAS_AL = (TERMS == 2 || TERMS == 3);
    constexpr bool HAS_BL = (TERMS == 3 || TERMS == 4);
    constexpr int AL_OFF = 2 * ASZ;
    constexpr int BH_OFF = AL_OFF + (HAS_AL ? 2 * ASZ : 0);
    constexpr int BL_OFF = BH_OFF + 2 * BSZ;
    constexpr int SMEM_BYTES = BL_OFF + (HAS_BL ? 2 * BSZ : 0);
    __shared__ __align__(16) char smem[SMEM_BYTES];
    char* aH = smem;
    char* aL = smem + AL_OFF;
    char* bH = smem + BH_OFF;
    char* bL = smem + BL_OFF;

    const int t = threadIdx.x;
    const int nwg = gridDim.x, cpx = nwg >> 3;
    const int bid = blockIdx.x;
    const int sid = (bid & 7) * cpx + (bid >> 3);   // XCD-chunked
    const int m0 = (sid / gridn) * BM;
    const int n0 = (sid % gridn) * BN;
    const int wid = t >> 6, lane = t & 63;
    const int wr = wid >> 1, wc = wid & 1;
    const int lr = lane & 15, lg = lane >> 4;

    auto STAGE = [&](int d, int ks) {
        const int k0 = ks * 32;
#pragma unroll
        for (int it = 0; it < BM / 64; ++it) {
            int c = t + it * 256;
            int row = c >> 2, sub = c & 3;
            size_t ga = (size_t)(m0 + row) * 256 + k0 + sub * 8;
            gl2lds16(Ahi + ga, aH + d * ASZ + c * 16);
            if constexpr (HAS_AL)
                gl2lds16(Alo + ga, aL + d * ASZ + c * 16);
        }
#pragma unroll
        for (int it = 0; it < BN / 64; ++it) {
            int c = t + it * 256;
            int row = c >> 2, sub = c & 3;
            size_t gb = (size_t)(n0 + row) * 256 + k0 + sub * 8;
            gl2lds16(Bthi + gb, bH + d * BSZ + c * 16);
            if constexpr (HAS_BL)
                gl2lds16(Btlo + gb, bL + d * BSZ + c * 16);
        }
    };

    f32x4 acc[MT][NT] = {};

    STAGE(0, 0);
    asm volatile("s_waitcnt vmcnt(0)" ::: "memory");
    __syncthreads();

    int cur = 0;
    for (int ks = 0; ks < 8; ++ks) {
        if (ks < 7) STAGE(cur ^ 1, ks + 1);

        const ushort_t* Ap = (const ushort_t*)(aH + cur * ASZ);
        const ushort_t* ALp = (const ushort_t*)(aL + cur * ASZ);
        const ushort_t* Bp = (const ushort_t*)(bH + cur * BSZ);
        const ushort_t* BLp = (const ushort_t*)(bL + cur * BSZ);

        short8v ah[MT], al[MT], bh[NT], bl[NT];
#pragma unroll
        for (int m = 0; m < MT; m++) {
            int off = (wr * (MT * 16) + m * 16 + lr) * 32 + lg * 8;
            ah[m] = *(const short8v*)&Ap[off];
            if constexpr (HAS_AL) al[m] = *(const short8v*)&ALp[off];
        }
#pragma unroll
        for (int n = 0; n < NT; n++) {
            int off = (wc * (NT * 16) + n * 16 + lr) * 32 + lg * 8;
            bh[n] = *(const short8v*)&Bp[off];
            if constexpr (HAS_BL) bl[n] = *(const short8v*)&BLp[off];
        }
#pragma unroll
        for (int m = 0; m < MT; m++)
#pragma unroll
            for (int n = 0; n < NT; n++) {
                acc[m][n] = __builtin_amdgcn_mfma_f32_16x16x32_bf16(
                    ah[m], bh[n], acc[m][n], 0, 0, 0);
                if constexpr (HAS_AL)
                    acc[m][n] = __builtin_amdgcn_mfma_f32_16x16x32_bf16(
                        al[m], bh[n], acc[m][n], 0, 0, 0);
                if constexpr (HAS_BL)
                    acc[m][n] = __builtin_amdgcn_mfma_f32_16x16x32_bf16(
                        ah[m], bl[n], acc[m][n], 0, 0, 0);
            }

        if (ks < 7) {
            asm volatile("s_waitcnt vmcnt(0)" ::: "memory");
            __syncthreads();
        }
        cur ^= 1;
    }

#pragma unroll
    for (int m = 0; m < MT; m++)
#pragma unroll
        for (int n = 0; n < NT; n++) {
            int gr0 = m0 + wr * (MT * 16) + m * 16 + lg * 4;
            int gc = n0 + wc * (NT * 16) + n * 16 + lr;
            if (EPI == 0) {
                if (gc < 256) {          // K fragment-packed, hi only
                    int hh_ = gc >> 5, dk = gc & 31;
                    int lgk = dk >> 3, ek = dk & 7;
#pragma unroll
                    for (int r = 0; r < 4; r++) {
                        int gr = gr0 + r;
                        int bb = gr >> 8, j = gr & 255;
                        int jt = j >> 6, mfk = (j >> 4) & 3, lrk = j & 15;
                        size_t a =
                            (((((size_t)(bb * 8 + hh_) * 4 + jt) * 4 + mfk) * 4
                              + lgk) * 16 + lrk) * 8 + ek;
                        kh[a] = f2bf(acc[m][n][r]);
                    }
                } else if (gc < 512) {   // V^T fragment-packed hi only
                    int cc = gc - 256;
                    int hh_ = cc >> 5, dv = cc & 31;
                    int mfv = dv >> 4, lrv = dv & 15;
                    int gr = gr0;
                    int bb = gr >> 8, j = gr & 255;
                    int jt = j >> 6, hbv = (j >> 5) & 1;
                    int lgv = (j >> 3) & 3, ev = j & 7;
                    size_t a =
                        ((((((size_t)(bb * 8 + hh_) * 4 + jt) * 2 + hbv) * 2
                           + mfv) * 4 + lgv) * 16 + lrv) * 8 + ev;
                    ushort4 hv;
                    hv.x = f2bf(acc[m][n][0]);
                    hv.y = f2bf(acc[m][n][1]);
                    hv.z = f2bf(acc[m][n][2]);
                    hv.w = f2bf(acc[m][n][3]);
                    *(ushort4*)(vP + a) = hv;
                } else {                 // gates bf16, attn-epilogue-fragment order
                    int c = gc - 512;
                    int hh_ = c >> 5, d = c & 31;
                    int mdv = d >> 4, lga = (d >> 2) & 3, ev = d & 3;
#pragma unroll
                    for (int r = 0; r < 4; r++) {
                        int gr = gr0 + r;
                        int bb = gr >> 8, i = gr & 255;
                        int i16 = i >> 4, lra = i & 15;
                        size_t a =
                            ((((size_t)(bb * 8 + hh_) * 16 + i16) * 2 + mdv)
                             * 64 + lga * 16 + lra) * 4 + ev;
                        float v = acc[m][n][r];
                        float g = 1.f / (1.f + __expf(-(v + bias[gc - 512])));
                        gatesP[a] = f2bf(g);
                    }
                }
            } else {
#pragma unroll
                for (int r = 0; r < 4; r++)
                    C[(size_t)(gr0 + r) * 256 + gc] = acc[m][n][r] + bias[gc];
            }
        }
}

// ---------------------------------------------------------------------------
// Per-wave online MFMA flash attention, 16 q-rows per wave, depth-2 prefetch.
// Single LDS round-trip per KV tile; setprio around MFMA clusters.
__global__ __launch_bounds__(256) void attn_mfma_kernel(
    const ushort_t* __restrict__ qPh, const ushort_t* __restrict__ kh,
    const ushort_t* __restrict__ vP, const ushort_t* __restrict__ gatesP,
    const float* __restrict__ biasP, const int* __restrict__ mask,
    ushort_t* __restrict__ atthi) {
    __shared__ __align__(16) ushort_t Pb[4][16 * 88];   // stride 88: 2-way banks
    const int bid = blockIdx.x;
    const int sid = ((bid & 7) << 8) | (bid >> 3);  // 2048 = 8*256
    const int b = sid >> 5;
    const int h = (sid >> 2) & 7;
    const int qq = sid & 3;
    const int t = threadIdx.x;
    const int w = t >> 6, lane = t & 63;
    const int lr = lane & 15, lg = lane >> 4;
    const int i0 = qq * 64 + w * 16;
    const int i16 = qq * 4 + w;
    ushort_t* pbh = Pb[w];

    short8v qf;
    {
        size_t off = ((((size_t)h * 16 + i16) * 4 + lg) * 16 + lr) * 8;
        qf = *(const short8v*)(qPh + off);
    }
    const int mi = mask[b * 256 + i0 + lr];

    const float* bbase = biasP +
        (size_t)(h * 256 + (i16 >> 1) * 32 + (i16 & 1) * 4) * 256 +
        (size_t)lane * 4;

    float m_run = NEG_MAX, l_run = 0.f;
    f32x4 acc_o[2] = {};

    // prefetch tile 0 K + bias
    short8v kf[2][4];
    float4 bf[2][4];
#pragma unroll
    for (int mf = 0; mf < 4; mf++) {
        size_t off = ((((size_t)(b * 8 + h) * 4 + 0) * 4 + mf) * 4 + lg);
        kf[0][mf] = *(const short8v*)(kh + (off * 16 + lr) * 8);
        bf[0][mf] = *(const float4*)(bbase + (size_t)mf * 256);
    }

#pragma unroll
    for (int jt = 0; jt < 4; ++jt) {
        const int cur = jt & 1, nxt = cur ^ 1;
        if (jt < 3) {
#pragma unroll
            for (int mf = 0; mf < 4; mf++) {
                size_t off = ((((size_t)(b * 8 + h) * 4 + (jt + 1)) * 4 + mf)
                              * 4 + lg);
                kf[nxt][mf] = *(const short8v*)(kh + (off * 16 + lr) * 8);
                bf[nxt][mf] = *(const float4*)(bbase +
                                               (size_t)((jt + 1) * 8 + mf) * 256);
            }
        }
        // V for current tile
        short8v vf[2][2];
#pragma unroll
        for (int hb = 0; hb < 2; hb++)
#pragma unroll
            for (int mv = 0; mv < 2; mv++) {
                size_t off = ((((((size_t)(b * 8 + h) * 4 + jt) * 2 + hb) * 2
                               + mv) * 4 + lg) * 16 + lr) * 8;
                vf[hb][mv] = *(const short8v*)(vP + off);
            }
        int4 mj[4];
#pragma unroll
        for (int mf = 0; mf < 4; mf++)
            mj[mf] = *(const int4*)(mask + b * 256 + jt * 64 + mf * 16 + lg * 4);

        // S^T = K * Q^T (1-term)
        f32x4 s[4];
        __builtin_amdgcn_s_setprio(1);
#pragma unroll
        for (int mf = 0; mf < 4; mf++) {
            f32x4 a = {};
            s[mf] = __builtin_amdgcn_mfma_f32_16x16x32_bf16(
                kf[cur][mf], qf, a, 0, 0, 0);
        }
        __builtin_amdgcn_s_setprio(0);
        // bias + mask
#pragma unroll
        for (int mf = 0; mf < 4; mf++) {
            float4 bv = bf[cur][mf];
            s[mf][0] = (mi && mj[mf].x) ? s[mf][0] + bv.x : NEG_MAX;
            s[mf][1] = (mi && mj[mf].y) ? s[mf][1] + bv.y : NEG_MAX;
            s[mf][2] = (mi && mj[mf].z) ? s[mf][2] + bv.z : NEG_MAX;
            s[mf][3] = (mi && mj[mf].w) ? s[mf][3] + bv.w : NEG_MAX;
        }

        // online softmax
        float tm = s[0][0];
#pragma unroll
        for (int mf = 0; mf < 4; mf++)
#pragma unroll
            for (int r = 0; r < 4; r++) tm = fmaxf(tm, s[mf][r]);
        tm = fmaxf(tm, __shfl_xor(tm, 16));
        tm = fmaxf(tm, __shfl_xor(tm, 32));
        float mnew = fmaxf(m_run, tm);
        float corr = __expf(m_run - mnew);
        m_run = mnew;
#pragma unroll
        for (int md = 0; md < 2; md++)
#pragma unroll
            for (int r = 0; r < 4; r++) acc_o[md][r] *= corr;
        float ls = 0.f;
#pragma unroll
        for (int mf = 0; mf < 4; mf++)
#pragma unroll
            for (int r = 0; r < 4; r++) {
                float wv = __expf(s[mf][r] - mnew);
                s[mf][r] = wv;
                ls += wv;
            }
        ls += __shfl_xor(ls, 16);
        ls += __shfl_xor(ls, 32);
        l_run = l_run * corr + ls;

        // PV: pack all 64 j-cols to LDS, single wait, 4 MFMAs
#pragma unroll
        for (int mf = 0; mf < 4; mf++) {
            uint2 hv;
            hv.x = (uint_t)f2bf(s[mf][0]) | ((uint_t)f2bf(s[mf][1]) << 16);
            hv.y = (uint_t)f2bf(s[mf][2]) | ((uint_t)f2bf(s[mf][3]) << 16);
            *(uint2*)(pbh + lr * 88 + mf * 16 + lg * 4) = hv;
        }
        asm volatile("s_waitcnt lgkmcnt(0)" ::: "memory");
        __builtin_amdgcn_sched_barrier(0);
        short8v ph0 = *(const short8v*)(pbh + lr * 88 + lg * 8);
        short8v ph1 = *(const short8v*)(pbh + lr * 88 + 32 + lg * 8);
        __builtin_amdgcn_s_setprio(1);
        acc_o[0] = __builtin_amdgcn_mfma_f32_16x16x32_bf16(
            vf[0][0], ph0, acc_o[0], 0, 0, 0);
        acc_o[1] = __builtin_amdgcn_mfma_f32_16x16x32_bf16(
            vf[0][1], ph0, acc_o[1], 0, 0, 0);
        acc_o[0] = __builtin_amdgcn_mfma_f32_16x16x32_bf16(
            vf[1][0], ph1, acc_o[0], 0, 0, 0);
        acc_o[1] = __builtin_amdgcn_mfma_f32_16x16x32_bf16(
            vf[1][1], ph1, acc_o[1], 0, 0, 0);
        __builtin_amdgcn_s_setprio(0);
    }

    // epilogue: O = acc/l * gate (gates coalesced), bf16 hi only
    float invl = 1.0f / l_run;
#pragma unroll
    for (int md = 0; md < 2; md++) {
        size_t ga = ((((size_t)(b * 8 + h) * 16 + i16) * 2 + md) * 64 + lane) * 4;
        uint2 gv = *(const uint2*)(gatesP + ga);
        float g0 = bf2f((ushort_t)(gv.x & 0xffff));
        float g1 = bf2f((ushort_t)(gv.x >> 16));
        float g2 = bf2f((ushort_t)(gv.y & 0xffff));
        float g3 = bf2f((ushort_t)(gv.y >> 16));
        int i = i0 + lr;
        int d0 = md * 16 + lg * 4;
        size_t base = ((size_t)(b * 256 + i)) * 256 + h * 32 + d0;
        ushort4 hh;
        hh.x = f2bf(acc_o[md][0] * invl * g0);
        hh.y = f2bf(acc_o[md][1] * invl * g1);
        hh.z = f2bf(acc_o[md][2] * invl * g2);
        hh.w = f2bf(acc_o[md][3] * invl * g3);
        *(ushort4*)(atthi + base) = hh;
    }
}

// ---------------------------------------------------------------------------
extern "C" void kernel_launch(void* const* d_in, const int* in_sizes, int n_in,
                              void* d_out, int out_size, void* d_ws, size_t ws_size,
                              hipStream_t stream) {
    const float* x    = (const float*)d_in[0];
    const unsigned char* mraw = (const unsigned char*)d_in[1];
    const float* bias = (const float*)d_in[2];
    const float* Wq   = (const float*)d_in[3];
    const float* Wkv  = (const float*)d_in[4];
    const float* Wg   = (const float*)d_in[5];
    const float* bg   = (const float*)d_in[6];
    const float* Wo   = (const float*)d_in[7];
    const float* bo   = (const float*)d_in[8];

    float* ws = (float*)d_ws;
    ushort_t* kh     = (ushort_t*)(ws + OFF_KH);
    ushort_t* vP     = (ushort_t*)(ws + OFF_VP);
    ushort_t* gatesP = (ushort_t*)(ws + OFF_GATES);
    ushort_t* xhi    = (ushort_t*)(ws + OFF_XHI);
    ushort_t* atthi  = (ushort_t*)(ws + OFF_ATTHI);  // aliases xhi (dead)
    ushort_t* bthi   = (ushort_t*)(ws + OFF_BTHI);
    ushort_t* btlo   = (ushort_t*)(ws + OFF_BTLO);
    ushort_t* qPh    = (ushort_t*)(ws + OFF_QTH);
    float*    biasP  = ws + OFF_BIASP;
    int*      maskc  = (int*)(ws + OFF_MASK);

    hipLaunchKernelGGL(prep_kernel, dim3(5648), dim3(256), 0, stream,
                       x, mraw, bias, Wkv, Wg, Wo,
                       xhi, maskc, bthi, btlo, biasP);
    hipLaunchKernelGGL(qt_gemm, dim3(256), dim3(256), 0, stream, xhi, Wq, qPh);
    // proj: M=16384, N=768, 128x128 tiles, 1-term, dbuf, XCD swizzle
    hipLaunchKernelGGL((mfma_gemm<0, 4, 4, 1>), dim3(768), dim3(256), 0, stream,
                       xhi, xhi, bthi, btlo, bg, (float*)nullptr,
                       kh, vP, gatesP, 6);
    hipLaunchKernelGGL(attn_mfma_kernel, dim3(2048), dim3(256), 0, stream,
                       qPh, kh, vP, gatesP, biasP, maskc, atthi);
    // out = att @ Wo + bo : TERMS=4 (ah*bh + ah*bl), 64x64 tiles
    hipLaunchKernelGGL((mfma_gemm<1, 2, 2, 4>), dim3(1024), dim3(256), 0, stream,
                       atthi, atthi, bthi + 768 * 256, btlo + 768 * 256, bo,
                       (float*)d_out, nullptr, nullptr, nullptr, 4);
}